// Round 18
// baseline (628.557 us; speedup 1.0000x reference)
//
#include <hip/hip_runtime.h>
#include <hip/hip_bf16.h>
#include <math.h>

#define NN 30000
#define EE 960000
#define IN_ 128
#define DD 256
#define CC 40
#define EPS 1e-5f

typedef short bf8 __attribute__((ext_vector_type(8)));    // 8 bf16 (4 VGPRs)
typedef float f32x4 __attribute__((ext_vector_type(4)));

__device__ inline short f2bf(float x) {
    unsigned u = __float_as_uint(x);
    unsigned r = (u + 0x7fffu + ((u >> 16) & 1u)) >> 16;   // RNE
    return (short)r;
}

__device__ inline unsigned pk2(float lo, float hi) {
    __hip_bfloat162 h = __float22bfloat162_rn(make_float2(lo, hi));
    return *reinterpret_cast<unsigned*>(&h);
}

// split 8 f32 into bf16 hi + bf16 lo(residual) fragments
__device__ inline void split8(float4 f0, float4 f1, bf8* h, bf8* l) {
    unsigned h0 = pk2(f0.x, f0.y), h1 = pk2(f0.z, f0.w);
    unsigned h2 = pk2(f1.x, f1.y), h3 = pk2(f1.z, f1.w);
    float e0 = f0.x - __uint_as_float(h0 << 16);
    float e1 = f0.y - __uint_as_float(h0 & 0xFFFF0000u);
    float e2 = f0.z - __uint_as_float(h1 << 16);
    float e3 = f0.w - __uint_as_float(h1 & 0xFFFF0000u);
    float e4 = f1.x - __uint_as_float(h2 << 16);
    float e5 = f1.y - __uint_as_float(h2 & 0xFFFF0000u);
    float e6 = f1.z - __uint_as_float(h3 << 16);
    float e7 = f1.w - __uint_as_float(h3 & 0xFFFF0000u);
    uint4 hu = make_uint4(h0, h1, h2, h3);
    uint4 lu = make_uint4(pk2(e0, e1), pk2(e2, e3), pk2(e4, e5), pk2(e6, e7));
    *h = *(bf8*)&hu;
    *l = *(bf8*)&lu;
}

// ---------------------------------------------------------------------------
// Small GEMM via bf16x3 split MFMA. Optional in-block BN fold of the INPUT
// from raw stats (isum/isq + ig/ib -> relu(a*x+c); K==256 in that mode) with
// JK-sum write (smode 1: sOut=a, 2: sOut+=a). Per-col output sum/sumsq stats.
// ---------------------------------------------------------------------------
__global__ __launch_bounds__(256) void gemm64_mfma(
    const float* __restrict__ A, int K,
    const short* __restrict__ Whi, const short* __restrict__ Wlo,
    const float* __restrict__ bias,
    float* __restrict__ Y, int Nrows,
    float* __restrict__ osum, float* __restrict__ osq,
    const float* __restrict__ isum, const float* __restrict__ isq,
    const float* __restrict__ ig, const float* __restrict__ ib,
    float* __restrict__ sOut, int smode, float invN)
{
    __shared__ float redS[4][64], redQ[4][64];
    __shared__ float ah_s[256], ch_s[256];
    const int t = threadIdx.x;
    if (isum) {   // K==256 in this mode; 256 threads each fold one column
        float m = isum[t] * invN;
        float vv = isq[t] * invN - m * m;
        float s = ig[t] * rsqrtf(vv + EPS);
        ah_s[t] = s;
        ch_s[t] = ib[t] - m * s;
        __syncthreads();
    }
    const int lane = t & 63;
    const int w = t >> 6;
    const int l15 = lane & 15, l4 = (lane >> 4) & 3;
    const int row0 = blockIdx.x * 64 + w * 16;
    const bf8* whi = (const bf8*)Whi;
    const bf8* wlo = (const bf8*)Wlo;

    f32x4 acc[4] = {};
    const int nst = K >> 5;
    const int nA = row0 + l15;
    const bool valA = nA < Nrows;

#pragma unroll 2
    for (int ks = 0; ks < nst; ++ks) {
        int k0 = ks * 32 + l4 * 8;
        float4 f0, f1;
        if (valA) {
            const float* p = &A[(size_t)nA * K + k0];
            f0 = *(const float4*)p;
            f1 = *(const float4*)(p + 4);
        } else {
            f0 = make_float4(0.f, 0.f, 0.f, 0.f);
            f1 = f0;
        }
        if (isum) {
            float4 a4 = *(const float4*)&ah_s[k0], a5 = *(const float4*)&ah_s[k0 + 4];
            float4 c4 = *(const float4*)&ch_s[k0], c5 = *(const float4*)&ch_s[k0 + 4];
            f0.x = fmaxf(a4.x * f0.x + c4.x, 0.f);
            f0.y = fmaxf(a4.y * f0.y + c4.y, 0.f);
            f0.z = fmaxf(a4.z * f0.z + c4.z, 0.f);
            f0.w = fmaxf(a4.w * f0.w + c4.w, 0.f);
            f1.x = fmaxf(a5.x * f1.x + c5.x, 0.f);
            f1.y = fmaxf(a5.y * f1.y + c5.y, 0.f);
            f1.z = fmaxf(a5.z * f1.z + c5.z, 0.f);
            f1.w = fmaxf(a5.w * f1.w + c5.w, 0.f);
            if (valA) {
                float* sp = &sOut[(size_t)nA * K + k0];
                if (smode == 1) {
                    *(float4*)sp = f0;
                    *(float4*)(sp + 4) = f1;
                } else {
                    float4 s0 = *(const float4*)sp, s1 = *(const float4*)(sp + 4);
                    s0.x += f0.x; s0.y += f0.y; s0.z += f0.z; s0.w += f0.w;
                    s1.x += f1.x; s1.y += f1.y; s1.z += f1.z; s1.w += f1.w;
                    *(float4*)sp = s0;
                    *(float4*)(sp + 4) = s1;
                }
            }
        }
        bf8 ah, al;
        split8(f0, f1, &ah, &al);
        bf8 bh[4], bl[4];
#pragma unroll
        for (int nr = 0; nr < 4; ++nr) {
            int idx = (ks * 4 + nr) * 64 + lane;
            bh[nr] = whi[idx];
            bl[nr] = wlo[idx];
        }
#pragma unroll
        for (int nr = 0; nr < 4; ++nr) {
            acc[nr] = __builtin_amdgcn_mfma_f32_16x16x32_bf16(ah, bh[nr], acc[nr], 0, 0, 0);
            acc[nr] = __builtin_amdgcn_mfma_f32_16x16x32_bf16(ah, bl[nr], acc[nr], 0, 0, 0);
            acc[nr] = __builtin_amdgcn_mfma_f32_16x16x32_bf16(al, bh[nr], acc[nr], 0, 0, 0);
        }
    }

    float cs[4] = {}, cq[4] = {};
#pragma unroll
    for (int nr = 0; nr < 4; ++nr) {
#pragma unroll
        for (int r = 0; r < 4; ++r) {
            int n = row0 + l4 * 4 + r;
            float v = acc[nr][r];
            if (bias) v += bias[nr * 16 + l15];
            v = (v > 0.f) ? v : 0.01f * v;
            if (n < Nrows) {
                Y[(size_t)n * 64 + nr * 16 + l15] = v;
                cs[nr] += v;
                cq[nr] += v * v;
            }
        }
    }
#pragma unroll
    for (int nr = 0; nr < 4; ++nr) {
        float s1 = cs[nr], s2 = cq[nr];
        s1 += __shfl_down(s1, 32);
        s2 += __shfl_down(s2, 32);
        s1 += __shfl_down(s1, 16);
        s2 += __shfl_down(s2, 16);
        if (lane < 16) {
            redS[w][nr * 16 + l15] = s1;
            redQ[w][nr * 16 + l15] = s2;
        }
    }
    __syncthreads();
    if (t < 64) {
        float s1 = redS[0][t] + redS[1][t] + redS[2][t] + redS[3][t];
        float s2 = redQ[0][t] + redQ[1][t] + redQ[2][t] + redQ[3][t];
        atomicAdd(&osum[t], s1);
        atomicAdd(&osq[t], s2);
    }
}

// ---------------------------------------------------------------------------
// Convert the three W1 weights ([64][K] f32) to bf16 hi/lo tiled frags, 1 launch.
// ---------------------------------------------------------------------------
__global__ void conv_w64_3(const float* __restrict__ W0, const float* __restrict__ Wa,
                           const float* __restrict__ Wb,
                           short* __restrict__ O0h, short* __restrict__ O0l,
                           short* __restrict__ O1h, short* __restrict__ O1l,
                           short* __restrict__ O2h, short* __restrict__ O2l)
{
    int tid = blockIdx.x * 256 + threadIdx.x;   // 1024 + 2048 + 2048 = 5120 frags
    const float* W; short* oh; short* ol; int K, f;
    if (tid < 1024)      { W = W0; oh = O0h; ol = O0l; K = 128; f = tid; }
    else if (tid < 3072) { W = Wa; oh = O1h; ol = O1l; K = 256; f = tid - 1024; }
    else if (tid < 5120) { W = Wb; oh = O2h; ol = O2l; K = 256; f = tid - 3072; }
    else return;
    int l = f & 63;
    int r = f >> 6;
    int cb = r & 3, ks = r >> 2;
    int col = cb * 16 + (l & 15);
    int k = ks * 32 + ((l >> 4) & 3) * 8;
    const float* src = W + (size_t)col * K + k;
    bf8 h, lo;
#pragma unroll
    for (int e = 0; e < 8; ++e) {
        float v = src[e];
        short hb = f2bf(v);
        float hf = __uint_as_float(((unsigned)(unsigned short)hb) << 16);
        h[e] = hb;
        lo[e] = f2bf(v - hf);
    }
    ((bf8*)oh)[f] = h;
    ((bf8*)ol)[f] = lo;
}

// ---------------------------------------------------------------------------
// Convert Wp (f32 [256][4096]) to bf16 pre-tiled in MFMA B-fragment order.
// ---------------------------------------------------------------------------
__global__ void conv_wp(const float* __restrict__ Wp, short* __restrict__ Wpb)
{
    int tid = blockIdx.x * 256 + threadIdx.x;   // 131072 threads
    int l = tid & 63;
    int r = tid >> 6;
    int jo = r & 1;
    int q = r >> 1;
    int cb = q & 15;
    int i = q >> 4;
    int col = cb * 16 + (l & 15);
    int k = i * 64 + jo * 32 + ((l >> 4) & 3) * 8;
    const float* src = Wp + (size_t)col * 4096 + k;
    bf8 v;
#pragma unroll
    for (int e = 0; e < 8; ++e) v[e] = f2bf(src[e]);
    ((bf8*)Wpb)[tid] = v;
}

// ---------------------------------------------------------------------------
// Convert Wm1 (f32 [256][256]) to bf16 hi/lo pre-tiled fragments (16 cb).
// ---------------------------------------------------------------------------
__global__ void conv_wm1(const float* __restrict__ W,
                         short* __restrict__ Whi, short* __restrict__ Wlo)
{
    int tid = blockIdx.x * 256 + threadIdx.x;   // 8192 threads
    int l = tid & 63;
    int f = tid >> 6;
    int cb = f & 15;
    int ks = f >> 4;
    int col = cb * 16 + (l & 15);
    int k = ks * 32 + ((l >> 4) & 3) * 8;
    const float* src = W + (size_t)col * 256 + k;
    bf8 h, lo;
#pragma unroll
    for (int e = 0; e < 8; ++e) {
        float v = src[e];
        short hb = f2bf(v);
        float hf = __uint_as_float(((unsigned)(unsigned short)hb) << 16);
        h[e] = hb;
        lo[e] = f2bf(v - hf);
    }
    ((bf8*)Whi)[tid] = h;
    ((bf8*)Wlo)[tid] = lo;
}

// ---------------------------------------------------------------------------
// MFMA big GEMM v10: v9 with B prefetch ISSUED FIRST in each step (before the
// af ds_reads) so the L2 service window spans the whole step's LDS+MFMA work.
// BM=128, one round per CU; lgkmcnt-only barrier.
// ---------------------------------------------------------------------------
#define FOG_BARRIER() asm volatile("s_waitcnt lgkmcnt(0)\n\ts_barrier" ::: "memory")

#define FOG_STEP(I, BUF, BU, BP)                                              \
  {                                                                           \
    int inext = ((I) < 63) ? (I) + 1 : 63;                                    \
    _Pragma("unroll")                                                         \
    for (int nr = 0; nr < 4; ++nr) {                                          \
      _Pragma("unroll")                                                       \
      for (int jo = 0; jo < 2; ++jo)                                          \
        BP[nr][jo] = wp8[((inext * 16 + cbb + nr) * 2 + jo) * 64 + lane];     \
    }                                                                         \
    bf8 af[4][2];                                                             \
    _Pragma("unroll")                                                         \
    for (int m = 0; m < 4; ++m) {                                             \
      _Pragma("unroll")                                                       \
      for (int jo = 0; jo < 2; ++jo) {                                        \
        int c = jo * 4 + l4;                                                  \
        int n = (mrb + m) * 16 + l15;                                         \
        af[m][jo] = *(const bf8*)&At[BUF][c][n ^ (c & 7)][0];                 \
      }                                                                       \
    }                                                                         \
    _Pragma("unroll")                                                         \
    for (int m = 0; m < 4; ++m) {                                             \
      _Pragma("unroll")                                                       \
      for (int nr = 0; nr < 4; ++nr) {                                        \
        acc[m][nr] = __builtin_amdgcn_mfma_f32_16x16x32_bf16(af[m][0], BU[nr][0], acc[m][nr], 0, 0, 0); \
        acc[m][nr] = __builtin_amdgcn_mfma_f32_16x16x32_bf16(af[m][1], BU[nr][1], acc[m][nr], 0, 0, 0); \
      }                                                                       \
    }                                                                         \
    if ((I) < 63) {                                                           \
      float xv = xd_s[nl][(I) + 1];                                           \
      uint4 q0, q1;                                                           \
      q0.x = pk2(xv * agr[0],  xv * agr[1]);                                  \
      q0.y = pk2(xv * agr[2],  xv * agr[3]);                                  \
      q0.z = pk2(xv * agr[4],  xv * agr[5]);                                  \
      q0.w = pk2(xv * agr[6],  xv * agr[7]);                                  \
      q1.x = pk2(xv * agr[8],  xv * agr[9]);                                  \
      q1.y = pk2(xv * agr[10], xv * agr[11]);                                 \
      q1.z = pk2(xv * agr[12], xv * agr[13]);                                 \
      q1.w = pk2(xv * agr[14], xv * agr[15]);                                 \
      *(uint4*)&At[(BUF) ^ 1][cA][nl ^ (cA & 7)][0] = q0;                     \
      *(uint4*)&At[(BUF) ^ 1][cB][nl ^ (cB & 7)][0] = q1;                     \
    }                                                                         \
    FOG_BARRIER();                                                            \
  }

__global__ __launch_bounds__(512, 2) void fog_mfma(
    const float* __restrict__ y1, const float* __restrict__ a1, const float* __restrict__ c1,
    const float* __restrict__ agg, const short* __restrict__ Wpb,
    float* __restrict__ H, int Nrows,
    float* __restrict__ ssum, float* __restrict__ ssq,
    float* __restrict__ sjk)
{
    __shared__ float xd_s[128][68];
    __shared__ __align__(16) short At[2][8][128][8];  // [buf][chunk][node^chunk][8 bf16]
    const int t = threadIdx.x;          // 0..511
    const int lane = t & 63;
    const int w = t >> 6;               // wave 0..7
    const int nbase = blockIdx.x * 128;
    const int nl = t >> 2;              // staging node 0..127
    const int cA = (t & 3) * 2;         // staging j-chunks cA, cB
    const int cB = cA + 1;
    const int l15 = lane & 15;
    const int l4 = (lane >> 4) & 3;
    const int mrb = (w & 1) * 4;        // row 16-block base: 0 or 4
    const int cbb = (w >> 1) * 4;       // col 16-block base: 0,4,8,12

    // stage xd (BN1-folded y1) into LDS; agg 16-value chunk into regs
    float agr[16];
    {
        int n = nbase + nl;
        bool valid = n < Nrows;
        const float* yr = y1 + (size_t)n * 64 + cA * 8;
        const float* ar = agg + (size_t)n * 64 + cA * 8;
#pragma unroll
        for (int u = 0; u < 16; u += 4) {
            float4 yv = valid ? *(const float4*)(yr + u) : make_float4(0.f, 0.f, 0.f, 0.f);
            float4 av = valid ? *(const float4*)(ar + u) : make_float4(0.f, 0.f, 0.f, 0.f);
            int j0 = cA * 8 + u;
            xd_s[nl][j0 + 0] = a1[j0 + 0] * yv.x + c1[j0 + 0];
            xd_s[nl][j0 + 1] = a1[j0 + 1] * yv.y + c1[j0 + 1];
            xd_s[nl][j0 + 2] = a1[j0 + 2] * yv.z + c1[j0 + 2];
            xd_s[nl][j0 + 3] = a1[j0 + 3] * yv.w + c1[j0 + 3];
            agr[u + 0] = av.x; agr[u + 1] = av.y; agr[u + 2] = av.z; agr[u + 3] = av.w;
        }
    }
    __syncthreads();

    const bf8* wp8 = (const bf8*)Wpb;
    // gen A(0) -> buf0 ; load B(0) -> bA
    {
        float xv = xd_s[nl][0];
        uint4 q0, q1;
        q0.x = pk2(xv * agr[0],  xv * agr[1]);
        q0.y = pk2(xv * agr[2],  xv * agr[3]);
        q0.z = pk2(xv * agr[4],  xv * agr[5]);
        q0.w = pk2(xv * agr[6],  xv * agr[7]);
        q1.x = pk2(xv * agr[8],  xv * agr[9]);
        q1.y = pk2(xv * agr[10], xv * agr[11]);
        q1.z = pk2(xv * agr[12], xv * agr[13]);
        q1.w = pk2(xv * agr[14], xv * agr[15]);
        *(uint4*)&At[0][cA][nl ^ (cA & 7)][0] = q0;
        *(uint4*)&At[0][cB][nl ^ (cB & 7)][0] = q1;
    }
    bf8 bA[4][2], bB[4][2];
#pragma unroll
    for (int nr = 0; nr < 4; ++nr)
#pragma unroll
        for (int jo = 0; jo < 2; ++jo)
            bA[nr][jo] = wp8[((cbb + nr) * 2 + jo) * 64 + lane];
    __syncthreads();

    f32x4 acc[4][4] = {};
    for (int i = 0; i < 64; i += 2) {
        FOG_STEP(i,     0, bA, bB);
        FOG_STEP(i + 1, 1, bB, bA);
    }

    if (ssum) {
        float cs[4] = {}, cq[4] = {};
#pragma unroll
        for (int m = 0; m < 4; ++m) {
#pragma unroll
            for (int r = 0; r < 4; ++r) {
                int n = nbase + (mrb + m) * 16 + l4 * 4 + r;
                if (n < Nrows) {
#pragma unroll
                    for (int nr = 0; nr < 4; ++nr) {
                        float v = acc[m][nr][r];
                        H[(size_t)n * 256 + (cbb + nr) * 16 + l15] = v;
                        cs[nr] += v;
                        cq[nr] += v * v;
                    }
                }
            }
        }
#pragma unroll
        for (int nr = 0; nr < 4; ++nr) {
            float s1 = cs[nr], s2 = cq[nr];
            s1 += __shfl_down(s1, 32);
            s2 += __shfl_down(s2, 32);
            s1 += __shfl_down(s1, 16);
            s2 += __shfl_down(s2, 16);
            if (l4 == 0 && lane < 16) {
                atomicAdd(&ssum[(cbb + nr) * 16 + l15], s1);
                atomicAdd(&ssq[(cbb + nr) * 16 + l15], s2);
            }
        }
    } else {
        // last layer: s += x3 fused (each (n,col) owned by exactly one thread)
#pragma unroll
        for (int m = 0; m < 4; ++m) {
#pragma unroll
            for (int r = 0; r < 4; ++r) {
                int n = nbase + (mrb + m) * 16 + l4 * 4 + r;
                if (n < Nrows) {
#pragma unroll
                    for (int nr = 0; nr < 4; ++nr) {
                        size_t idx = (size_t)n * 256 + (cbb + nr) * 16 + l15;
                        sjk[idx] += acc[m][nr][r];
                    }
                }
            }
        }
    }
}

// ---------------------------------------------------------------------------
// Fused MLP head: hid = relu(s @ Wm1.T + bm1) via bf16x3 MFMA (staged in LDS),
// then logits = hid @ Wm2.T + bm2 and row log_softmax -> out. One kernel.
// ---------------------------------------------------------------------------
__global__ __launch_bounds__(512) void head_lsm(
    const float* __restrict__ A,
    const short* __restrict__ Whi, const short* __restrict__ Wlo,
    const float* __restrict__ bias,
    const float* __restrict__ Wm2, const float* __restrict__ bm2,
    float* __restrict__ out, int Nrows)
{
    __shared__ float hid_s[64][257];
    __shared__ float Wl[40][257];
    __shared__ float bl[40];
    const int t = threadIdx.x;
    const int lane = t & 63;
    const int w = t >> 6;
    const int nbase = blockIdx.x * 64;
    const int l15 = lane & 15, l4 = (lane >> 4) & 3;
    const int mrb = (w & 1) * 32;
    const int cbb = (w >> 1) * 4;
    const bf8* whi = (const bf8*)Whi;
    const bf8* wlo = (const bf8*)Wlo;

    for (int e = t; e < 40 * 256; e += 512) Wl[e >> 8][e & 255] = Wm2[e];
    if (t < 40) bl[t] = bm2[t];

    f32x4 acc[2][4] = {};
#pragma unroll
    for (int ks = 0; ks < 8; ++ks) {
        bf8 ah[2], al[2];
#pragma unroll
        for (int m = 0; m < 2; ++m) {
            int n = nbase + mrb + m * 16 + l15;
            float4 f0, f1;
            if (n < Nrows) {
                const float* p = &A[(size_t)n * 256 + ks * 32 + l4 * 8];
                f0 = *(const float4*)p;
                f1 = *(const float4*)(p + 4);
            } else {
                f0 = make_float4(0.f, 0.f, 0.f, 0.f);
                f1 = f0;
            }
            split8(f0, f1, &ah[m], &al[m]);
        }
        bf8 bh[4], blw[4];
#pragma unroll
        for (int nr = 0; nr < 4; ++nr) {
            int idx = (ks * 16 + cbb + nr) * 64 + lane;
            bh[nr] = whi[idx];
            blw[nr] = wlo[idx];
        }
#pragma unroll
        for (int m = 0; m < 2; ++m)
#pragma unroll
            for (int nr = 0; nr < 4; ++nr) {
                acc[m][nr] = __builtin_amdgcn_mfma_f32_16x16x32_bf16(ah[m], bh[nr], acc[m][nr], 0, 0, 0);
                acc[m][nr] = __builtin_amdgcn_mfma_f32_16x16x32_bf16(ah[m], blw[nr], acc[m][nr], 0, 0, 0);
                acc[m][nr] = __builtin_amdgcn_mfma_f32_16x16x32_bf16(al[m], bh[nr], acc[m][nr], 0, 0, 0);
            }
    }

#pragma unroll
    for (int m = 0; m < 2; ++m) {
#pragma unroll
        for (int r = 0; r < 4; ++r) {
            int rl = mrb + m * 16 + l4 * 4 + r;   // local row 0..63
#pragma unroll
            for (int nr = 0; nr < 4; ++nr) {
                int col = (cbb + nr) * 16 + l15;
                float v = acc[m][nr][r] + bias[col];
                hid_s[rl][col] = fmaxf(v, 0.f);
            }
        }
    }
    __syncthreads();

    // log-softmax: 8 threads per node, 5 classes each
    int nl2 = t >> 3;
    int sub = t & 7;
    int node = nbase + nl2;
    if (node >= Nrows) return;

    float accl[5];
#pragma unroll
    for (int r = 0; r < 5; ++r) accl[r] = bl[sub * 5 + r];
    for (int k = 0; k < 256; k += 4) {
        float4 h4 = *(const float4*)&hid_s[nl2][k];
        float hv[4] = {h4.x, h4.y, h4.z, h4.w};
#pragma unroll
        for (int kk = 0; kk < 4; ++kk)
#pragma unroll
            for (int r = 0; r < 5; ++r)
                accl[r] += hv[kk] * Wl[sub * 5 + r][k + kk];
    }
    float mx = accl[0];
#pragma unroll
    for (int r = 1; r < 5; ++r) mx = fmaxf(mx, accl[r]);
    for (int off = 1; off < 8; off <<= 1) mx = fmaxf(mx, __shfl_xor(mx, off, 8));
    float se = 0.f;
#pragma unroll
    for (int r = 0; r < 5; ++r) se += expf(accl[r] - mx);
    for (int off = 1; off < 8; off <<= 1) se += __shfl_xor(se, off, 8);
    float lse = logf(se);
#pragma unroll
    for (int r = 0; r < 5; ++r)
        out[(size_t)node * 40 + sub * 5 + r] = accl[r] - mx - lse;
}

// ---------------------------------------------------------------------------
// CSR build: histogram of dst, prefix scan, fill src lists.
// ---------------------------------------------------------------------------
__global__ void hist_deg(const int* __restrict__ dst, int* __restrict__ deg)
{
    int e = blockIdx.x * 256 + threadIdx.x;
    if (e < EE) atomicAdd(&deg[dst[e]], 1);
}

__global__ void scan1(const int* __restrict__ deg, int* __restrict__ rowptr,
                      int* __restrict__ bsum)
{
    __shared__ int sh[256];
    int t = threadIdx.x;
    int i = blockIdx.x * 256 + t;
    int v = (i < NN) ? deg[i] : 0;
    sh[t] = v;
    __syncthreads();
    for (int off = 1; off < 256; off <<= 1) {
        int add = (t >= off) ? sh[t - off] : 0;
        __syncthreads();
        sh[t] += add;
        __syncthreads();
    }
    if (i < NN) rowptr[i] = sh[t] - v;          // exclusive
    if (t == 255) bsum[blockIdx.x] = sh[255];
}

__global__ void scan2(int* __restrict__ bsum, int* __restrict__ rowptr, int nb2)
{
    __shared__ int sh[256];
    int t = threadIdx.x;
    int v = (t < nb2) ? bsum[t] : 0;
    sh[t] = v;
    __syncthreads();
    for (int off = 1; off < 256; off <<= 1) {
        int add = (t >= off) ? sh[t - off] : 0;
        __syncthreads();
        sh[t] += add;
        __syncthreads();
    }
    if (t < nb2) bsum[t] = sh[t] - v;            // exclusive
    if (t == 0) rowptr[NN] = EE;
}

__global__ void scan3(int* __restrict__ rowptr, const int* __restrict__ bsum,
                      int* __restrict__ cursor)
{
    int i = blockIdx.x * 256 + threadIdx.x;
    if (i < NN) {
        int r = rowptr[i] + bsum[blockIdx.x];
        rowptr[i] = r;
        cursor[i] = r;
    }
}

__global__ void fill_csr(const int* __restrict__ src, const int* __restrict__ dst,
                         int* __restrict__ cursor, int* __restrict__ csr_src)
{
    int e = blockIdx.x * 256 + threadIdx.x;
    if (e < EE) {
        int p = atomicAdd(&cursor[dst[e]], 1);
        csr_src[p] = src[e];
    }
}

// ---------------------------------------------------------------------------
// Gather aggregation with in-block BN2 fold from raw y2 stats:
// agg[v] = a2 * (sum_{e: dst=v} y2[src_e]) + deg_v * c2.
// ONE WAVE per node: 4 edge-substreams x 16 chunk-lanes; 4 row-loads in
// flight per substream.
// ---------------------------------------------------------------------------
__global__ __launch_bounds__(256) void gather_agg(
    const int* __restrict__ rowptr, const int* __restrict__ csr_src,
    const float* __restrict__ y2,
    const float* __restrict__ isum, const float* __restrict__ isq,
    const float* __restrict__ g2, const float* __restrict__ b2,
    float* __restrict__ agg, float invN)
{
    __shared__ float a2s[64], c2s[64];
    int t = threadIdx.x;
    if (t < 64) {
        float m = isum[t] * invN;
        float vv = isq[t] * invN - m * m;
        float s = g2[t] * rsqrtf(vv + EPS);
        a2s[t] = s;
        c2s[t] = b2[t] - m * s;
    }
    __syncthreads();
    int g = t >> 6;              // node within block: 0..3 (one wave per node)
    int sub = (t >> 4) & 3;      // edge substream 0..3
    int l = t & 15;              // float4 chunk
    int v = blockIdx.x * 4 + g;
    if (v >= NN) return;
    int beg = rowptr[v], end = rowptr[v + 1];
    float ax0 = 0.f, ay0 = 0.f, az0 = 0.f, aw0 = 0.f;
    float ax1 = 0.f, ay1 = 0.f, az1 = 0.f, aw1 = 0.f;
    int k = beg + sub;
    for (; k + 12 < end; k += 16) {
        int s0 = csr_src[k], s1 = csr_src[k + 4];
        int s2 = csr_src[k + 8], s3 = csr_src[k + 12];
        float4 v0 = *(const float4*)&y2[(size_t)s0 * 64 + l * 4];
        float4 v1 = *(const float4*)&y2[(size_t)s1 * 64 + l * 4];
        float4 v2 = *(const float4*)&y2[(size_t)s2 * 64 + l * 4];
        float4 v3 = *(const float4*)&y2[(size_t)s3 * 64 + l * 4];
        ax0 += v0.x + v2.x; ay0 += v0.y + v2.y; az0 += v0.z + v2.z; aw0 += v0.w + v2.w;
        ax1 += v1.x + v3.x; ay1 += v1.y + v3.y; az1 += v1.z + v3.z; aw1 += v1.w + v3.w;
    }
    for (; k < end; k += 4) {
        int s = csr_src[k];
        float4 val = *(const float4*)&y2[(size_t)s * 64 + l * 4];
        ax0 += val.x; ay0 += val.y; az0 += val.z; aw0 += val.w;
    }
    float ax = ax0 + ax1, ay = ay0 + ay1, az = az0 + az1, aw = aw0 + aw1;
    ax += __shfl_down(ax, 32);
    ay += __shfl_down(ay, 32);
    az += __shfl_down(az, 32);
    aw += __shfl_down(aw, 32);
    ax += __shfl_down(ax, 16);
    ay += __shfl_down(ay, 16);
    az += __shfl_down(az, 16);
    aw += __shfl_down(aw, 16);
    if ((t & 63) < 16) {
        float dg = (float)(end - beg);
        float4 a4 = *(const float4*)&a2s[l * 4];
        float4 c4 = *(const float4*)&c2s[l * 4];
        float4 o;
        o.x = a4.x * ax + dg * c4.x;
        o.y = a4.y * ay + dg * c4.y;
        o.z = a4.z * az + dg * c4.z;
        o.w = a4.w * aw + dg * c4.w;
        *(float4*)&agg[(size_t)v * 64 + l * 4] = o;
    }
}

// ---------------------------------------------------------------------------
// fold BN1 (a1,c1); fold into W2 and emit bf16 hi/lo tiled fragments. 64 thr.
// ---------------------------------------------------------------------------
__global__ void fold_bn1_w2(const float* __restrict__ ssum, const float* __restrict__ ssq,
                            const float* __restrict__ g, const float* __restrict__ b,
                            float* __restrict__ a, float* __restrict__ c,
                            const float* __restrict__ W2,
                            short* __restrict__ w2h, short* __restrict__ w2l,
                            float* __restrict__ b2f, float invN)
{
    __shared__ float as[64], cs[64];
    __shared__ float W2s[64][65];
    int j = threadIdx.x;   // 64 threads
    {
        float m = ssum[j] * invN;
        float v = ssq[j] * invN - m * m;
        float s = g[j] * rsqrtf(v + EPS);
        a[j] = s;
        c[j] = b[j] - m * s;
        as[j] = s;
        cs[j] = b[j] - m * s;
    }
    __syncthreads();
    float bb = 0.f;
    for (int i = 0; i < 64; ++i) {
        float wv = W2[j * 64 + i];
        W2s[j][i] = wv * as[i];
        bb += wv * cs[i];
    }
    b2f[j] = bb;
    __syncthreads();
#pragma unroll
    for (int rep = 0; rep < 8; ++rep) {
        int cb = rep & 3, ks = rep >> 2;
        int col = cb * 16 + (j & 15);
        int k = ks * 32 + ((j >> 4) & 3) * 8;
        bf8 h, lo;
#pragma unroll
        for (int e = 0; e < 8; ++e) {
            float v = W2s[col][k + e];
            short hb = f2bf(v);
            float hf = __uint_as_float(((unsigned)(unsigned short)hb) << 16);
            h[e] = hb;
            lo[e] = f2bf(v - hf);
        }
        ((bf8*)w2h)[rep * 64 + j] = h;
        ((bf8*)w2l)[rep * 64 + j] = lo;
    }
}

// ---------------------------------------------------------------------------
extern "C" void kernel_launch(void* const* d_in, const int* in_sizes, int n_in,
                              void* d_out, int out_size, void* d_ws, size_t ws_size,
                              hipStream_t stream)
{
    const float* x = (const float*)d_in[0];
    const int* ei = (const int*)d_in[1];
    const int* src = ei;          // row 0
    const int* dst = ei + EE;     // row 1
    const float* W1[3] = {(const float*)d_in[2], (const float*)d_in[9],  (const float*)d_in[16]};
    const float* W2[3] = {(const float*)d_in[3], (const float*)d_in[10], (const float*)d_in[17]};
    const float* Wp[3] = {(const float*)d_in[4], (const float*)d_in[11], (const float*)d_in[18]};
    const float* g1[3] = {(const float*)d_in[5], (const float*)d_in[12], (const float*)d_in[19]};
    const float* b1[3] = {(const float*)d_in[6], (const float*)d_in[13], (const float*)d_in[20]};
    const float* g2[3] = {(const float*)d_in[7], (const float*)d_in[14], (const float*)d_in[21]};
    const float* b2[3] = {(const float*)d_in[8], (const float*)d_in[15], (const float*)d_in[22]};
    const float* gbn[2] = {(const float*)d_in[23], (const float*)d_in[25]};
    const float* bbn[2] = {(const float*)d_in[24], (const float*)d_in[26]};
    const float* Wm1 = (const float*)d_in[27];
    const float* bm1 = (const float*)d_in[28];
    const float* Wm2 = (const float*)d_in[29];
    const float* bm2 = (const float*)d_in[30];

    // workspace layout (floats)
    float* wsf  = (float*)d_ws;
    float* hbuf = wsf;                          // N*256
    float* sbuf = hbuf + (size_t)NN * DD;       // N*256
    float* y1   = sbuf + (size_t)NN * DD;       // N*64
    float* y2   = y1 + (size_t)NN * 64;         // N*64 (reused as Wpb)
    float* agg  = y2 + (size_t)NN * 64;         // N*64
    float* sm   = agg + (size_t)NN * 64;        // small scratch region
    float* y1s  = sm;             // 384
    float* y2s  = sm + 384;       // 384
    float* hs   = sm + 768;       // 1024
    float* a1p  = sm + 1792;      // 64
    float* c1p  = sm + 1856;      // 64
    float* b2f  = sm + 1920;      // 64
    short* w2h  = (short*)(sm + 1984);   // 4096 shorts
    short* w2l  = (short*)(sm + 4032);   // 4096 shorts
    int* ibase   = (int*)(sm + 6080);
    int* deg     = ibase;                 // NN
    int* rowptr  = deg + NN;              // NN+1
    int* cursor  = rowptr + NN + 1;       // NN
    int* bsum    = cursor + NN;           // 256
    int* csr_src = bsum + 256;            // EE
    int  ioff    = ((NN * 3 + 1 + 256 + EE) + 7) & ~7;
    short* wm1h  = (short*)(ibase + ioff);     // 65536 shorts
    short* wm1l  = wm1h + 65536;               // 65536 shorts
    short* w1h   = wm1l + 65536;               // 3 * 16384 shorts
    short* w1l   = w1h + 3 * 16384;            // 3 * 16384 shorts

    const dim3 blk(256);
    const float invN = 1.0f / NN;
    const int nb = (NN + 63) / 64;     // 469
    const int nbf = (NN + 127) / 128;  // 235 (fog BM=128, one round per CU)
    const int nb2 = (NN + 255) / 256;  // 118
    const int nbe = (EE + 255) / 256;  // 3750

    hipMemsetAsync(sm, 0, 1792 * sizeof(float), stream);   // all stats accumulators
    conv_wm1<<<32, blk, 0, stream>>>(Wm1, wm1h, wm1l);
    conv_w64_3<<<20, blk, 0, stream>>>(W1[0], W1[1], W1[2],
                                       w1h, w1l,
                                       w1h + 16384, w1l + 16384,
                                       w1h + 32768, w1l + 32768);

    // ---- CSR build (once; reused by all 3 layers) ----
    hipMemsetAsync(deg, 0, NN * sizeof(int), stream);
    hist_deg<<<nbe, blk, 0, stream>>>(dst, deg);
    scan1<<<nb2, blk, 0, stream>>>(deg, rowptr, bsum);
    scan2<<<1, blk, 0, stream>>>(bsum, rowptr, nb2);
    scan3<<<nb2, blk, 0, stream>>>(rowptr, bsum, cursor);
    fill_csr<<<nbe, blk, 0, stream>>>(src, dst, cursor, csr_src);

    for (int l = 0; l < 3; ++l) {
        const float* xin = (l == 0) ? x : hbuf;
        int cin = (l == 0) ? IN_ : DD;
        float* sO = (l == 0) ? nullptr : sbuf;
        int smode = (l == 0) ? 0 : ((l == 1) ? 1 : 2);
        const float* pim = (l == 0) ? nullptr : hs + (l - 1) * 512;
        const float* piq = (l == 0) ? nullptr : hs + (l - 1) * 512 + 256;
        const float* pig = (l == 0) ? nullptr : gbn[l - 1];
        const float* pib = (l == 0) ? nullptr : bbn[l - 1];

        gemm64_mfma<<<nb, blk, 0, stream>>>(xin, cin, w1h + l * 16384, w1l + l * 16384,
                                            nullptr, y1, NN,
                                            y1s + l * 128, y1s + l * 128 + 64,
                                            pim, piq, pig, pib, sO, smode, invN);
        fold_bn1_w2<<<1, 64, 0, stream>>>(y1s + l * 128, y1s + l * 128 + 64,
                                          g1[l], b1[l], a1p, c1p,
                                          W2[l], w2h, w2l, b2f, invN);

        gemm64_mfma<<<nb, blk, 0, stream>>>(y1, 64, w2h, w2l, b2f, y2, NN,
                                            y2s + l * 128, y2s + l * 128 + 64,
                                            nullptr, nullptr, nullptr, nullptr,
                                            nullptr, 0, invN);

        gather_agg<<<(NN + 3) / 4, blk, 0, stream>>>(rowptr, csr_src, y2,
                                                     y2s + l * 128, y2s + l * 128 + 64,
                                                     g2[l], b2[l], agg, invN);

        short* Wpb = (short*)y2;
        conv_wp<<<512, blk, 0, stream>>>(Wp[l], Wpb);

        bool st = (l < 2);
        fog_mfma<<<dim3(nbf), dim3(512), 0, stream>>>(y1, a1p, c1p, agg, Wpb, hbuf, NN,
                                                      st ? hs + l * 512 : nullptr,
                                                      st ? hs + l * 512 + 256 : nullptr,
                                                      st ? nullptr : sbuf);
    }

    // fused MLP head + log-softmax
    head_lsm<<<nb, dim3(512), 0, stream>>>(sbuf, wm1h, wm1l, bm1, Wm2, bm2,
                                           (float*)d_out, NN);
}

// Round 19
// 603.827 us; speedup vs baseline: 1.0410x; 1.0410x over previous
//
#include <hip/hip_runtime.h>
#include <hip/hip_bf16.h>
#include <math.h>

#define NN 30000
#define EE 960000
#define IN_ 128
#define DD 256
#define CC 40
#define EPS 1e-5f

typedef short bf8 __attribute__((ext_vector_type(8)));    // 8 bf16 (4 VGPRs)
typedef float f32x4 __attribute__((ext_vector_type(4)));

__device__ inline short f2bf(float x) {
    unsigned u = __float_as_uint(x);
    unsigned r = (u + 0x7fffu + ((u >> 16) & 1u)) >> 16;   // RNE
    return (short)r;
}

__device__ inline unsigned pk2(float lo, float hi) {
    __hip_bfloat162 h = __float22bfloat162_rn(make_float2(lo, hi));
    return *reinterpret_cast<unsigned*>(&h);
}

// split 8 f32 into bf16 hi + bf16 lo(residual) fragments
__device__ inline void split8(float4 f0, float4 f1, bf8* h, bf8* l) {
    unsigned h0 = pk2(f0.x, f0.y), h1 = pk2(f0.z, f0.w);
    unsigned h2 = pk2(f1.x, f1.y), h3 = pk2(f1.z, f1.w);
    float e0 = f0.x - __uint_as_float(h0 << 16);
    float e1 = f0.y - __uint_as_float(h0 & 0xFFFF0000u);
    float e2 = f0.z - __uint_as_float(h1 << 16);
    float e3 = f0.w - __uint_as_float(h1 & 0xFFFF0000u);
    float e4 = f1.x - __uint_as_float(h2 << 16);
    float e5 = f1.y - __uint_as_float(h2 & 0xFFFF0000u);
    float e6 = f1.z - __uint_as_float(h3 << 16);
    float e7 = f1.w - __uint_as_float(h3 & 0xFFFF0000u);
    uint4 hu = make_uint4(h0, h1, h2, h3);
    uint4 lu = make_uint4(pk2(e0, e1), pk2(e2, e3), pk2(e4, e5), pk2(e6, e7));
    *h = *(bf8*)&hu;
    *l = *(bf8*)&lu;
}

// ---------------------------------------------------------------------------
// Small GEMM via bf16x3 split MFMA (y1 layers). Optional in-block BN fold of
// the INPUT from raw stats (isum/isq + ig/ib -> relu(a*x+c); K==256 in that
// mode) with JK-sum write (smode 1: sOut=a, 2: sOut+=a). Per-col output
// sum/sumsq stats.
// ---------------------------------------------------------------------------
__global__ __launch_bounds__(256) void gemm64_mfma(
    const float* __restrict__ A, int K,
    const short* __restrict__ Whi, const short* __restrict__ Wlo,
    const float* __restrict__ bias,
    float* __restrict__ Y, int Nrows,
    float* __restrict__ osum, float* __restrict__ osq,
    const float* __restrict__ isum, const float* __restrict__ isq,
    const float* __restrict__ ig, const float* __restrict__ ib,
    float* __restrict__ sOut, int smode, float invN)
{
    __shared__ float redS[4][64], redQ[4][64];
    __shared__ float ah_s[256], ch_s[256];
    const int t = threadIdx.x;
    if (isum) {   // K==256 in this mode; 256 threads each fold one column
        float m = isum[t] * invN;
        float vv = isq[t] * invN - m * m;
        float s = ig[t] * rsqrtf(vv + EPS);
        ah_s[t] = s;
        ch_s[t] = ib[t] - m * s;
        __syncthreads();
    }
    const int lane = t & 63;
    const int w = t >> 6;
    const int l15 = lane & 15, l4 = (lane >> 4) & 3;
    const int row0 = blockIdx.x * 64 + w * 16;
    const bf8* whi = (const bf8*)Whi;
    const bf8* wlo = (const bf8*)Wlo;

    f32x4 acc[4] = {};
    const int nst = K >> 5;
    const int nA = row0 + l15;
    const bool valA = nA < Nrows;

#pragma unroll 2
    for (int ks = 0; ks < nst; ++ks) {
        int k0 = ks * 32 + l4 * 8;
        float4 f0, f1;
        if (valA) {
            const float* p = &A[(size_t)nA * K + k0];
            f0 = *(const float4*)p;
            f1 = *(const float4*)(p + 4);
        } else {
            f0 = make_float4(0.f, 0.f, 0.f, 0.f);
            f1 = f0;
        }
        if (isum) {
            float4 a4 = *(const float4*)&ah_s[k0], a5 = *(const float4*)&ah_s[k0 + 4];
            float4 c4 = *(const float4*)&ch_s[k0], c5 = *(const float4*)&ch_s[k0 + 4];
            f0.x = fmaxf(a4.x * f0.x + c4.x, 0.f);
            f0.y = fmaxf(a4.y * f0.y + c4.y, 0.f);
            f0.z = fmaxf(a4.z * f0.z + c4.z, 0.f);
            f0.w = fmaxf(a4.w * f0.w + c4.w, 0.f);
            f1.x = fmaxf(a5.x * f1.x + c5.x, 0.f);
            f1.y = fmaxf(a5.y * f1.y + c5.y, 0.f);
            f1.z = fmaxf(a5.z * f1.z + c5.z, 0.f);
            f1.w = fmaxf(a5.w * f1.w + c5.w, 0.f);
            if (valA) {
                float* sp = &sOut[(size_t)nA * K + k0];
                if (smode == 1) {
                    *(float4*)sp = f0;
                    *(float4*)(sp + 4) = f1;
                } else {
                    float4 s0 = *(const float4*)sp, s1 = *(const float4*)(sp + 4);
                    s0.x += f0.x; s0.y += f0.y; s0.z += f0.z; s0.w += f0.w;
                    s1.x += f1.x; s1.y += f1.y; s1.z += f1.z; s1.w += f1.w;
                    *(float4*)sp = s0;
                    *(float4*)(sp + 4) = s1;
                }
            }
        }
        bf8 ah, al;
        split8(f0, f1, &ah, &al);
        bf8 bh[4], bl[4];
#pragma unroll
        for (int nr = 0; nr < 4; ++nr) {
            int idx = (ks * 4 + nr) * 64 + lane;
            bh[nr] = whi[idx];
            bl[nr] = wlo[idx];
        }
#pragma unroll
        for (int nr = 0; nr < 4; ++nr) {
            acc[nr] = __builtin_amdgcn_mfma_f32_16x16x32_bf16(ah, bh[nr], acc[nr], 0, 0, 0);
            acc[nr] = __builtin_amdgcn_mfma_f32_16x16x32_bf16(ah, bl[nr], acc[nr], 0, 0, 0);
            acc[nr] = __builtin_amdgcn_mfma_f32_16x16x32_bf16(al, bh[nr], acc[nr], 0, 0, 0);
        }
    }

    float cs[4] = {}, cq[4] = {};
#pragma unroll
    for (int nr = 0; nr < 4; ++nr) {
#pragma unroll
        for (int r = 0; r < 4; ++r) {
            int n = row0 + l4 * 4 + r;
            float v = acc[nr][r];
            if (bias) v += bias[nr * 16 + l15];
            v = (v > 0.f) ? v : 0.01f * v;
            if (n < Nrows) {
                Y[(size_t)n * 64 + nr * 16 + l15] = v;
                cs[nr] += v;
                cq[nr] += v * v;
            }
        }
    }
#pragma unroll
    for (int nr = 0; nr < 4; ++nr) {
        float s1 = cs[nr], s2 = cq[nr];
        s1 += __shfl_down(s1, 32);
        s2 += __shfl_down(s2, 32);
        s1 += __shfl_down(s1, 16);
        s2 += __shfl_down(s2, 16);
        if (lane < 16) {
            redS[w][nr * 16 + l15] = s1;
            redQ[w][nr * 16 + l15] = s2;
        }
    }
    __syncthreads();
    if (t < 64) {
        float s1 = redS[0][t] + redS[1][t] + redS[2][t] + redS[3][t];
        float s2 = redQ[0][t] + redQ[1][t] + redQ[2][t] + redQ[3][t];
        atomicAdd(&osum[t], s1);
        atomicAdd(&osq[t], s2);
    }
}

// ---------------------------------------------------------------------------
// y2 GEMM with IN-BLOCK BN1 fold + W2 fold: computes a1/c1 from y1 stats,
// builds b2f and bf16 hi/lo W2f fragments in LDS (identical FP expressions
// to the old fold_bn1_w2), then y2 = leaky(y1_bn @ W2f.T + b2f). K=64.
// Removes the single-block fold dispatch between the two GEMMs.
// ---------------------------------------------------------------------------
__global__ __launch_bounds__(256) void gemm64_w2(
    const float* __restrict__ A,          // y1 [N][64]
    const float* __restrict__ W2,         // [64][64] f32
    const float* __restrict__ isum, const float* __restrict__ isq,   // y1 stats
    const float* __restrict__ g1v, const float* __restrict__ b1v,
    float* __restrict__ Y, int Nrows,
    float* __restrict__ osum, float* __restrict__ osq, float invN)
{
    __shared__ float redS[4][64], redQ[4][64];
    __shared__ float as_[64], cs_[64], b2s[64];
    __shared__ __align__(16) short w2hs[4096], w2ls[4096];
    const int t = threadIdx.x;

    // fold BN1 from raw stats (identical expressions to fold_bn1_w2)
    if (t < 64) {
        float m = isum[t] * invN;
        float vv = isq[t] * invN - m * m;
        float s = g1v[t] * rsqrtf(vv + EPS);
        as_[t] = s;
        cs_[t] = b1v[t] - m * s;
    }
    __syncthreads();
    if (t < 64) {
        float bb = 0.f;
        for (int i = 0; i < 64; ++i) bb += W2[t * 64 + i] * cs_[i];
        b2s[t] = bb;
    }
    // build W2f bf16 hi/lo fragments (512 slots, 2 per thread)
    for (int slot = t; slot < 512; slot += 256) {
        int rep = slot >> 6, l = slot & 63;
        int cb = rep & 3, ks = rep >> 2;
        int col = cb * 16 + (l & 15);
        int k = ks * 32 + ((l >> 4) & 3) * 8;
        bf8 h, lo;
#pragma unroll
        for (int e = 0; e < 8; ++e) {
            float v = W2[col * 64 + k + e] * as_[k + e];
            short hb = f2bf(v);
            float hf = __uint_as_float(((unsigned)(unsigned short)hb) << 16);
            h[e] = hb;
            lo[e] = f2bf(v - hf);
        }
        ((bf8*)w2hs)[slot] = h;
        ((bf8*)w2ls)[slot] = lo;
    }
    __syncthreads();

    const int lane = t & 63;
    const int w = t >> 6;
    const int l15 = lane & 15, l4 = (lane >> 4) & 3;
    const int row0 = blockIdx.x * 64 + w * 16;
    const bf8* whi = (const bf8*)w2hs;
    const bf8* wlo = (const bf8*)w2ls;

    f32x4 acc[4] = {};
    const int nA = row0 + l15;
    const bool valA = nA < Nrows;

#pragma unroll
    for (int ks = 0; ks < 2; ++ks) {
        int k0 = ks * 32 + l4 * 8;
        float4 f0, f1;
        if (valA) {
            const float* p = &A[(size_t)nA * 64 + k0];
            f0 = *(const float4*)p;
            f1 = *(const float4*)(p + 4);
        } else {
            f0 = make_float4(0.f, 0.f, 0.f, 0.f);
            f1 = f0;
        }
        bf8 ah, al;
        split8(f0, f1, &ah, &al);
        bf8 bh[4], bl[4];
#pragma unroll
        for (int nr = 0; nr < 4; ++nr) {
            int idx = (ks * 4 + nr) * 64 + lane;
            bh[nr] = whi[idx];
            bl[nr] = wlo[idx];
        }
#pragma unroll
        for (int nr = 0; nr < 4; ++nr) {
            acc[nr] = __builtin_amdgcn_mfma_f32_16x16x32_bf16(ah, bh[nr], acc[nr], 0, 0, 0);
            acc[nr] = __builtin_amdgcn_mfma_f32_16x16x32_bf16(ah, bl[nr], acc[nr], 0, 0, 0);
            acc[nr] = __builtin_amdgcn_mfma_f32_16x16x32_bf16(al, bh[nr], acc[nr], 0, 0, 0);
        }
    }

    float cs[4] = {}, cq[4] = {};
#pragma unroll
    for (int nr = 0; nr < 4; ++nr) {
#pragma unroll
        for (int r = 0; r < 4; ++r) {
            int n = row0 + l4 * 4 + r;
            float v = acc[nr][r] + b2s[nr * 16 + l15];
            v = (v > 0.f) ? v : 0.01f * v;
            if (n < Nrows) {
                Y[(size_t)n * 64 + nr * 16 + l15] = v;
                cs[nr] += v;
                cq[nr] += v * v;
            }
        }
    }
#pragma unroll
    for (int nr = 0; nr < 4; ++nr) {
        float s1 = cs[nr], s2 = cq[nr];
        s1 += __shfl_down(s1, 32);
        s2 += __shfl_down(s2, 32);
        s1 += __shfl_down(s1, 16);
        s2 += __shfl_down(s2, 16);
        if (lane < 16) {
            redS[w][nr * 16 + l15] = s1;
            redQ[w][nr * 16 + l15] = s2;
        }
    }
    __syncthreads();
    if (t < 64) {
        float s1 = redS[0][t] + redS[1][t] + redS[2][t] + redS[3][t];
        float s2 = redQ[0][t] + redQ[1][t] + redQ[2][t] + redQ[3][t];
        atomicAdd(&osum[t], s1);
        atomicAdd(&osq[t], s2);
    }
}

// ---------------------------------------------------------------------------
// Convert the three W1 weights ([64][K] f32) to bf16 hi/lo tiled frags, 1 launch.
// ---------------------------------------------------------------------------
__global__ void conv_w64_3(const float* __restrict__ W0, const float* __restrict__ Wa,
                           const float* __restrict__ Wb,
                           short* __restrict__ O0h, short* __restrict__ O0l,
                           short* __restrict__ O1h, short* __restrict__ O1l,
                           short* __restrict__ O2h, short* __restrict__ O2l)
{
    int tid = blockIdx.x * 256 + threadIdx.x;   // 1024 + 2048 + 2048 = 5120 frags
    const float* W; short* oh; short* ol; int K, f;
    if (tid < 1024)      { W = W0; oh = O0h; ol = O0l; K = 128; f = tid; }
    else if (tid < 3072) { W = Wa; oh = O1h; ol = O1l; K = 256; f = tid - 1024; }
    else if (tid < 5120) { W = Wb; oh = O2h; ol = O2l; K = 256; f = tid - 3072; }
    else return;
    int l = f & 63;
    int r = f >> 6;
    int cb = r & 3, ks = r >> 2;
    int col = cb * 16 + (l & 15);
    int k = ks * 32 + ((l >> 4) & 3) * 8;
    const float* src = W + (size_t)col * K + k;
    bf8 h, lo;
#pragma unroll
    for (int e = 0; e < 8; ++e) {
        float v = src[e];
        short hb = f2bf(v);
        float hf = __uint_as_float(((unsigned)(unsigned short)hb) << 16);
        h[e] = hb;
        lo[e] = f2bf(v - hf);
    }
    ((bf8*)oh)[f] = h;
    ((bf8*)ol)[f] = lo;
}

// ---------------------------------------------------------------------------
// Convert Wp (f32 [256][4096]) to bf16 pre-tiled in MFMA B-fragment order.
// ---------------------------------------------------------------------------
__global__ void conv_wp(const float* __restrict__ Wp, short* __restrict__ Wpb)
{
    int tid = blockIdx.x * 256 + threadIdx.x;   // 131072 threads
    int l = tid & 63;
    int r = tid >> 6;
    int jo = r & 1;
    int q = r >> 1;
    int cb = q & 15;
    int i = q >> 4;
    int col = cb * 16 + (l & 15);
    int k = i * 64 + jo * 32 + ((l >> 4) & 3) * 8;
    const float* src = Wp + (size_t)col * 4096 + k;
    bf8 v;
#pragma unroll
    for (int e = 0; e < 8; ++e) v[e] = f2bf(src[e]);
    ((bf8*)Wpb)[tid] = v;
}

// ---------------------------------------------------------------------------
// Convert Wm1 (f32 [256][256]) to bf16 hi/lo pre-tiled fragments (16 cb).
// ---------------------------------------------------------------------------
__global__ void conv_wm1(const float* __restrict__ W,
                         short* __restrict__ Whi, short* __restrict__ Wlo)
{
    int tid = blockIdx.x * 256 + threadIdx.x;   // 8192 threads
    int l = tid & 63;
    int f = tid >> 6;
    int cb = f & 15;
    int ks = f >> 4;
    int col = cb * 16 + (l & 15);
    int k = ks * 32 + ((l >> 4) & 3) * 8;
    const float* src = W + (size_t)col * 256 + k;
    bf8 h, lo;
#pragma unroll
    for (int e = 0; e < 8; ++e) {
        float v = src[e];
        short hb = f2bf(v);
        float hf = __uint_as_float(((unsigned)(unsigned short)hb) << 16);
        h[e] = hb;
        lo[e] = f2bf(v - hf);
    }
    ((bf8*)Whi)[tid] = h;
    ((bf8*)Wlo)[tid] = lo;
}

// ---------------------------------------------------------------------------
// MFMA big GEMM v9 (BM=128, one round per CU, lgkmcnt-only barrier) with
// IN-BLOCK BN1 fold prologue (a1/c1 from y1 stats; identical FP expressions).
// ---------------------------------------------------------------------------
#define FOG_BARRIER() asm volatile("s_waitcnt lgkmcnt(0)\n\ts_barrier" ::: "memory")

#define FOG_STEP(I, BUF, BU, BP)                                              \
  {                                                                           \
    bf8 af[4][2];                                                             \
    _Pragma("unroll")                                                         \
    for (int m = 0; m < 4; ++m) {                                             \
      _Pragma("unroll")                                                       \
      for (int jo = 0; jo < 2; ++jo) {                                        \
        int c = jo * 4 + l4;                                                  \
        int n = (mrb + m) * 16 + l15;                                         \
        af[m][jo] = *(const bf8*)&At[BUF][c][n ^ (c & 7)][0];                 \
      }                                                                       \
    }                                                                         \
    int inext = ((I) < 63) ? (I) + 1 : 63;                                    \
    _Pragma("unroll")                                                         \
    for (int nr = 0; nr < 4; ++nr) {                                          \
      _Pragma("unroll")                                                       \
      for (int jo = 0; jo < 2; ++jo)                                          \
        BP[nr][jo] = wp8[((inext * 16 + cbb + nr) * 2 + jo) * 64 + lane];     \
    }                                                                         \
    _Pragma("unroll")                                                         \
    for (int m = 0; m < 4; ++m) {                                             \
      _Pragma("unroll")                                                       \
      for (int nr = 0; nr < 4; ++nr) {                                        \
        acc[m][nr] = __builtin_amdgcn_mfma_f32_16x16x32_bf16(af[m][0], BU[nr][0], acc[m][nr], 0, 0, 0); \
        acc[m][nr] = __builtin_amdgcn_mfma_f32_16x16x32_bf16(af[m][1], BU[nr][1], acc[m][nr], 0, 0, 0); \
      }                                                                       \
    }                                                                         \
    if ((I) < 63) {                                                           \
      float xv = xd_s[nl][(I) + 1];                                           \
      uint4 q0, q1;                                                           \
      q0.x = pk2(xv * agr[0],  xv * agr[1]);                                  \
      q0.y = pk2(xv * agr[2],  xv * agr[3]);                                  \
      q0.z = pk2(xv * agr[4],  xv * agr[5]);                                  \
      q0.w = pk2(xv * agr[6],  xv * agr[7]);                                  \
      q1.x = pk2(xv * agr[8],  xv * agr[9]);                                  \
      q1.y = pk2(xv * agr[10], xv * agr[11]);                                 \
      q1.z = pk2(xv * agr[12], xv * agr[13]);                                 \
      q1.w = pk2(xv * agr[14], xv * agr[15]);                                 \
      *(uint4*)&At[(BUF) ^ 1][cA][nl ^ (cA & 7)][0] = q0;                     \
      *(uint4*)&At[(BUF) ^ 1][cB][nl ^ (cB & 7)][0] = q1;                     \
    }                                                                         \
    FOG_BARRIER();                                                            \
  }

__global__ __launch_bounds__(512, 2) void fog_mfma(
    const float* __restrict__ y1,
    const float* __restrict__ isum, const float* __restrict__ isq,   // y1 stats
    const float* __restrict__ g1v, const float* __restrict__ b1v,
    const float* __restrict__ agg, const short* __restrict__ Wpb,
    float* __restrict__ H, int Nrows,
    float* __restrict__ ssum, float* __restrict__ ssq,
    float* __restrict__ sjk, float invN)
{
    __shared__ float xd_s[128][68];
    __shared__ __align__(16) short At[2][8][128][8];  // [buf][chunk][node^chunk][8 bf16]
    __shared__ float a1s[64], c1s[64];
    const int t = threadIdx.x;          // 0..511
    const int lane = t & 63;
    const int w = t >> 6;               // wave 0..7
    const int nbase = blockIdx.x * 128;
    const int nl = t >> 2;              // staging node 0..127
    const int cA = (t & 3) * 2;         // staging j-chunks cA, cB
    const int cB = cA + 1;
    const int l15 = lane & 15;
    const int l4 = (lane >> 4) & 3;
    const int mrb = (w & 1) * 4;        // row 16-block base: 0 or 4
    const int cbb = (w >> 1) * 4;       // col 16-block base: 0,4,8,12

    // in-block BN1 fold (identical expressions to the old fold kernel)
    if (t < 64) {
        float m = isum[t] * invN;
        float vv = isq[t] * invN - m * m;
        float s = g1v[t] * rsqrtf(vv + EPS);
        a1s[t] = s;
        c1s[t] = b1v[t] - m * s;
    }
    __syncthreads();

    // stage xd (BN1-folded y1) into LDS; agg 16-value chunk into regs
    float agr[16];
    {
        int n = nbase + nl;
        bool valid = n < Nrows;
        const float* yr = y1 + (size_t)n * 64 + cA * 8;
        const float* ar = agg + (size_t)n * 64 + cA * 8;
#pragma unroll
        for (int u = 0; u < 16; u += 4) {
            float4 yv = valid ? *(const float4*)(yr + u) : make_float4(0.f, 0.f, 0.f, 0.f);
            float4 av = valid ? *(const float4*)(ar + u) : make_float4(0.f, 0.f, 0.f, 0.f);
            int j0 = cA * 8 + u;
            xd_s[nl][j0 + 0] = a1s[j0 + 0] * yv.x + c1s[j0 + 0];
            xd_s[nl][j0 + 1] = a1s[j0 + 1] * yv.y + c1s[j0 + 1];
            xd_s[nl][j0 + 2] = a1s[j0 + 2] * yv.z + c1s[j0 + 2];
            xd_s[nl][j0 + 3] = a1s[j0 + 3] * yv.w + c1s[j0 + 3];
            agr[u + 0] = av.x; agr[u + 1] = av.y; agr[u + 2] = av.z; agr[u + 3] = av.w;
        }
    }
    __syncthreads();

    const bf8* wp8 = (const bf8*)Wpb;
    // gen A(0) -> buf0 ; load B(0) -> bA
    {
        float xv = xd_s[nl][0];
        uint4 q0, q1;
        q0.x = pk2(xv * agr[0],  xv * agr[1]);
        q0.y = pk2(xv * agr[2],  xv * agr[3]);
        q0.z = pk2(xv * agr[4],  xv * agr[5]);
        q0.w = pk2(xv * agr[6],  xv * agr[7]);
        q1.x = pk2(xv * agr[8],  xv * agr[9]);
        q1.y = pk2(xv * agr[10], xv * agr[11]);
        q1.z = pk2(xv * agr[12], xv * agr[13]);
        q1.w = pk2(xv * agr[14], xv * agr[15]);
        *(uint4*)&At[0][cA][nl ^ (cA & 7)][0] = q0;
        *(uint4*)&At[0][cB][nl ^ (cB & 7)][0] = q1;
    }
    bf8 bA[4][2], bB[4][2];
#pragma unroll
    for (int nr = 0; nr < 4; ++nr)
#pragma unroll
        for (int jo = 0; jo < 2; ++jo)
            bA[nr][jo] = wp8[((cbb + nr) * 2 + jo) * 64 + lane];
    __syncthreads();

    f32x4 acc[4][4] = {};
    for (int i = 0; i < 64; i += 2) {
        FOG_STEP(i,     0, bA, bB);
        FOG_STEP(i + 1, 1, bB, bA);
    }

    if (ssum) {
        float cs[4] = {}, cq[4] = {};
#pragma unroll
        for (int m = 0; m < 4; ++m) {
#pragma unroll
            for (int r = 0; r < 4; ++r) {
                int n = nbase + (mrb + m) * 16 + l4 * 4 + r;
                if (n < Nrows) {
#pragma unroll
                    for (int nr = 0; nr < 4; ++nr) {
                        float v = acc[m][nr][r];
                        H[(size_t)n * 256 + (cbb + nr) * 16 + l15] = v;
                        cs[nr] += v;
                        cq[nr] += v * v;
                    }
                }
            }
        }
#pragma unroll
        for (int nr = 0; nr < 4; ++nr) {
            float s1 = cs[nr], s2 = cq[nr];
            s1 += __shfl_down(s1, 32);
            s2 += __shfl_down(s2, 32);
            s1 += __shfl_down(s1, 16);
            s2 += __shfl_down(s2, 16);
            if (l4 == 0 && lane < 16) {
                atomicAdd(&ssum[(cbb + nr) * 16 + l15], s1);
                atomicAdd(&ssq[(cbb + nr) * 16 + l15], s2);
            }
        }
    } else {
        // last layer: s += x3 fused (each (n,col) owned by exactly one thread)
#pragma unroll
        for (int m = 0; m < 4; ++m) {
#pragma unroll
            for (int r = 0; r < 4; ++r) {
                int n = nbase + (mrb + m) * 16 + l4 * 4 + r;
                if (n < Nrows) {
#pragma unroll
                    for (int nr = 0; nr < 4; ++nr) {
                        size_t idx = (size_t)n * 256 + (cbb + nr) * 16 + l15;
                        sjk[idx] += acc[m][nr][r];
                    }
                }
            }
        }
    }
}

// ---------------------------------------------------------------------------
// Fused MLP head: hid = relu(s @ Wm1.T + bm1) via bf16x3 MFMA (staged in LDS),
// then logits = hid @ Wm2.T + bm2 and row log_softmax -> out. One kernel.
// ---------------------------------------------------------------------------
__global__ __launch_bounds__(512) void head_lsm(
    const float* __restrict__ A,
    const short* __restrict__ Whi, const short* __restrict__ Wlo,
    const float* __restrict__ bias,
    const float* __restrict__ Wm2, const float* __restrict__ bm2,
    float* __restrict__ out, int Nrows)
{
    __shared__ float hid_s[64][257];
    __shared__ float Wl[40][257];
    __shared__ float bl[40];
    const int t = threadIdx.x;
    const int lane = t & 63;
    const int w = t >> 6;
    const int nbase = blockIdx.x * 64;
    const int l15 = lane & 15, l4 = (lane >> 4) & 3;
    const int mrb = (w & 1) * 32;
    const int cbb = (w >> 1) * 4;
    const bf8* whi = (const bf8*)Whi;
    const bf8* wlo = (const bf8*)Wlo;

    for (int e = t; e < 40 * 256; e += 512) Wl[e >> 8][e & 255] = Wm2[e];
    if (t < 40) bl[t] = bm2[t];

    f32x4 acc[2][4] = {};
#pragma unroll
    for (int ks = 0; ks < 8; ++ks) {
        bf8 ah[2], al[2];
#pragma unroll
        for (int m = 0; m < 2; ++m) {
            int n = nbase + mrb + m * 16 + l15;
            float4 f0, f1;
            if (n < Nrows) {
                const float* p = &A[(size_t)n * 256 + ks * 32 + l4 * 8];
                f0 = *(const float4*)p;
                f1 = *(const float4*)(p + 4);
            } else {
                f0 = make_float4(0.f, 0.f, 0.f, 0.f);
                f1 = f0;
            }
            split8(f0, f1, &ah[m], &al[m]);
        }
        bf8 bh[4], blw[4];
#pragma unroll
        for (int nr = 0; nr < 4; ++nr) {
            int idx = (ks * 16 + cbb + nr) * 64 + lane;
            bh[nr] = whi[idx];
            blw[nr] = wlo[idx];
        }
#pragma unroll
        for (int m = 0; m < 2; ++m)
#pragma unroll
            for (int nr = 0; nr < 4; ++nr) {
                acc[m][nr] = __builtin_amdgcn_mfma_f32_16x16x32_bf16(ah[m], bh[nr], acc[m][nr], 0, 0, 0);
                acc[m][nr] = __builtin_amdgcn_mfma_f32_16x16x32_bf16(ah[m], blw[nr], acc[m][nr], 0, 0, 0);
                acc[m][nr] = __builtin_amdgcn_mfma_f32_16x16x32_bf16(al[m], bh[nr], acc[m][nr], 0, 0, 0);
            }
    }

#pragma unroll
    for (int m = 0; m < 2; ++m) {
#pragma unroll
        for (int r = 0; r < 4; ++r) {
            int rl = mrb + m * 16 + l4 * 4 + r;   // local row 0..63
#pragma unroll
            for (int nr = 0; nr < 4; ++nr) {
                int col = (cbb + nr) * 16 + l15;
                float v = acc[m][nr][r] + bias[col];
                hid_s[rl][col] = fmaxf(v, 0.f);
            }
        }
    }
    __syncthreads();

    // log-softmax: 8 threads per node, 5 classes each
    int nl2 = t >> 3;
    int sub = t & 7;
    int node = nbase + nl2;
    if (node >= Nrows) return;

    float accl[5];
#pragma unroll
    for (int r = 0; r < 5; ++r) accl[r] = bl[sub * 5 + r];
    for (int k = 0; k < 256; k += 4) {
        float4 h4 = *(const float4*)&hid_s[nl2][k];
        float hv[4] = {h4.x, h4.y, h4.z, h4.w};
#pragma unroll
        for (int kk = 0; kk < 4; ++kk)
#pragma unroll
            for (int r = 0; r < 5; ++r)
                accl[r] += hv[kk] * Wl[sub * 5 + r][k + kk];
    }
    float mx = accl[0];
#pragma unroll
    for (int r = 1; r < 5; ++r) mx = fmaxf(mx, accl[r]);
    for (int off = 1; off < 8; off <<= 1) mx = fmaxf(mx, __shfl_xor(mx, off, 8));
    float se = 0.f;
#pragma unroll
    for (int r = 0; r < 5; ++r) se += expf(accl[r] - mx);
    for (int off = 1; off < 8; off <<= 1) se += __shfl_xor(se, off, 8);
    float lse = logf(se);
#pragma unroll
    for (int r = 0; r < 5; ++r)
        out[(size_t)node * 40 + sub * 5 + r] = accl[r] - mx - lse;
}

// ---------------------------------------------------------------------------
// CSR build: histogram of dst, prefix scan, fill src lists.
// ---------------------------------------------------------------------------
__global__ void hist_deg(const int* __restrict__ dst, int* __restrict__ deg)
{
    int e = blockIdx.x * 256 + threadIdx.x;
    if (e < EE) atomicAdd(&deg[dst[e]], 1);
}

__global__ void scan1(const int* __restrict__ deg, int* __restrict__ rowptr,
                      int* __restrict__ bsum)
{
    __shared__ int sh[256];
    int t = threadIdx.x;
    int i = blockIdx.x * 256 + t;
    int v = (i < NN) ? deg[i] : 0;
    sh[t] = v;
    __syncthreads();
    for (int off = 1; off < 256; off <<= 1) {
        int add = (t >= off) ? sh[t - off] : 0;
        __syncthreads();
        sh[t] += add;
        __syncthreads();
    }
    if (i < NN) rowptr[i] = sh[t] - v;          // exclusive
    if (t == 255) bsum[blockIdx.x] = sh[255];
}

__global__ void scan2(int* __restrict__ bsum, int* __restrict__ rowptr, int nb2)
{
    __shared__ int sh[256];
    int t = threadIdx.x;
    int v = (t < nb2) ? bsum[t] : 0;
    sh[t] = v;
    __syncthreads();
    for (int off = 1; off < 256; off <<= 1) {
        int add = (t >= off) ? sh[t - off] : 0;
        __syncthreads();
        sh[t] += add;
        __syncthreads();
    }
    if (t < nb2) bsum[t] = sh[t] - v;            // exclusive
    if (t == 0) rowptr[NN] = EE;
}

__global__ void scan3(int* __restrict__ rowptr, const int* __restrict__ bsum,
                      int* __restrict__ cursor)
{
    int i = blockIdx.x * 256 + threadIdx.x;
    if (i < NN) {
        int r = rowptr[i] + bsum[blockIdx.x];
        rowptr[i] = r;
        cursor[i] = r;
    }
}

__global__ void fill_csr(const int* __restrict__ src, const int* __restrict__ dst,
                         int* __restrict__ cursor, int* __restrict__ csr_src)
{
    int e = blockIdx.x * 256 + threadIdx.x;
    if (e < EE) {
        int p = atomicAdd(&cursor[dst[e]], 1);
        csr_src[p] = src[e];
    }
}

// ---------------------------------------------------------------------------
// Gather aggregation with in-block BN2 fold from raw y2 stats:
// agg[v] = a2 * (sum_{e: dst=v} y2[src_e]) + deg_v * c2.
// ONE WAVE per node: 4 edge-substreams x 16 chunk-lanes; 4 row-loads in
// flight per substream.
// ---------------------------------------------------------------------------
__global__ __launch_bounds__(256) void gather_agg(
    const int* __restrict__ rowptr, const int* __restrict__ csr_src,
    const float* __restrict__ y2,
    const float* __restrict__ isum, const float* __restrict__ isq,
    const float* __restrict__ g2, const float* __restrict__ b2,
    float* __restrict__ agg, float invN)
{
    __shared__ float a2s[64], c2s[64];
    int t = threadIdx.x;
    if (t < 64) {
        float m = isum[t] * invN;
        float vv = isq[t] * invN - m * m;
        float s = g2[t] * rsqrtf(vv + EPS);
        a2s[t] = s;
        c2s[t] = b2[t] - m * s;
    }
    __syncthreads();
    int g = t >> 6;              // node within block: 0..3 (one wave per node)
    int sub = (t >> 4) & 3;      // edge substream 0..3
    int l = t & 15;              // float4 chunk
    int v = blockIdx.x * 4 + g;
    if (v >= NN) return;
    int beg = rowptr[v], end = rowptr[v + 1];
    float ax0 = 0.f, ay0 = 0.f, az0 = 0.f, aw0 = 0.f;
    float ax1 = 0.f, ay1 = 0.f, az1 = 0.f, aw1 = 0.f;
    int k = beg + sub;
    for (; k + 12 < end; k += 16) {
        int s0 = csr_src[k], s1 = csr_src[k + 4];
        int s2 = csr_src[k + 8], s3 = csr_src[k + 12];
        float4 v0 = *(const float4*)&y2[(size_t)s0 * 64 + l * 4];
        float4 v1 = *(const float4*)&y2[(size_t)s1 * 64 + l * 4];
        float4 v2 = *(const float4*)&y2[(size_t)s2 * 64 + l * 4];
        float4 v3 = *(const float4*)&y2[(size_t)s3 * 64 + l * 4];
        ax0 += v0.x + v2.x; ay0 += v0.y + v2.y; az0 += v0.z + v2.z; aw0 += v0.w + v2.w;
        ax1 += v1.x + v3.x; ay1 += v1.y + v3.y; az1 += v1.z + v3.z; aw1 += v1.w + v3.w;
    }
    for (; k < end; k += 4) {
        int s = csr_src[k];
        float4 val = *(const float4*)&y2[(size_t)s * 64 + l * 4];
        ax0 += val.x; ay0 += val.y; az0 += val.z; aw0 += val.w;
    }
    float ax = ax0 + ax1, ay = ay0 + ay1, az = az0 + az1, aw = aw0 + aw1;
    ax += __shfl_down(ax, 32);
    ay += __shfl_down(ay, 32);
    az += __shfl_down(az, 32);
    aw += __shfl_down(aw, 32);
    ax += __shfl_down(ax, 16);
    ay += __shfl_down(ay, 16);
    az += __shfl_down(az, 16);
    aw += __shfl_down(aw, 16);
    if ((t & 63) < 16) {
        float dg = (float)(end - beg);
        float4 a4 = *(const float4*)&a2s[l * 4];
        float4 c4 = *(const float4*)&c2s[l * 4];
        float4 o;
        o.x = a4.x * ax + dg * c4.x;
        o.y = a4.y * ay + dg * c4.y;
        o.z = a4.z * az + dg * c4.z;
        o.w = a4.w * aw + dg * c4.w;
        *(float4*)&agg[(size_t)v * 64 + l * 4] = o;
    }
}

// ---------------------------------------------------------------------------
extern "C" void kernel_launch(void* const* d_in, const int* in_sizes, int n_in,
                              void* d_out, int out_size, void* d_ws, size_t ws_size,
                              hipStream_t stream)
{
    const float* x = (const float*)d_in[0];
    const int* ei = (const int*)d_in[1];
    const int* src = ei;          // row 0
    const int* dst = ei + EE;     // row 1
    const float* W1[3] = {(const float*)d_in[2], (const float*)d_in[9],  (const float*)d_in[16]};
    const float* W2[3] = {(const float*)d_in[3], (const float*)d_in[10], (const float*)d_in[17]};
    const float* Wp[3] = {(const float*)d_in[4], (const float*)d_in[11], (const float*)d_in[18]};
    const float* g1[3] = {(const float*)d_in[5], (const float*)d_in[12], (const float*)d_in[19]};
    const float* b1[3] = {(const float*)d_in[6], (const float*)d_in[13], (const float*)d_in[20]};
    const float* g2[3] = {(const float*)d_in[7], (const float*)d_in[14], (const float*)d_in[21]};
    const float* b2[3] = {(const float*)d_in[8], (const float*)d_in[15], (const float*)d_in[22]};
    const float* gbn[2] = {(const float*)d_in[23], (const float*)d_in[25]};
    const float* bbn[2] = {(const float*)d_in[24], (const float*)d_in[26]};
    const float* Wm1 = (const float*)d_in[27];
    const float* bm1 = (const float*)d_in[28];
    const float* Wm2 = (const float*)d_in[29];
    const float* bm2 = (const float*)d_in[30];

    // workspace layout (floats)
    float* wsf  = (float*)d_ws;
    float* hbuf = wsf;                          // N*256
    float* sbuf = hbuf + (size_t)NN * DD;       // N*256
    float* y1   = sbuf + (size_t)NN * DD;       // N*64
    float* y2   = y1 + (size_t)NN * 64;         // N*64 (reused as Wpb)
    float* agg  = y2 + (size_t)NN * 64;         // N*64
    float* sm   = agg + (size_t)NN * 64;        // small scratch region
    float* y1s  = sm;             // 384
    float* y2s  = sm + 384;       // 384
    float* hs   = sm + 768;       // 1024
    int* ibase   = (int*)(sm + 6080);
    int* deg     = ibase;                 // NN
    int* rowptr  = deg + NN;              // NN+1
    int* cursor  = rowptr + NN + 1;       // NN
    int* bsum    = cursor + NN;           // 256
    int* csr_src = bsum + 256;            // EE
    int  ioff    = ((NN * 3 + 1 + 256 + EE) + 7) & ~7;
    short* wm1h  = (short*)(ibase + ioff);     // 65536 shorts
    short* wm1l  = wm1h + 65536;               // 65536 shorts
    short* w1h   = wm1l + 65536;               // 3 * 16384 shorts
    short* w1l   = w1h + 3 * 16384;            // 3 * 16384 shorts

    const dim3 blk(256);
    const float invN = 1.0f / NN;
    const int nb = (NN + 63) / 64;     // 469
    const int nbf = (NN + 127) / 128;  // 235 (fog BM=128, one round per CU)
    const int nb2 = (NN + 255) / 256;  // 118
    const int nbe = (EE + 255) / 256;  // 3750

    hipMemsetAsync(sm, 0, 1792 * sizeof(float), stream);   // all stats accumulators
    conv_wm1<<<32, blk, 0, stream>>>(Wm1, wm1h, wm1l);
    conv_w64_3<<<20, blk, 0, stream>>>(W1[0], W1[1], W1[2],
                                       w1h, w1l,
                                       w1h + 16384, w1l + 16384,
                                       w1h + 32768, w1l + 32768);

    // ---- CSR build (once; reused by all 3 layers) ----
    hipMemsetAsync(deg, 0, NN * sizeof(int), stream);
    hist_deg<<<nbe, blk, 0, stream>>>(dst, deg);
    scan1<<<nb2, blk, 0, stream>>>(deg, rowptr, bsum);
    scan2<<<1, blk, 0, stream>>>(bsum, rowptr, nb2);
    scan3<<<nb2, blk, 0, stream>>>(rowptr, bsum, cursor);
    fill_csr<<<nbe, blk, 0, stream>>>(src, dst, cursor, csr_src);

    for (int l = 0; l < 3; ++l) {
        const float* xin = (l == 0) ? x : hbuf;
        int cin = (l == 0) ? IN_ : DD;
        float* sO = (l == 0) ? nullptr : sbuf;
        int smode = (l == 0) ? 0 : ((l == 1) ? 1 : 2);
        const float* pim = (l == 0) ? nullptr : hs + (l - 1) * 512;
        const float* piq = (l == 0) ? nullptr : hs + (l - 1) * 512 + 256;
        const float* pig = (l == 0) ? nullptr : gbn[l - 1];
        const float* pib = (l == 0) ? nullptr : bbn[l - 1];

        // y1 = leaky(xin' @ W1.T)  with fused prev-H BN+ReLU + JK-sum write
        gemm64_mfma<<<nb, blk, 0, stream>>>(xin, cin, w1h + l * 16384, w1l + l * 16384,
                                            nullptr, y1, NN,
                                            y1s + l * 128, y1s + l * 128 + 64,
                                            pim, piq, pig, pib, sO, smode, invN);

        // y2 = leaky(y1_bn @ W2f.T + b2f)  with in-block BN1+W2 fold
        gemm64_w2<<<nb, blk, 0, stream>>>(y1, W2[l],
                                          y1s + l * 128, y1s + l * 128 + 64,
                                          g1[l], b1[l], y2, NN,
                                          y2s + l * 128, y2s + l * 128 + 64, invN);

        // agg with in-block BN2 fold from y2 stats
        gather_agg<<<(NN + 3) / 4, blk, 0, stream>>>(rowptr, csr_src, y2,
                                                     y2s + l * 128, y2s + l * 128 + 64,
                                                     g2[l], b2[l], agg, invN);

        // y2 dead after gather -> reuse for pre-tiled bf16 Wp
        short* Wpb = (short*)y2;
        conv_wp<<<512, blk, 0, stream>>>(Wp[l], Wpb);

        bool st = (l < 2);
        fog_mfma<<<dim3(nbf), dim3(512), 0, stream>>>(y1,
                                                      y1s + l * 128, y1s + l * 128 + 64,
                                                      g1[l], b1[l],
                                                      agg, Wpb, hbuf, NN,
                                                      st ? hs + l * 512 : nullptr,
                                                      st ? hs + l * 512 + 256 : nullptr,
                                                      st ? nullptr : sbuf, invN);
    }

    // fused MLP head + log-softmax
    head_lsm<<<nb, dim3(512), 0, stream>>>(sbuf, wm1h, wm1l, bm1, Wm2, bm2,
                                           (float*)d_out, NN);
}

// Round 20
// 602.238 us; speedup vs baseline: 1.0437x; 1.0026x over previous
//
#include <hip/hip_runtime.h>
#include <hip/hip_bf16.h>
#include <math.h>

#define NN 30000
#define EE 960000
#define IN_ 128
#define DD 256
#define CC 40
#define EPS 1e-5f

typedef short bf8 __attribute__((ext_vector_type(8)));    // 8 bf16 (4 VGPRs)
typedef float f32x4 __attribute__((ext_vector_type(4)));

__device__ inline short f2bf(float x) {
    unsigned u = __float_as_uint(x);
    unsigned r = (u + 0x7fffu + ((u >> 16) & 1u)) >> 16;   // RNE
    return (short)r;
}

__device__ inline unsigned pk2(float lo, float hi) {
    __hip_bfloat162 h = __float22bfloat162_rn(make_float2(lo, hi));
    return *reinterpret_cast<unsigned*>(&h);
}

// split 8 f32 into bf16 hi + bf16 lo(residual) fragments
__device__ inline void split8(float4 f0, float4 f1, bf8* h, bf8* l) {
    unsigned h0 = pk2(f0.x, f0.y), h1 = pk2(f0.z, f0.w);
    unsigned h2 = pk2(f1.x, f1.y), h3 = pk2(f1.z, f1.w);
    float e0 = f0.x - __uint_as_float(h0 << 16);
    float e1 = f0.y - __uint_as_float(h0 & 0xFFFF0000u);
    float e2 = f0.z - __uint_as_float(h1 << 16);
    float e3 = f0.w - __uint_as_float(h1 & 0xFFFF0000u);
    float e4 = f1.x - __uint_as_float(h2 << 16);
    float e5 = f1.y - __uint_as_float(h2 & 0xFFFF0000u);
    float e6 = f1.z - __uint_as_float(h3 << 16);
    float e7 = f1.w - __uint_as_float(h3 & 0xFFFF0000u);
    uint4 hu = make_uint4(h0, h1, h2, h3);
    uint4 lu = make_uint4(pk2(e0, e1), pk2(e2, e3), pk2(e4, e5), pk2(e6, e7));
    *h = *(bf8*)&hu;
    *l = *(bf8*)&lu;
}

// ---------------------------------------------------------------------------
// Small GEMM via bf16x3 split MFMA (y1 layers). Optional in-block BN fold of
// the INPUT from raw stats (isum/isq + ig/ib -> relu(a*x+c); K==256 in that
// mode) with JK-sum write (smode 1: sOut=a, 2: sOut+=a). Per-col output
// sum/sumsq stats.
// ---------------------------------------------------------------------------
__global__ __launch_bounds__(256) void gemm64_mfma(
    const float* __restrict__ A, int K,
    const short* __restrict__ Whi, const short* __restrict__ Wlo,
    const float* __restrict__ bias,
    float* __restrict__ Y, int Nrows,
    float* __restrict__ osum, float* __restrict__ osq,
    const float* __restrict__ isum, const float* __restrict__ isq,
    const float* __restrict__ ig, const float* __restrict__ ib,
    float* __restrict__ sOut, int smode, float invN)
{
    __shared__ float redS[4][64], redQ[4][64];
    __shared__ float ah_s[256], ch_s[256];
    const int t = threadIdx.x;
    if (isum) {   // K==256 in this mode; 256 threads each fold one column
        float m = isum[t] * invN;
        float vv = isq[t] * invN - m * m;
        float s = ig[t] * rsqrtf(vv + EPS);
        ah_s[t] = s;
        ch_s[t] = ib[t] - m * s;
        __syncthreads();
    }
    const int lane = t & 63;
    const int w = t >> 6;
    const int l15 = lane & 15, l4 = (lane >> 4) & 3;
    const int row0 = blockIdx.x * 64 + w * 16;
    const bf8* whi = (const bf8*)Whi;
    const bf8* wlo = (const bf8*)Wlo;

    f32x4 acc[4] = {};
    const int nst = K >> 5;
    const int nA = row0 + l15;
    const bool valA = nA < Nrows;

#pragma unroll 2
    for (int ks = 0; ks < nst; ++ks) {
        int k0 = ks * 32 + l4 * 8;
        float4 f0, f1;
        if (valA) {
            const float* p = &A[(size_t)nA * K + k0];
            f0 = *(const float4*)p;
            f1 = *(const float4*)(p + 4);
        } else {
            f0 = make_float4(0.f, 0.f, 0.f, 0.f);
            f1 = f0;
        }
        if (isum) {
            float4 a4 = *(const float4*)&ah_s[k0], a5 = *(const float4*)&ah_s[k0 + 4];
            float4 c4 = *(const float4*)&ch_s[k0], c5 = *(const float4*)&ch_s[k0 + 4];
            f0.x = fmaxf(a4.x * f0.x + c4.x, 0.f);
            f0.y = fmaxf(a4.y * f0.y + c4.y, 0.f);
            f0.z = fmaxf(a4.z * f0.z + c4.z, 0.f);
            f0.w = fmaxf(a4.w * f0.w + c4.w, 0.f);
            f1.x = fmaxf(a5.x * f1.x + c5.x, 0.f);
            f1.y = fmaxf(a5.y * f1.y + c5.y, 0.f);
            f1.z = fmaxf(a5.z * f1.z + c5.z, 0.f);
            f1.w = fmaxf(a5.w * f1.w + c5.w, 0.f);
            if (valA) {
                float* sp = &sOut[(size_t)nA * K + k0];
                if (smode == 1) {
                    *(float4*)sp = f0;
                    *(float4*)(sp + 4) = f1;
                } else {
                    float4 s0 = *(const float4*)sp, s1 = *(const float4*)(sp + 4);
                    s0.x += f0.x; s0.y += f0.y; s0.z += f0.z; s0.w += f0.w;
                    s1.x += f1.x; s1.y += f1.y; s1.z += f1.z; s1.w += f1.w;
                    *(float4*)sp = s0;
                    *(float4*)(sp + 4) = s1;
                }
            }
        }
        bf8 ah, al;
        split8(f0, f1, &ah, &al);
        bf8 bh[4], bl[4];
#pragma unroll
        for (int nr = 0; nr < 4; ++nr) {
            int idx = (ks * 4 + nr) * 64 + lane;
            bh[nr] = whi[idx];
            bl[nr] = wlo[idx];
        }
#pragma unroll
        for (int nr = 0; nr < 4; ++nr) {
            acc[nr] = __builtin_amdgcn_mfma_f32_16x16x32_bf16(ah, bh[nr], acc[nr], 0, 0, 0);
            acc[nr] = __builtin_amdgcn_mfma_f32_16x16x32_bf16(ah, bl[nr], acc[nr], 0, 0, 0);
            acc[nr] = __builtin_amdgcn_mfma_f32_16x16x32_bf16(al, bh[nr], acc[nr], 0, 0, 0);
        }
    }

    float cs[4] = {}, cq[4] = {};
#pragma unroll
    for (int nr = 0; nr < 4; ++nr) {
#pragma unroll
        for (int r = 0; r < 4; ++r) {
            int n = row0 + l4 * 4 + r;
            float v = acc[nr][r];
            if (bias) v += bias[nr * 16 + l15];
            v = (v > 0.f) ? v : 0.01f * v;
            if (n < Nrows) {
                Y[(size_t)n * 64 + nr * 16 + l15] = v;
                cs[nr] += v;
                cq[nr] += v * v;
            }
        }
    }
#pragma unroll
    for (int nr = 0; nr < 4; ++nr) {
        float s1 = cs[nr], s2 = cq[nr];
        s1 += __shfl_down(s1, 32);
        s2 += __shfl_down(s2, 32);
        s1 += __shfl_down(s1, 16);
        s2 += __shfl_down(s2, 16);
        if (lane < 16) {
            redS[w][nr * 16 + l15] = s1;
            redQ[w][nr * 16 + l15] = s2;
        }
    }
    __syncthreads();
    if (t < 64) {
        float s1 = redS[0][t] + redS[1][t] + redS[2][t] + redS[3][t];
        float s2 = redQ[0][t] + redQ[1][t] + redQ[2][t] + redQ[3][t];
        atomicAdd(&osum[t], s1);
        atomicAdd(&osq[t], s2);
    }
}

// ---------------------------------------------------------------------------
// y2 GEMM with IN-BLOCK BN1 fold + W2 fold (blocks < nbG), PLUS fused Wp
// bf16 conversion (blocks >= nbG do conv_wp's work into the dedicated Wpb
// buffer -- data-independent, runs concurrently instead of serializing
// between gather and fog).
// ---------------------------------------------------------------------------
__global__ __launch_bounds__(256) void gemm64_w2(
    const float* __restrict__ A,          // y1 [N][64]
    const float* __restrict__ W2,         // [64][64] f32
    const float* __restrict__ isum, const float* __restrict__ isq,   // y1 stats
    const float* __restrict__ g1v, const float* __restrict__ b1v,
    float* __restrict__ Y, int Nrows,
    float* __restrict__ osum, float* __restrict__ osq, float invN,
    const float* __restrict__ Wp, short* __restrict__ Wpb, int nbG)
{
    if (blockIdx.x >= nbG) {
        // conv_wp: convert Wp (f32 [256][4096]) to bf16 pre-tiled fragments
        int tid = (blockIdx.x - nbG) * 256 + threadIdx.x;   // 131072 threads
        int l = tid & 63;
        int r = tid >> 6;
        int jo = r & 1;
        int q = r >> 1;
        int cb = q & 15;
        int i = q >> 4;
        int col = cb * 16 + (l & 15);
        int k = i * 64 + jo * 32 + ((l >> 4) & 3) * 8;
        const float* srcp = Wp + (size_t)col * 4096 + k;
        bf8 v;
#pragma unroll
        for (int e = 0; e < 8; ++e) v[e] = f2bf(srcp[e]);
        ((bf8*)Wpb)[tid] = v;
        return;
    }

    __shared__ float redS[4][64], redQ[4][64];
    __shared__ float as_[64], cs_[64], b2s[64];
    __shared__ __align__(16) short w2hs[4096], w2ls[4096];
    const int t = threadIdx.x;

    // fold BN1 from raw stats (identical expressions to fold_bn1_w2)
    if (t < 64) {
        float m = isum[t] * invN;
        float vv = isq[t] * invN - m * m;
        float s = g1v[t] * rsqrtf(vv + EPS);
        as_[t] = s;
        cs_[t] = b1v[t] - m * s;
    }
    __syncthreads();
    if (t < 64) {
        float bb = 0.f;
        for (int i = 0; i < 64; ++i) bb += W2[t * 64 + i] * cs_[i];
        b2s[t] = bb;
    }
    // build W2f bf16 hi/lo fragments (512 slots, 2 per thread)
    for (int slot = t; slot < 512; slot += 256) {
        int rep = slot >> 6, l = slot & 63;
        int cb = rep & 3, ks = rep >> 2;
        int col = cb * 16 + (l & 15);
        int k = ks * 32 + ((l >> 4) & 3) * 8;
        bf8 h, lo;
#pragma unroll
        for (int e = 0; e < 8; ++e) {
            float v = W2[col * 64 + k + e] * as_[k + e];
            short hb = f2bf(v);
            float hf = __uint_as_float(((unsigned)(unsigned short)hb) << 16);
            h[e] = hb;
            lo[e] = f2bf(v - hf);
        }
        ((bf8*)w2hs)[slot] = h;
        ((bf8*)w2ls)[slot] = lo;
    }
    __syncthreads();

    const int lane = t & 63;
    const int w = t >> 6;
    const int l15 = lane & 15, l4 = (lane >> 4) & 3;
    const int row0 = blockIdx.x * 64 + w * 16;
    const bf8* whi = (const bf8*)w2hs;
    const bf8* wlo = (const bf8*)w2ls;

    f32x4 acc[4] = {};
    const int nA = row0 + l15;
    const bool valA = nA < Nrows;

#pragma unroll
    for (int ks = 0; ks < 2; ++ks) {
        int k0 = ks * 32 + l4 * 8;
        float4 f0, f1;
        if (valA) {
            const float* p = &A[(size_t)nA * 64 + k0];
            f0 = *(const float4*)p;
            f1 = *(const float4*)(p + 4);
        } else {
            f0 = make_float4(0.f, 0.f, 0.f, 0.f);
            f1 = f0;
        }
        bf8 ah, al;
        split8(f0, f1, &ah, &al);
        bf8 bh[4], bl[4];
#pragma unroll
        for (int nr = 0; nr < 4; ++nr) {
            int idx = (ks * 4 + nr) * 64 + lane;
            bh[nr] = whi[idx];
            bl[nr] = wlo[idx];
        }
#pragma unroll
        for (int nr = 0; nr < 4; ++nr) {
            acc[nr] = __builtin_amdgcn_mfma_f32_16x16x32_bf16(ah, bh[nr], acc[nr], 0, 0, 0);
            acc[nr] = __builtin_amdgcn_mfma_f32_16x16x32_bf16(ah, bl[nr], acc[nr], 0, 0, 0);
            acc[nr] = __builtin_amdgcn_mfma_f32_16x16x32_bf16(al, bh[nr], acc[nr], 0, 0, 0);
        }
    }

    float cs[4] = {}, cq[4] = {};
#pragma unroll
    for (int nr = 0; nr < 4; ++nr) {
#pragma unroll
        for (int r = 0; r < 4; ++r) {
            int n = row0 + l4 * 4 + r;
            float v = acc[nr][r] + b2s[nr * 16 + l15];
            v = (v > 0.f) ? v : 0.01f * v;
            if (n < Nrows) {
                Y[(size_t)n * 64 + nr * 16 + l15] = v;
                cs[nr] += v;
                cq[nr] += v * v;
            }
        }
    }
#pragma unroll
    for (int nr = 0; nr < 4; ++nr) {
        float s1 = cs[nr], s2 = cq[nr];
        s1 += __shfl_down(s1, 32);
        s2 += __shfl_down(s2, 32);
        s1 += __shfl_down(s1, 16);
        s2 += __shfl_down(s2, 16);
        if (lane < 16) {
            redS[w][nr * 16 + l15] = s1;
            redQ[w][nr * 16 + l15] = s2;
        }
    }
    __syncthreads();
    if (t < 64) {
        float s1 = redS[0][t] + redS[1][t] + redS[2][t] + redS[3][t];
        float s2 = redQ[0][t] + redQ[1][t] + redQ[2][t] + redQ[3][t];
        atomicAdd(&osum[t], s1);
        atomicAdd(&osq[t], s2);
    }
}

// ---------------------------------------------------------------------------
// Convert the three W1 weights ([64][K] f32) to bf16 hi/lo tiled frags, 1 launch.
// ---------------------------------------------------------------------------
__global__ void conv_w64_3(const float* __restrict__ W0, const float* __restrict__ Wa,
                           const float* __restrict__ Wb,
                           short* __restrict__ O0h, short* __restrict__ O0l,
                           short* __restrict__ O1h, short* __restrict__ O1l,
                           short* __restrict__ O2h, short* __restrict__ O2l)
{
    int tid = blockIdx.x * 256 + threadIdx.x;   // 1024 + 2048 + 2048 = 5120 frags
    const float* W; short* oh; short* ol; int K, f;
    if (tid < 1024)      { W = W0; oh = O0h; ol = O0l; K = 128; f = tid; }
    else if (tid < 3072) { W = Wa; oh = O1h; ol = O1l; K = 256; f = tid - 1024; }
    else if (tid < 5120) { W = Wb; oh = O2h; ol = O2l; K = 256; f = tid - 3072; }
    else return;
    int l = f & 63;
    int r = f >> 6;
    int cb = r & 3, ks = r >> 2;
    int col = cb * 16 + (l & 15);
    int k = ks * 32 + ((l >> 4) & 3) * 8;
    const float* src = W + (size_t)col * K + k;
    bf8 h, lo;
#pragma unroll
    for (int e = 0; e < 8; ++e) {
        float v = src[e];
        short hb = f2bf(v);
        float hf = __uint_as_float(((unsigned)(unsigned short)hb) << 16);
        h[e] = hb;
        lo[e] = f2bf(v - hf);
    }
    ((bf8*)oh)[f] = h;
    ((bf8*)ol)[f] = lo;
}

// ---------------------------------------------------------------------------
// Convert Wm1 (f32 [256][256]) to bf16 hi/lo pre-tiled fragments (16 cb).
// ---------------------------------------------------------------------------
__global__ void conv_wm1(const float* __restrict__ W,
                         short* __restrict__ Whi, short* __restrict__ Wlo)
{
    int tid = blockIdx.x * 256 + threadIdx.x;   // 8192 threads
    int l = tid & 63;
    int f = tid >> 6;
    int cb = f & 15;
    int ks = f >> 4;
    int col = cb * 16 + (l & 15);
    int k = ks * 32 + ((l >> 4) & 3) * 8;
    const float* src = W + (size_t)col * 256 + k;
    bf8 h, lo;
#pragma unroll
    for (int e = 0; e < 8; ++e) {
        float v = src[e];
        short hb = f2bf(v);
        float hf = __uint_as_float(((unsigned)(unsigned short)hb) << 16);
        h[e] = hb;
        lo[e] = f2bf(v - hf);
    }
    ((bf8*)Whi)[tid] = h;
    ((bf8*)Wlo)[tid] = lo;
}

// ---------------------------------------------------------------------------
// MFMA big GEMM v9 (BM=128, one round per CU, lgkmcnt-only barrier) with
// IN-BLOCK BN1 fold prologue (a1/c1 from y1 stats; identical FP expressions).
// ---------------------------------------------------------------------------
#define FOG_BARRIER() asm volatile("s_waitcnt lgkmcnt(0)\n\ts_barrier" ::: "memory")

#define FOG_STEP(I, BUF, BU, BP)                                              \
  {                                                                           \
    bf8 af[4][2];                                                             \
    _Pragma("unroll")                                                         \
    for (int m = 0; m < 4; ++m) {                                             \
      _Pragma("unroll")                                                       \
      for (int jo = 0; jo < 2; ++jo) {                                        \
        int c = jo * 4 + l4;                                                  \
        int n = (mrb + m) * 16 + l15;                                         \
        af[m][jo] = *(const bf8*)&At[BUF][c][n ^ (c & 7)][0];                 \
      }                                                                       \
    }                                                                         \
    int inext = ((I) < 63) ? (I) + 1 : 63;                                    \
    _Pragma("unroll")                                                         \
    for (int nr = 0; nr < 4; ++nr) {                                          \
      _Pragma("unroll")                                                       \
      for (int jo = 0; jo < 2; ++jo)                                          \
        BP[nr][jo] = wp8[((inext * 16 + cbb + nr) * 2 + jo) * 64 + lane];     \
    }                                                                         \
    _Pragma("unroll")                                                         \
    for (int m = 0; m < 4; ++m) {                                             \
      _Pragma("unroll")                                                       \
      for (int nr = 0; nr < 4; ++nr) {                                        \
        acc[m][nr] = __builtin_amdgcn_mfma_f32_16x16x32_bf16(af[m][0], BU[nr][0], acc[m][nr], 0, 0, 0); \
        acc[m][nr] = __builtin_amdgcn_mfma_f32_16x16x32_bf16(af[m][1], BU[nr][1], acc[m][nr], 0, 0, 0); \
      }                                                                       \
    }                                                                         \
    if ((I) < 63) {                                                           \
      float xv = xd_s[nl][(I) + 1];                                           \
      uint4 q0, q1;                                                           \
      q0.x = pk2(xv * agr[0],  xv * agr[1]);                                  \
      q0.y = pk2(xv * agr[2],  xv * agr[3]);                                  \
      q0.z = pk2(xv * agr[4],  xv * agr[5]);                                  \
      q0.w = pk2(xv * agr[6],  xv * agr[7]);                                  \
      q1.x = pk2(xv * agr[8],  xv * agr[9]);                                  \
      q1.y = pk2(xv * agr[10], xv * agr[11]);                                 \
      q1.z = pk2(xv * agr[12], xv * agr[13]);                                 \
      q1.w = pk2(xv * agr[14], xv * agr[15]);                                 \
      *(uint4*)&At[(BUF) ^ 1][cA][nl ^ (cA & 7)][0] = q0;                     \
      *(uint4*)&At[(BUF) ^ 1][cB][nl ^ (cB & 7)][0] = q1;                     \
    }                                                                         \
    FOG_BARRIER();                                                            \
  }

__global__ __launch_bounds__(512, 2) void fog_mfma(
    const float* __restrict__ y1,
    const float* __restrict__ isum, const float* __restrict__ isq,   // y1 stats
    const float* __restrict__ g1v, const float* __restrict__ b1v,
    const float* __restrict__ agg, const short* __restrict__ Wpb,
    float* __restrict__ H, int Nrows,
    float* __restrict__ ssum, float* __restrict__ ssq,
    float* __restrict__ sjk, float invN)
{
    __shared__ float xd_s[128][68];
    __shared__ __align__(16) short At[2][8][128][8];  // [buf][chunk][node^chunk][8 bf16]
    __shared__ float a1s[64], c1s[64];
    const int t = threadIdx.x;          // 0..511
    const int lane = t & 63;
    const int w = t >> 6;               // wave 0..7
    const int nbase = blockIdx.x * 128;
    const int nl = t >> 2;              // staging node 0..127
    const int cA = (t & 3) * 2;         // staging j-chunks cA, cB
    const int cB = cA + 1;
    const int l15 = lane & 15;
    const int l4 = (lane >> 4) & 3;
    const int mrb = (w & 1) * 4;        // row 16-block base: 0 or 4
    const int cbb = (w >> 1) * 4;       // col 16-block base: 0,4,8,12

    // in-block BN1 fold (identical expressions to the old fold kernel)
    if (t < 64) {
        float m = isum[t] * invN;
        float vv = isq[t] * invN - m * m;
        float s = g1v[t] * rsqrtf(vv + EPS);
        a1s[t] = s;
        c1s[t] = b1v[t] - m * s;
    }
    __syncthreads();

    // stage xd (BN1-folded y1) into LDS; agg 16-value chunk into regs
    float agr[16];
    {
        int n = nbase + nl;
        bool valid = n < Nrows;
        const float* yr = y1 + (size_t)n * 64 + cA * 8;
        const float* ar = agg + (size_t)n * 64 + cA * 8;
#pragma unroll
        for (int u = 0; u < 16; u += 4) {
            float4 yv = valid ? *(const float4*)(yr + u) : make_float4(0.f, 0.f, 0.f, 0.f);
            float4 av = valid ? *(const float4*)(ar + u) : make_float4(0.f, 0.f, 0.f, 0.f);
            int j0 = cA * 8 + u;
            xd_s[nl][j0 + 0] = a1s[j0 + 0] * yv.x + c1s[j0 + 0];
            xd_s[nl][j0 + 1] = a1s[j0 + 1] * yv.y + c1s[j0 + 1];
            xd_s[nl][j0 + 2] = a1s[j0 + 2] * yv.z + c1s[j0 + 2];
            xd_s[nl][j0 + 3] = a1s[j0 + 3] * yv.w + c1s[j0 + 3];
            agr[u + 0] = av.x; agr[u + 1] = av.y; agr[u + 2] = av.z; agr[u + 3] = av.w;
        }
    }
    __syncthreads();

    const bf8* wp8 = (const bf8*)Wpb;
    // gen A(0) -> buf0 ; load B(0) -> bA
    {
        float xv = xd_s[nl][0];
        uint4 q0, q1;
        q0.x = pk2(xv * agr[0],  xv * agr[1]);
        q0.y = pk2(xv * agr[2],  xv * agr[3]);
        q0.z = pk2(xv * agr[4],  xv * agr[5]);
        q0.w = pk2(xv * agr[6],  xv * agr[7]);
        q1.x = pk2(xv * agr[8],  xv * agr[9]);
        q1.y = pk2(xv * agr[10], xv * agr[11]);
        q1.z = pk2(xv * agr[12], xv * agr[13]);
        q1.w = pk2(xv * agr[14], xv * agr[15]);
        *(uint4*)&At[0][cA][nl ^ (cA & 7)][0] = q0;
        *(uint4*)&At[0][cB][nl ^ (cB & 7)][0] = q1;
    }
    bf8 bA[4][2], bB[4][2];
#pragma unroll
    for (int nr = 0; nr < 4; ++nr)
#pragma unroll
        for (int jo = 0; jo < 2; ++jo)
            bA[nr][jo] = wp8[((cbb + nr) * 2 + jo) * 64 + lane];
    __syncthreads();

    f32x4 acc[4][4] = {};
    for (int i = 0; i < 64; i += 2) {
        FOG_STEP(i,     0, bA, bB);
        FOG_STEP(i + 1, 1, bB, bA);
    }

    if (ssum) {
        float cs[4] = {}, cq[4] = {};
#pragma unroll
        for (int m = 0; m < 4; ++m) {
#pragma unroll
            for (int r = 0; r < 4; ++r) {
                int n = nbase + (mrb + m) * 16 + l4 * 4 + r;
                if (n < Nrows) {
#pragma unroll
                    for (int nr = 0; nr < 4; ++nr) {
                        float v = acc[m][nr][r];
                        H[(size_t)n * 256 + (cbb + nr) * 16 + l15] = v;
                        cs[nr] += v;
                        cq[nr] += v * v;
                    }
                }
            }
        }
#pragma unroll
        for (int nr = 0; nr < 4; ++nr) {
            float s1 = cs[nr], s2 = cq[nr];
            s1 += __shfl_down(s1, 32);
            s2 += __shfl_down(s2, 32);
            s1 += __shfl_down(s1, 16);
            s2 += __shfl_down(s2, 16);
            if (l4 == 0 && lane < 16) {
                atomicAdd(&ssum[(cbb + nr) * 16 + l15], s1);
                atomicAdd(&ssq[(cbb + nr) * 16 + l15], s2);
            }
        }
    } else {
        // last layer: s += x3 fused (each (n,col) owned by exactly one thread)
#pragma unroll
        for (int m = 0; m < 4; ++m) {
#pragma unroll
            for (int r = 0; r < 4; ++r) {
                int n = nbase + (mrb + m) * 16 + l4 * 4 + r;
                if (n < Nrows) {
#pragma unroll
                    for (int nr = 0; nr < 4; ++nr) {
                        size_t idx = (size_t)n * 256 + (cbb + nr) * 16 + l15;
                        sjk[idx] += acc[m][nr][r];
                    }
                }
            }
        }
    }
}

// ---------------------------------------------------------------------------
// Fused MLP head: hid = relu(s @ Wm1.T + bm1) via bf16x3 MFMA (staged in LDS),
// then logits = hid @ Wm2.T + bm2 and row log_softmax -> out. One kernel.
// ---------------------------------------------------------------------------
__global__ __launch_bounds__(512) void head_lsm(
    const float* __restrict__ A,
    const short* __restrict__ Whi, const short* __restrict__ Wlo,
    const float* __restrict__ bias,
    const float* __restrict__ Wm2, const float* __restrict__ bm2,
    float* __restrict__ out, int Nrows)
{
    __shared__ float hid_s[64][257];
    __shared__ float Wl[40][257];
    __shared__ float bl[40];
    const int t = threadIdx.x;
    const int lane = t & 63;
    const int w = t >> 6;
    const int nbase = blockIdx.x * 64;
    const int l15 = lane & 15, l4 = (lane >> 4) & 3;
    const int mrb = (w & 1) * 32;
    const int cbb = (w >> 1) * 4;
    const bf8* whi = (const bf8*)Whi;
    const bf8* wlo = (const bf8*)Wlo;

    for (int e = t; e < 40 * 256; e += 512) Wl[e >> 8][e & 255] = Wm2[e];
    if (t < 40) bl[t] = bm2[t];

    f32x4 acc[2][4] = {};
#pragma unroll
    for (int ks = 0; ks < 8; ++ks) {
        bf8 ah[2], al[2];
#pragma unroll
        for (int m = 0; m < 2; ++m) {
            int n = nbase + mrb + m * 16 + l15;
            float4 f0, f1;
            if (n < Nrows) {
                const float* p = &A[(size_t)n * 256 + ks * 32 + l4 * 8];
                f0 = *(const float4*)p;
                f1 = *(const float4*)(p + 4);
            } else {
                f0 = make_float4(0.f, 0.f, 0.f, 0.f);
                f1 = f0;
            }
            split8(f0, f1, &ah[m], &al[m]);
        }
        bf8 bh[4], blw[4];
#pragma unroll
        for (int nr = 0; nr < 4; ++nr) {
            int idx = (ks * 16 + cbb + nr) * 64 + lane;
            bh[nr] = whi[idx];
            blw[nr] = wlo[idx];
        }
#pragma unroll
        for (int m = 0; m < 2; ++m)
#pragma unroll
            for (int nr = 0; nr < 4; ++nr) {
                acc[m][nr] = __builtin_amdgcn_mfma_f32_16x16x32_bf16(ah[m], bh[nr], acc[m][nr], 0, 0, 0);
                acc[m][nr] = __builtin_amdgcn_mfma_f32_16x16x32_bf16(ah[m], blw[nr], acc[m][nr], 0, 0, 0);
                acc[m][nr] = __builtin_amdgcn_mfma_f32_16x16x32_bf16(al[m], bh[nr], acc[m][nr], 0, 0, 0);
            }
    }

#pragma unroll
    for (int m = 0; m < 2; ++m) {
#pragma unroll
        for (int r = 0; r < 4; ++r) {
            int rl = mrb + m * 16 + l4 * 4 + r;   // local row 0..63
#pragma unroll
            for (int nr = 0; nr < 4; ++nr) {
                int col = (cbb + nr) * 16 + l15;
                float v = acc[m][nr][r] + bias[col];
                hid_s[rl][col] = fmaxf(v, 0.f);
            }
        }
    }
    __syncthreads();

    // log-softmax: 8 threads per node, 5 classes each
    int nl2 = t >> 3;
    int sub = t & 7;
    int node = nbase + nl2;
    if (node >= Nrows) return;

    float accl[5];
#pragma unroll
    for (int r = 0; r < 5; ++r) accl[r] = bl[sub * 5 + r];
    for (int k = 0; k < 256; k += 4) {
        float4 h4 = *(const float4*)&hid_s[nl2][k];
        float hv[4] = {h4.x, h4.y, h4.z, h4.w};
#pragma unroll
        for (int kk = 0; kk < 4; ++kk)
#pragma unroll
            for (int r = 0; r < 5; ++r)
                accl[r] += hv[kk] * Wl[sub * 5 + r][k + kk];
    }
    float mx = accl[0];
#pragma unroll
    for (int r = 1; r < 5; ++r) mx = fmaxf(mx, accl[r]);
    for (int off = 1; off < 8; off <<= 1) mx = fmaxf(mx, __shfl_xor(mx, off, 8));
    float se = 0.f;
#pragma unroll
    for (int r = 0; r < 5; ++r) se += expf(accl[r] - mx);
    for (int off = 1; off < 8; off <<= 1) se += __shfl_xor(se, off, 8);
    float lse = logf(se);
#pragma unroll
    for (int r = 0; r < 5; ++r)
        out[(size_t)node * 40 + sub * 5 + r] = accl[r] - mx - lse;
}

// ---------------------------------------------------------------------------
// CSR build: histogram of dst, prefix scan, fill src lists.
// ---------------------------------------------------------------------------
__global__ void hist_deg(const int* __restrict__ dst, int* __restrict__ deg)
{
    int e = blockIdx.x * 256 + threadIdx.x;
    if (e < EE) atomicAdd(&deg[dst[e]], 1);
}

__global__ void scan1(const int* __restrict__ deg, int* __restrict__ rowptr,
                      int* __restrict__ bsum)
{
    __shared__ int sh[256];
    int t = threadIdx.x;
    int i = blockIdx.x * 256 + t;
    int v = (i < NN) ? deg[i] : 0;
    sh[t] = v;
    __syncthreads();
    for (int off = 1; off < 256; off <<= 1) {
        int add = (t >= off) ? sh[t - off] : 0;
        __syncthreads();
        sh[t] += add;
        __syncthreads();
    }
    if (i < NN) rowptr[i] = sh[t] - v;          // exclusive
    if (t == 255) bsum[blockIdx.x] = sh[255];
}

__global__ void scan2(int* __restrict__ bsum, int* __restrict__ rowptr, int nb2)
{
    __shared__ int sh[256];
    int t = threadIdx.x;
    int v = (t < nb2) ? bsum[t] : 0;
    sh[t] = v;
    __syncthreads();
    for (int off = 1; off < 256; off <<= 1) {
        int add = (t >= off) ? sh[t - off] : 0;
        __syncthreads();
        sh[t] += add;
        __syncthreads();
    }
    if (t < nb2) bsum[t] = sh[t] - v;            // exclusive
    if (t == 0) rowptr[NN] = EE;
}

__global__ void scan3(int* __restrict__ rowptr, const int* __restrict__ bsum,
                      int* __restrict__ cursor)
{
    int i = blockIdx.x * 256 + threadIdx.x;
    if (i < NN) {
        int r = rowptr[i] + bsum[blockIdx.x];
        rowptr[i] = r;
        cursor[i] = r;
    }
}

__global__ void fill_csr(const int* __restrict__ src, const int* __restrict__ dst,
                         int* __restrict__ cursor, int* __restrict__ csr_src)
{
    int e = blockIdx.x * 256 + threadIdx.x;
    if (e < EE) {
        int p = atomicAdd(&cursor[dst[e]], 1);
        csr_src[p] = src[e];
    }
}

// ---------------------------------------------------------------------------
// Gather aggregation with in-block BN2 fold from raw y2 stats:
// agg[v] = a2 * (sum_{e: dst=v} y2[src_e]) + deg_v * c2.
// ONE WAVE per node: 4 edge-substreams x 16 chunk-lanes; 4 row-loads in
// flight per substream.
// ---------------------------------------------------------------------------
__global__ __launch_bounds__(256) void gather_agg(
    const int* __restrict__ rowptr, const int* __restrict__ csr_src,
    const float* __restrict__ y2,
    const float* __restrict__ isum, const float* __restrict__ isq,
    const float* __restrict__ g2, const float* __restrict__ b2,
    float* __restrict__ agg, float invN)
{
    __shared__ float a2s[64], c2s[64];
    int t = threadIdx.x;
    if (t < 64) {
        float m = isum[t] * invN;
        float vv = isq[t] * invN - m * m;
        float s = g2[t] * rsqrtf(vv + EPS);
        a2s[t] = s;
        c2s[t] = b2[t] - m * s;
    }
    __syncthreads();
    int g = t >> 6;              // node within block: 0..3 (one wave per node)
    int sub = (t >> 4) & 3;      // edge substream 0..3
    int l = t & 15;              // float4 chunk
    int v = blockIdx.x * 4 + g;
    if (v >= NN) return;
    int beg = rowptr[v], end = rowptr[v + 1];
    float ax0 = 0.f, ay0 = 0.f, az0 = 0.f, aw0 = 0.f;
    float ax1 = 0.f, ay1 = 0.f, az1 = 0.f, aw1 = 0.f;
    int k = beg + sub;
    for (; k + 12 < end; k += 16) {
        int s0 = csr_src[k], s1 = csr_src[k + 4];
        int s2 = csr_src[k + 8], s3 = csr_src[k + 12];
        float4 v0 = *(const float4*)&y2[(size_t)s0 * 64 + l * 4];
        float4 v1 = *(const float4*)&y2[(size_t)s1 * 64 + l * 4];
        float4 v2 = *(const float4*)&y2[(size_t)s2 * 64 + l * 4];
        float4 v3 = *(const float4*)&y2[(size_t)s3 * 64 + l * 4];
        ax0 += v0.x + v2.x; ay0 += v0.y + v2.y; az0 += v0.z + v2.z; aw0 += v0.w + v2.w;
        ax1 += v1.x + v3.x; ay1 += v1.y + v3.y; az1 += v1.z + v3.z; aw1 += v1.w + v3.w;
    }
    for (; k < end; k += 4) {
        int s = csr_src[k];
        float4 val = *(const float4*)&y2[(size_t)s * 64 + l * 4];
        ax0 += val.x; ay0 += val.y; az0 += val.z; aw0 += val.w;
    }
    float ax = ax0 + ax1, ay = ay0 + ay1, az = az0 + az1, aw = aw0 + aw1;
    ax += __shfl_down(ax, 32);
    ay += __shfl_down(ay, 32);
    az += __shfl_down(az, 32);
    aw += __shfl_down(aw, 32);
    ax += __shfl_down(ax, 16);
    ay += __shfl_down(ay, 16);
    az += __shfl_down(az, 16);
    aw += __shfl_down(aw, 16);
    if ((t & 63) < 16) {
        float dg = (float)(end - beg);
        float4 a4 = *(const float4*)&a2s[l * 4];
        float4 c4 = *(const float4*)&c2s[l * 4];
        float4 o;
        o.x = a4.x * ax + dg * c4.x;
        o.y = a4.y * ay + dg * c4.y;
        o.z = a4.z * az + dg * c4.z;
        o.w = a4.w * aw + dg * c4.w;
        *(float4*)&agg[(size_t)v * 64 + l * 4] = o;
    }
}

// ---------------------------------------------------------------------------
extern "C" void kernel_launch(void* const* d_in, const int* in_sizes, int n_in,
                              void* d_out, int out_size, void* d_ws, size_t ws_size,
                              hipStream_t stream)
{
    const float* x = (const float*)d_in[0];
    const int* ei = (const int*)d_in[1];
    const int* src = ei;          // row 0
    const int* dst = ei + EE;     // row 1
    const float* W1[3] = {(const float*)d_in[2], (const float*)d_in[9],  (const float*)d_in[16]};
    const float* W2[3] = {(const float*)d_in[3], (const float*)d_in[10], (const float*)d_in[17]};
    const float* Wp[3] = {(const float*)d_in[4], (const float*)d_in[11], (const float*)d_in[18]};
    const float* g1[3] = {(const float*)d_in[5], (const float*)d_in[12], (const float*)d_in[19]};
    const float* b1[3] = {(const float*)d_in[6], (const float*)d_in[13], (const float*)d_in[20]};
    const float* g2[3] = {(const float*)d_in[7], (const float*)d_in[14], (const float*)d_in[21]};
    const float* b2[3] = {(const float*)d_in[8], (const float*)d_in[15], (const float*)d_in[22]};
    const float* gbn[2] = {(const float*)d_in[23], (const float*)d_in[25]};
    const float* bbn[2] = {(const float*)d_in[24], (const float*)d_in[26]};
    const float* Wm1 = (const float*)d_in[27];
    const float* bm1 = (const float*)d_in[28];
    const float* Wm2 = (const float*)d_in[29];
    const float* bm2 = (const float*)d_in[30];

    // workspace layout (floats)
    float* wsf  = (float*)d_ws;
    float* hbuf = wsf;                          // N*256
    float* sbuf = hbuf + (size_t)NN * DD;       // N*256
    float* y1   = sbuf + (size_t)NN * DD;       // N*64
    float* y2   = y1 + (size_t)NN * 64;         // N*64
    float* agg  = y2 + (size_t)NN * 64;         // N*64
    float* sm   = agg + (size_t)NN * 64;        // small scratch region
    float* y1s  = sm;             // 384
    float* y2s  = sm + 384;       // 384
    float* hs   = sm + 768;       // 1024
    int* ibase   = (int*)(sm + 6080);
    int* deg     = ibase;                 // NN
    int* rowptr  = deg + NN;              // NN+1
    int* cursor  = rowptr + NN + 1;       // NN
    int* bsum    = cursor + NN;           // 256
    int* csr_src = bsum + 256;            // EE
    int  ioff    = ((NN * 3 + 1 + 256 + EE) + 7) & ~7;
    short* wm1h  = (short*)(ibase + ioff);     // 65536 shorts
    short* wm1l  = wm1h + 65536;               // 65536 shorts
    short* w1h   = wm1l + 65536;               // 3 * 16384 shorts
    short* w1l   = w1h + 3 * 16384;            // 3 * 16384 shorts
    short* wpb   = w1l + 3 * 16384;            // 1048576 shorts (dedicated Wpb)

    const dim3 blk(256);
    const float invN = 1.0f / NN;
    const int nb = (NN + 63) / 64;     // 469
    const int nbf = (NN + 127) / 128;  // 235 (fog BM=128, one round per CU)
    const int nb2 = (NN + 255) / 256;  // 118
    const int nbe = (EE + 255) / 256;  // 3750

    hipMemsetAsync(sm, 0, 1792 * sizeof(float), stream);   // all stats accumulators
    conv_wm1<<<32, blk, 0, stream>>>(Wm1, wm1h, wm1l);
    conv_w64_3<<<20, blk, 0, stream>>>(W1[0], W1[1], W1[2],
                                       w1h, w1l,
                                       w1h + 16384, w1l + 16384,
                                       w1h + 32768, w1l + 32768);

    // ---- CSR build (once; reused by all 3 layers) ----
    hipMemsetAsync(deg, 0, NN * sizeof(int), stream);
    hist_deg<<<nbe, blk, 0, stream>>>(dst, deg);
    scan1<<<nb2, blk, 0, stream>>>(deg, rowptr, bsum);
    scan2<<<1, blk, 0, stream>>>(bsum, rowptr, nb2);
    scan3<<<nb2, blk, 0, stream>>>(rowptr, bsum, cursor);
    fill_csr<<<nbe, blk, 0, stream>>>(src, dst, cursor, csr_src);

    for (int l = 0; l < 3; ++l) {
        const float* xin = (l == 0) ? x : hbuf;
        int cin = (l == 0) ? IN_ : DD;
        float* sO = (l == 0) ? nullptr : sbuf;
        int smode = (l == 0) ? 0 : ((l == 1) ? 1 : 2);
        const float* pim = (l == 0) ? nullptr : hs + (l - 1) * 512;
        const float* piq = (l == 0) ? nullptr : hs + (l - 1) * 512 + 256;
        const float* pig = (l == 0) ? nullptr : gbn[l - 1];
        const float* pib = (l == 0) ? nullptr : bbn[l - 1];

        // y1 = leaky(xin' @ W1.T)  with fused prev-H BN+ReLU + JK-sum write
        gemm64_mfma<<<nb, blk, 0, stream>>>(xin, cin, w1h + l * 16384, w1l + l * 16384,
                                            nullptr, y1, NN,
                                            y1s + l * 128, y1s + l * 128 + 64,
                                            pim, piq, pig, pib, sO, smode, invN);

        // y2 = leaky(y1_bn @ W2f.T + b2f)  with in-block BN1+W2 fold
        // + fused Wp->bf16 conversion (512 extra blocks -> dedicated wpb)
        gemm64_w2<<<nb + 512, blk, 0, stream>>>(y1, W2[l],
                                                y1s + l * 128, y1s + l * 128 + 64,
                                                g1[l], b1[l], y2, NN,
                                                y2s + l * 128, y2s + l * 128 + 64, invN,
                                                Wp[l], wpb, nb);

        // agg with in-block BN2 fold from y2 stats
        gather_agg<<<(NN + 3) / 4, blk, 0, stream>>>(rowptr, csr_src, y2,
                                                     y2s + l * 128, y2s + l * 128 + 64,
                                                     g2[l], b2[l], agg, invN);

        bool st = (l < 2);
        fog_mfma<<<dim3(nbf), dim3(512), 0, stream>>>(y1,
                                                      y1s + l * 128, y1s + l * 128 + 64,
                                                      g1[l], b1[l],
                                                      agg, wpb, hbuf, NN,
                                                      st ? hs + l * 512 : nullptr,
                                                      st ? hs + l * 512 + 256 : nullptr,
                                                      st ? nullptr : sbuf, invN);
    }

    // fused MLP head + log-softmax
    head_lsm<<<nb, dim3(512), 0, stream>>>(sbuf, wm1h, wm1l, bm1, Wm2, bm2,
                                           (float*)d_out, NN);
}

// Round 21
// 577.175 us; speedup vs baseline: 1.0890x; 1.0434x over previous
//
#include <hip/hip_runtime.h>
#include <hip/hip_bf16.h>
#include <math.h>

#define NN 30000
#define EE 960000
#define IN_ 128
#define DD 256
#define CC 40
#define EPS 1e-5f

typedef short bf8 __attribute__((ext_vector_type(8)));    // 8 bf16 (4 VGPRs)
typedef float f32x4 __attribute__((ext_vector_type(4)));

__device__ inline short f2bf(float x) {
    unsigned u = __float_as_uint(x);
    unsigned r = (u + 0x7fffu + ((u >> 16) & 1u)) >> 16;   // RNE
    return (short)r;
}

__device__ inline unsigned pk2(float lo, float hi) {
    __hip_bfloat162 h = __float22bfloat162_rn(make_float2(lo, hi));
    return *reinterpret_cast<unsigned*>(&h);
}

// split 8 f32 into bf16 hi + bf16 lo(residual) fragments
__device__ inline void split8(float4 f0, float4 f1, bf8* h, bf8* l) {
    unsigned h0 = pk2(f0.x, f0.y), h1 = pk2(f0.z, f0.w);
    unsigned h2 = pk2(f1.x, f1.y), h3 = pk2(f1.z, f1.w);
    float e0 = f0.x - __uint_as_float(h0 << 16);
    float e1 = f0.y - __uint_as_float(h0 & 0xFFFF0000u);
    float e2 = f0.z - __uint_as_float(h1 << 16);
    float e3 = f0.w - __uint_as_float(h1 & 0xFFFF0000u);
    float e4 = f1.x - __uint_as_float(h2 << 16);
    float e5 = f1.y - __uint_as_float(h2 & 0xFFFF0000u);
    float e6 = f1.z - __uint_as_float(h3 << 16);
    float e7 = f1.w - __uint_as_float(h3 & 0xFFFF0000u);
    uint4 hu = make_uint4(h0, h1, h2, h3);
    uint4 lu = make_uint4(pk2(e0, e1), pk2(e2, e3), pk2(e4, e5), pk2(e6, e7));
    *h = *(bf8*)&hu;
    *l = *(bf8*)&lu;
}

// ---------------------------------------------------------------------------
// Small GEMM via bf16x3 split MFMA (y1 layers). Optional in-block BN fold of
// the INPUT from raw stats (K==256 mode) with JK-sum write. Per-col output
// sum/sumsq stats. Blocks >= nbG run hist_deg's edge histogram (layer-0
// CSR build hidden under the GEMM).
// ---------------------------------------------------------------------------
__global__ __launch_bounds__(256) void gemm64_mfma(
    const float* __restrict__ A, int K,
    const short* __restrict__ Whi, const short* __restrict__ Wlo,
    const float* __restrict__ bias,
    float* __restrict__ Y, int Nrows,
    float* __restrict__ osum, float* __restrict__ osq,
    const float* __restrict__ isum, const float* __restrict__ isq,
    const float* __restrict__ ig, const float* __restrict__ ib,
    float* __restrict__ sOut, int smode, float invN,
    const int* __restrict__ hdst, int* __restrict__ hdeg, int nbG)
{
    if (blockIdx.x >= nbG) {
        // fused hist_deg (layer 0 only)
        int e = (blockIdx.x - nbG) * 256 + threadIdx.x;
        if (e < EE) atomicAdd(&hdeg[hdst[e]], 1);
        return;
    }

    __shared__ float redS[4][64], redQ[4][64];
    __shared__ float ah_s[256], ch_s[256];
    const int t = threadIdx.x;
    if (isum) {   // K==256 in this mode; 256 threads each fold one column
        float m = isum[t] * invN;
        float vv = isq[t] * invN - m * m;
        float s = ig[t] * rsqrtf(vv + EPS);
        ah_s[t] = s;
        ch_s[t] = ib[t] - m * s;
        __syncthreads();
    }
    const int lane = t & 63;
    const int w = t >> 6;
    const int l15 = lane & 15, l4 = (lane >> 4) & 3;
    const int row0 = blockIdx.x * 64 + w * 16;
    const bf8* whi = (const bf8*)Whi;
    const bf8* wlo = (const bf8*)Wlo;

    f32x4 acc[4] = {};
    const int nst = K >> 5;
    const int nA = row0 + l15;
    const bool valA = nA < Nrows;

#pragma unroll 2
    for (int ks = 0; ks < nst; ++ks) {
        int k0 = ks * 32 + l4 * 8;
        float4 f0, f1;
        if (valA) {
            const float* p = &A[(size_t)nA * K + k0];
            f0 = *(const float4*)p;
            f1 = *(const float4*)(p + 4);
        } else {
            f0 = make_float4(0.f, 0.f, 0.f, 0.f);
            f1 = f0;
        }
        if (isum) {
            float4 a4 = *(const float4*)&ah_s[k0], a5 = *(const float4*)&ah_s[k0 + 4];
            float4 c4 = *(const float4*)&ch_s[k0], c5 = *(const float4*)&ch_s[k0 + 4];
            f0.x = fmaxf(a4.x * f0.x + c4.x, 0.f);
            f0.y = fmaxf(a4.y * f0.y + c4.y, 0.f);
            f0.z = fmaxf(a4.z * f0.z + c4.z, 0.f);
            f0.w = fmaxf(a4.w * f0.w + c4.w, 0.f);
            f1.x = fmaxf(a5.x * f1.x + c5.x, 0.f);
            f1.y = fmaxf(a5.y * f1.y + c5.y, 0.f);
            f1.z = fmaxf(a5.z * f1.z + c5.z, 0.f);
            f1.w = fmaxf(a5.w * f1.w + c5.w, 0.f);
            if (valA) {
                float* sp = &sOut[(size_t)nA * K + k0];
                if (smode == 1) {
                    *(float4*)sp = f0;
                    *(float4*)(sp + 4) = f1;
                } else {
                    float4 s0 = *(const float4*)sp, s1 = *(const float4*)(sp + 4);
                    s0.x += f0.x; s0.y += f0.y; s0.z += f0.z; s0.w += f0.w;
                    s1.x += f1.x; s1.y += f1.y; s1.z += f1.z; s1.w += f1.w;
                    *(float4*)sp = s0;
                    *(float4*)(sp + 4) = s1;
                }
            }
        }
        bf8 ah, al;
        split8(f0, f1, &ah, &al);
        bf8 bh[4], bl[4];
#pragma unroll
        for (int nr = 0; nr < 4; ++nr) {
            int idx = (ks * 4 + nr) * 64 + lane;
            bh[nr] = whi[idx];
            bl[nr] = wlo[idx];
        }
#pragma unroll
        for (int nr = 0; nr < 4; ++nr) {
            acc[nr] = __builtin_amdgcn_mfma_f32_16x16x32_bf16(ah, bh[nr], acc[nr], 0, 0, 0);
            acc[nr] = __builtin_amdgcn_mfma_f32_16x16x32_bf16(ah, bl[nr], acc[nr], 0, 0, 0);
            acc[nr] = __builtin_amdgcn_mfma_f32_16x16x32_bf16(al, bh[nr], acc[nr], 0, 0, 0);
        }
    }

    float cs[4] = {}, cq[4] = {};
#pragma unroll
    for (int nr = 0; nr < 4; ++nr) {
#pragma unroll
        for (int r = 0; r < 4; ++r) {
            int n = row0 + l4 * 4 + r;
            float v = acc[nr][r];
            if (bias) v += bias[nr * 16 + l15];
            v = (v > 0.f) ? v : 0.01f * v;
            if (n < Nrows) {
                Y[(size_t)n * 64 + nr * 16 + l15] = v;
                cs[nr] += v;
                cq[nr] += v * v;
            }
        }
    }
#pragma unroll
    for (int nr = 0; nr < 4; ++nr) {
        float s1 = cs[nr], s2 = cq[nr];
        s1 += __shfl_down(s1, 32);
        s2 += __shfl_down(s2, 32);
        s1 += __shfl_down(s1, 16);
        s2 += __shfl_down(s2, 16);
        if (lane < 16) {
            redS[w][nr * 16 + l15] = s1;
            redQ[w][nr * 16 + l15] = s2;
        }
    }
    __syncthreads();
    if (t < 64) {
        float s1 = redS[0][t] + redS[1][t] + redS[2][t] + redS[3][t];
        float s2 = redQ[0][t] + redQ[1][t] + redQ[2][t] + redQ[3][t];
        atomicAdd(&osum[t], s1);
        atomicAdd(&osq[t], s2);
    }
}

// ---------------------------------------------------------------------------
// y2 GEMM with IN-BLOCK BN1 fold + W2 fold (blocks < nbG), fused Wp bf16
// conversion (blocks [nbG, nbG+512)), and fused fill_csr (blocks >= nbG+512,
// layer-0 only; scans complete before this launch, gather comes after).
// ---------------------------------------------------------------------------
__global__ __launch_bounds__(256) void gemm64_w2(
    const float* __restrict__ A,          // y1 [N][64]
    const float* __restrict__ W2,         // [64][64] f32
    const float* __restrict__ isum, const float* __restrict__ isq,   // y1 stats
    const float* __restrict__ g1v, const float* __restrict__ b1v,
    float* __restrict__ Y, int Nrows,
    float* __restrict__ osum, float* __restrict__ osq, float invN,
    const float* __restrict__ Wp, short* __restrict__ Wpb, int nbG,
    const int* __restrict__ fsrc, const int* __restrict__ fdst,
    int* __restrict__ fcursor, int* __restrict__ fcsr)
{
    if (blockIdx.x >= nbG + 512) {
        // fused fill_csr (layer 0 only)
        int e = (blockIdx.x - nbG - 512) * 256 + threadIdx.x;
        if (e < EE) {
            int p = atomicAdd(&fcursor[fdst[e]], 1);
            fcsr[p] = fsrc[e];
        }
        return;
    }
    if (blockIdx.x >= nbG) {
        // conv_wp: convert Wp (f32 [256][4096]) to bf16 pre-tiled fragments
        int tid = (blockIdx.x - nbG) * 256 + threadIdx.x;   // 131072 threads
        int l = tid & 63;
        int r = tid >> 6;
        int jo = r & 1;
        int q = r >> 1;
        int cb = q & 15;
        int i = q >> 4;
        int col = cb * 16 + (l & 15);
        int k = i * 64 + jo * 32 + ((l >> 4) & 3) * 8;
        const float* srcp = Wp + (size_t)col * 4096 + k;
        bf8 v;
#pragma unroll
        for (int e = 0; e < 8; ++e) v[e] = f2bf(srcp[e]);
        ((bf8*)Wpb)[tid] = v;
        return;
    }

    __shared__ float redS[4][64], redQ[4][64];
    __shared__ float as_[64], cs_[64], b2s[64];
    __shared__ __align__(16) short w2hs[4096], w2ls[4096];
    const int t = threadIdx.x;

    // fold BN1 from raw stats (identical expressions to fold_bn1_w2)
    if (t < 64) {
        float m = isum[t] * invN;
        float vv = isq[t] * invN - m * m;
        float s = g1v[t] * rsqrtf(vv + EPS);
        as_[t] = s;
        cs_[t] = b1v[t] - m * s;
    }
    __syncthreads();
    if (t < 64) {
        float bb = 0.f;
        for (int i = 0; i < 64; ++i) bb += W2[t * 64 + i] * cs_[i];
        b2s[t] = bb;
    }
    // build W2f bf16 hi/lo fragments (512 slots, 2 per thread)
    for (int slot = t; slot < 512; slot += 256) {
        int rep = slot >> 6, l = slot & 63;
        int cb = rep & 3, ks = rep >> 2;
        int col = cb * 16 + (l & 15);
        int k = ks * 32 + ((l >> 4) & 3) * 8;
        bf8 h, lo;
#pragma unroll
        for (int e = 0; e < 8; ++e) {
            float v = W2[col * 64 + k + e] * as_[k + e];
            short hb = f2bf(v);
            float hf = __uint_as_float(((unsigned)(unsigned short)hb) << 16);
            h[e] = hb;
            lo[e] = f2bf(v - hf);
        }
        ((bf8*)w2hs)[slot] = h;
        ((bf8*)w2ls)[slot] = lo;
    }
    __syncthreads();

    const int lane = t & 63;
    const int w = t >> 6;
    const int l15 = lane & 15, l4 = (lane >> 4) & 3;
    const int row0 = blockIdx.x * 64 + w * 16;
    const bf8* whi = (const bf8*)w2hs;
    const bf8* wlo = (const bf8*)w2ls;

    f32x4 acc[4] = {};
    const int nA = row0 + l15;
    const bool valA = nA < Nrows;

#pragma unroll
    for (int ks = 0; ks < 2; ++ks) {
        int k0 = ks * 32 + l4 * 8;
        float4 f0, f1;
        if (valA) {
            const float* p = &A[(size_t)nA * 64 + k0];
            f0 = *(const float4*)p;
            f1 = *(const float4*)(p + 4);
        } else {
            f0 = make_float4(0.f, 0.f, 0.f, 0.f);
            f1 = f0;
        }
        bf8 ah, al;
        split8(f0, f1, &ah, &al);
        bf8 bh[4], bl[4];
#pragma unroll
        for (int nr = 0; nr < 4; ++nr) {
            int idx = (ks * 4 + nr) * 64 + lane;
            bh[nr] = whi[idx];
            bl[nr] = wlo[idx];
        }
#pragma unroll
        for (int nr = 0; nr < 4; ++nr) {
            acc[nr] = __builtin_amdgcn_mfma_f32_16x16x32_bf16(ah, bh[nr], acc[nr], 0, 0, 0);
            acc[nr] = __builtin_amdgcn_mfma_f32_16x16x32_bf16(ah, bl[nr], acc[nr], 0, 0, 0);
            acc[nr] = __builtin_amdgcn_mfma_f32_16x16x32_bf16(al, bh[nr], acc[nr], 0, 0, 0);
        }
    }

    float cs[4] = {}, cq[4] = {};
#pragma unroll
    for (int nr = 0; nr < 4; ++nr) {
#pragma unroll
        for (int r = 0; r < 4; ++r) {
            int n = row0 + l4 * 4 + r;
            float v = acc[nr][r] + b2s[nr * 16 + l15];
            v = (v > 0.f) ? v : 0.01f * v;
            if (n < Nrows) {
                Y[(size_t)n * 64 + nr * 16 + l15] = v;
                cs[nr] += v;
                cq[nr] += v * v;
            }
        }
    }
#pragma unroll
    for (int nr = 0; nr < 4; ++nr) {
        float s1 = cs[nr], s2 = cq[nr];
        s1 += __shfl_down(s1, 32);
        s2 += __shfl_down(s2, 32);
        s1 += __shfl_down(s1, 16);
        s2 += __shfl_down(s2, 16);
        if (lane < 16) {
            redS[w][nr * 16 + l15] = s1;
            redQ[w][nr * 16 + l15] = s2;
        }
    }
    __syncthreads();
    if (t < 64) {
        float s1 = redS[0][t] + redS[1][t] + redS[2][t] + redS[3][t];
        float s2 = redQ[0][t] + redQ[1][t] + redQ[2][t] + redQ[3][t];
        atomicAdd(&osum[t], s1);
        atomicAdd(&osq[t], s2);
    }
}

// ---------------------------------------------------------------------------
// Convert the three W1 weights ([64][K] f32) to bf16 hi/lo tiled frags, 1 launch.
// ---------------------------------------------------------------------------
__global__ void conv_w64_3(const float* __restrict__ W0, const float* __restrict__ Wa,
                           const float* __restrict__ Wb,
                           short* __restrict__ O0h, short* __restrict__ O0l,
                           short* __restrict__ O1h, short* __restrict__ O1l,
                           short* __restrict__ O2h, short* __restrict__ O2l)
{
    int tid = blockIdx.x * 256 + threadIdx.x;   // 1024 + 2048 + 2048 = 5120 frags
    const float* W; short* oh; short* ol; int K, f;
    if (tid < 1024)      { W = W0; oh = O0h; ol = O0l; K = 128; f = tid; }
    else if (tid < 3072) { W = Wa; oh = O1h; ol = O1l; K = 256; f = tid - 1024; }
    else if (tid < 5120) { W = Wb; oh = O2h; ol = O2l; K = 256; f = tid - 3072; }
    else return;
    int l = f & 63;
    int r = f >> 6;
    int cb = r & 3, ks = r >> 2;
    int col = cb * 16 + (l & 15);
    int k = ks * 32 + ((l >> 4) & 3) * 8;
    const float* src = W + (size_t)col * K + k;
    bf8 h, lo;
#pragma unroll
    for (int e = 0; e < 8; ++e) {
        float v = src[e];
        short hb = f2bf(v);
        float hf = __uint_as_float(((unsigned)(unsigned short)hb) << 16);
        h[e] = hb;
        lo[e] = f2bf(v - hf);
    }
    ((bf8*)oh)[f] = h;
    ((bf8*)ol)[f] = lo;
}

// ---------------------------------------------------------------------------
// Convert Wm1 (f32 [256][256]) to bf16 hi/lo pre-tiled fragments (16 cb).
// ---------------------------------------------------------------------------
__global__ void conv_wm1(const float* __restrict__ W,
                         short* __restrict__ Whi, short* __restrict__ Wlo)
{
    int tid = blockIdx.x * 256 + threadIdx.x;   // 8192 threads
    int l = tid & 63;
    int f = tid >> 6;
    int cb = f & 15;
    int ks = f >> 4;
    int col = cb * 16 + (l & 15);
    int k = ks * 32 + ((l >> 4) & 3) * 8;
    const float* src = W + (size_t)col * 256 + k;
    bf8 h, lo;
#pragma unroll
    for (int e = 0; e < 8; ++e) {
        float v = src[e];
        short hb = f2bf(v);
        float hf = __uint_as_float(((unsigned)(unsigned short)hb) << 16);
        h[e] = hb;
        lo[e] = f2bf(v - hf);
    }
    ((bf8*)Whi)[tid] = h;
    ((bf8*)Wlo)[tid] = lo;
}

// ---------------------------------------------------------------------------
// MFMA big GEMM v9 (BM=128, one round per CU, lgkmcnt-only barrier) with
// IN-BLOCK BN1 fold prologue (a1/c1 from y1 stats; identical FP expressions).
// ---------------------------------------------------------------------------
#define FOG_BARRIER() asm volatile("s_waitcnt lgkmcnt(0)\n\ts_barrier" ::: "memory")

#define FOG_STEP(I, BUF, BU, BP)                                              \
  {                                                                           \
    bf8 af[4][2];                                                             \
    _Pragma("unroll")                                                         \
    for (int m = 0; m < 4; ++m) {                                             \
      _Pragma("unroll")                                                       \
      for (int jo = 0; jo < 2; ++jo) {                                        \
        int c = jo * 4 + l4;                                                  \
        int n = (mrb + m) * 16 + l15;                                         \
        af[m][jo] = *(const bf8*)&At[BUF][c][n ^ (c & 7)][0];                 \
      }                                                                       \
    }                                                                         \
    int inext = ((I) < 63) ? (I) + 1 : 63;                                    \
    _Pragma("unroll")                                                         \
    for (int nr = 0; nr < 4; ++nr) {                                          \
      _Pragma("unroll")                                                       \
      for (int jo = 0; jo < 2; ++jo)                                          \
        BP[nr][jo] = wp8[((inext * 16 + cbb + nr) * 2 + jo) * 64 + lane];     \
    }                                                                         \
    _Pragma("unroll")                                                         \
    for (int m = 0; m < 4; ++m) {                                             \
      _Pragma("unroll")                                                       \
      for (int nr = 0; nr < 4; ++nr) {                                        \
        acc[m][nr] = __builtin_amdgcn_mfma_f32_16x16x32_bf16(af[m][0], BU[nr][0], acc[m][nr], 0, 0, 0); \
        acc[m][nr] = __builtin_amdgcn_mfma_f32_16x16x32_bf16(af[m][1], BU[nr][1], acc[m][nr], 0, 0, 0); \
      }                                                                       \
    }                                                                         \
    if ((I) < 63) {                                                           \
      float xv = xd_s[nl][(I) + 1];                                           \
      uint4 q0, q1;                                                           \
      q0.x = pk2(xv * agr[0],  xv * agr[1]);                                  \
      q0.y = pk2(xv * agr[2],  xv * agr[3]);                                  \
      q0.z = pk2(xv * agr[4],  xv * agr[5]);                                  \
      q0.w = pk2(xv * agr[6],  xv * agr[7]);                                  \
      q1.x = pk2(xv * agr[8],  xv * agr[9]);                                  \
      q1.y = pk2(xv * agr[10], xv * agr[11]);                                 \
      q1.z = pk2(xv * agr[12], xv * agr[13]);                                 \
      q1.w = pk2(xv * agr[14], xv * agr[15]);                                 \
      *(uint4*)&At[(BUF) ^ 1][cA][nl ^ (cA & 7)][0] = q0;                     \
      *(uint4*)&At[(BUF) ^ 1][cB][nl ^ (cB & 7)][0] = q1;                     \
    }                                                                         \
    FOG_BARRIER();                                                            \
  }

__global__ __launch_bounds__(512, 2) void fog_mfma(
    const float* __restrict__ y1,
    const float* __restrict__ isum, const float* __restrict__ isq,   // y1 stats
    const float* __restrict__ g1v, const float* __restrict__ b1v,
    const float* __restrict__ agg, const short* __restrict__ Wpb,
    float* __restrict__ H, int Nrows,
    float* __restrict__ ssum, float* __restrict__ ssq,
    float* __restrict__ sjk, float invN)
{
    __shared__ float xd_s[128][68];
    __shared__ __align__(16) short At[2][8][128][8];  // [buf][chunk][node^chunk][8 bf16]
    __shared__ float a1s[64], c1s[64];
    const int t = threadIdx.x;          // 0..511
    const int lane = t & 63;
    const int w = t >> 6;               // wave 0..7
    const int nbase = blockIdx.x * 128;
    const int nl = t >> 2;              // staging node 0..127
    const int cA = (t & 3) * 2;         // staging j-chunks cA, cB
    const int cB = cA + 1;
    const int l15 = lane & 15;
    const int l4 = (lane >> 4) & 3;
    const int mrb = (w & 1) * 4;        // row 16-block base: 0 or 4
    const int cbb = (w >> 1) * 4;       // col 16-block base: 0,4,8,12

    // in-block BN1 fold (identical expressions to the old fold kernel)
    if (t < 64) {
        float m = isum[t] * invN;
        float vv = isq[t] * invN - m * m;
        float s = g1v[t] * rsqrtf(vv + EPS);
        a1s[t] = s;
        c1s[t] = b1v[t] - m * s;
    }
    __syncthreads();

    // stage xd (BN1-folded y1) into LDS; agg 16-value chunk into regs
    float agr[16];
    {
        int n = nbase + nl;
        bool valid = n < Nrows;
        const float* yr = y1 + (size_t)n * 64 + cA * 8;
        const float* ar = agg + (size_t)n * 64 + cA * 8;
#pragma unroll
        for (int u = 0; u < 16; u += 4) {
            float4 yv = valid ? *(const float4*)(yr + u) : make_float4(0.f, 0.f, 0.f, 0.f);
            float4 av = valid ? *(const float4*)(ar + u) : make_float4(0.f, 0.f, 0.f, 0.f);
            int j0 = cA * 8 + u;
            xd_s[nl][j0 + 0] = a1s[j0 + 0] * yv.x + c1s[j0 + 0];
            xd_s[nl][j0 + 1] = a1s[j0 + 1] * yv.y + c1s[j0 + 1];
            xd_s[nl][j0 + 2] = a1s[j0 + 2] * yv.z + c1s[j0 + 2];
            xd_s[nl][j0 + 3] = a1s[j0 + 3] * yv.w + c1s[j0 + 3];
            agr[u + 0] = av.x; agr[u + 1] = av.y; agr[u + 2] = av.z; agr[u + 3] = av.w;
        }
    }
    __syncthreads();

    const bf8* wp8 = (const bf8*)Wpb;
    // gen A(0) -> buf0 ; load B(0) -> bA
    {
        float xv = xd_s[nl][0];
        uint4 q0, q1;
        q0.x = pk2(xv * agr[0],  xv * agr[1]);
        q0.y = pk2(xv * agr[2],  xv * agr[3]);
        q0.z = pk2(xv * agr[4],  xv * agr[5]);
        q0.w = pk2(xv * agr[6],  xv * agr[7]);
        q1.x = pk2(xv * agr[8],  xv * agr[9]);
        q1.y = pk2(xv * agr[10], xv * agr[11]);
        q1.z = pk2(xv * agr[12], xv * agr[13]);
        q1.w = pk2(xv * agr[14], xv * agr[15]);
        *(uint4*)&At[0][cA][nl ^ (cA & 7)][0] = q0;
        *(uint4*)&At[0][cB][nl ^ (cB & 7)][0] = q1;
    }
    bf8 bA[4][2], bB[4][2];
#pragma unroll
    for (int nr = 0; nr < 4; ++nr)
#pragma unroll
        for (int jo = 0; jo < 2; ++jo)
            bA[nr][jo] = wp8[((cbb + nr) * 2 + jo) * 64 + lane];
    __syncthreads();

    f32x4 acc[4][4] = {};
    for (int i = 0; i < 64; i += 2) {
        FOG_STEP(i,     0, bA, bB);
        FOG_STEP(i + 1, 1, bB, bA);
    }

    if (ssum) {
        float cs[4] = {}, cq[4] = {};
#pragma unroll
        for (int m = 0; m < 4; ++m) {
#pragma unroll
            for (int r = 0; r < 4; ++r) {
                int n = nbase + (mrb + m) * 16 + l4 * 4 + r;
                if (n < Nrows) {
#pragma unroll
                    for (int nr = 0; nr < 4; ++nr) {
                        float v = acc[m][nr][r];
                        H[(size_t)n * 256 + (cbb + nr) * 16 + l15] = v;
                        cs[nr] += v;
                        cq[nr] += v * v;
                    }
                }
            }
        }
#pragma unroll
        for (int nr = 0; nr < 4; ++nr) {
            float s1 = cs[nr], s2 = cq[nr];
            s1 += __shfl_down(s1, 32);
            s2 += __shfl_down(s2, 32);
            s1 += __shfl_down(s1, 16);
            s2 += __shfl_down(s2, 16);
            if (l4 == 0 && lane < 16) {
                atomicAdd(&ssum[(cbb + nr) * 16 + l15], s1);
                atomicAdd(&ssq[(cbb + nr) * 16 + l15], s2);
            }
        }
    } else {
        // last layer: s += x3 fused (each (n,col) owned by exactly one thread)
#pragma unroll
        for (int m = 0; m < 4; ++m) {
#pragma unroll
            for (int r = 0; r < 4; ++r) {
                int n = nbase + (mrb + m) * 16 + l4 * 4 + r;
                if (n < Nrows) {
#pragma unroll
                    for (int nr = 0; nr < 4; ++nr) {
                        size_t idx = (size_t)n * 256 + (cbb + nr) * 16 + l15;
                        sjk[idx] += acc[m][nr][r];
                    }
                }
            }
        }
    }
}

// ---------------------------------------------------------------------------
// Fused MLP head: hid = relu(s @ Wm1.T + bm1) via bf16x3 MFMA (staged in LDS),
// then logits = hid @ Wm2.T + bm2 and row log_softmax -> out. One kernel.
// ---------------------------------------------------------------------------
__global__ __launch_bounds__(512) void head_lsm(
    const float* __restrict__ A,
    const short* __restrict__ Whi, const short* __restrict__ Wlo,
    const float* __restrict__ bias,
    const float* __restrict__ Wm2, const float* __restrict__ bm2,
    float* __restrict__ out, int Nrows)
{
    __shared__ float hid_s[64][257];
    __shared__ float Wl[40][257];
    __shared__ float bl[40];
    const int t = threadIdx.x;
    const int lane = t & 63;
    const int w = t >> 6;
    const int nbase = blockIdx.x * 64;
    const int l15 = lane & 15, l4 = (lane >> 4) & 3;
    const int mrb = (w & 1) * 32;
    const int cbb = (w >> 1) * 4;
    const bf8* whi = (const bf8*)Whi;
    const bf8* wlo = (const bf8*)Wlo;

    for (int e = t; e < 40 * 256; e += 512) Wl[e >> 8][e & 255] = Wm2[e];
    if (t < 40) bl[t] = bm2[t];

    f32x4 acc[2][4] = {};
#pragma unroll
    for (int ks = 0; ks < 8; ++ks) {
        bf8 ah[2], al[2];
#pragma unroll
        for (int m = 0; m < 2; ++m) {
            int n = nbase + mrb + m * 16 + l15;
            float4 f0, f1;
            if (n < Nrows) {
                const float* p = &A[(size_t)n * 256 + ks * 32 + l4 * 8];
                f0 = *(const float4*)p;
                f1 = *(const float4*)(p + 4);
            } else {
                f0 = make_float4(0.f, 0.f, 0.f, 0.f);
                f1 = f0;
            }
            split8(f0, f1, &ah[m], &al[m]);
        }
        bf8 bh[4], blw[4];
#pragma unroll
        for (int nr = 0; nr < 4; ++nr) {
            int idx = (ks * 16 + cbb + nr) * 64 + lane;
            bh[nr] = whi[idx];
            blw[nr] = wlo[idx];
        }
#pragma unroll
        for (int m = 0; m < 2; ++m)
#pragma unroll
            for (int nr = 0; nr < 4; ++nr) {
                acc[m][nr] = __builtin_amdgcn_mfma_f32_16x16x32_bf16(ah[m], bh[nr], acc[m][nr], 0, 0, 0);
                acc[m][nr] = __builtin_amdgcn_mfma_f32_16x16x32_bf16(ah[m], blw[nr], acc[m][nr], 0, 0, 0);
                acc[m][nr] = __builtin_amdgcn_mfma_f32_16x16x32_bf16(al[m], bh[nr], acc[m][nr], 0, 0, 0);
            }
    }

#pragma unroll
    for (int m = 0; m < 2; ++m) {
#pragma unroll
        for (int r = 0; r < 4; ++r) {
            int rl = mrb + m * 16 + l4 * 4 + r;   // local row 0..63
#pragma unroll
            for (int nr = 0; nr < 4; ++nr) {
                int col = (cbb + nr) * 16 + l15;
                float v = acc[m][nr][r] + bias[col];
                hid_s[rl][col] = fmaxf(v, 0.f);
            }
        }
    }
    __syncthreads();

    // log-softmax: 8 threads per node, 5 classes each
    int nl2 = t >> 3;
    int sub = t & 7;
    int node = nbase + nl2;
    if (node >= Nrows) return;

    float accl[5];
#pragma unroll
    for (int r = 0; r < 5; ++r) accl[r] = bl[sub * 5 + r];
    for (int k = 0; k < 256; k += 4) {
        float4 h4 = *(const float4*)&hid_s[nl2][k];
        float hv[4] = {h4.x, h4.y, h4.z, h4.w};
#pragma unroll
        for (int kk = 0; kk < 4; ++kk)
#pragma unroll
            for (int r = 0; r < 5; ++r)
                accl[r] += hv[kk] * Wl[sub * 5 + r][k + kk];
    }
    float mx = accl[0];
#pragma unroll
    for (int r = 1; r < 5; ++r) mx = fmaxf(mx, accl[r]);
    for (int off = 1; off < 8; off <<= 1) mx = fmaxf(mx, __shfl_xor(mx, off, 8));
    float se = 0.f;
#pragma unroll
    for (int r = 0; r < 5; ++r) se += expf(accl[r] - mx);
    for (int off = 1; off < 8; off <<= 1) se += __shfl_xor(se, off, 8);
    float lse = logf(se);
#pragma unroll
    for (int r = 0; r < 5; ++r)
        out[(size_t)node * 40 + sub * 5 + r] = accl[r] - mx - lse;
}

// ---------------------------------------------------------------------------
// CSR scans (hist and fill are fused into the layer-0 GEMM launches).
// ---------------------------------------------------------------------------
__global__ void scan1(const int* __restrict__ deg, int* __restrict__ rowptr,
                      int* __restrict__ bsum)
{
    __shared__ int sh[256];
    int t = threadIdx.x;
    int i = blockIdx.x * 256 + t;
    int v = (i < NN) ? deg[i] : 0;
    sh[t] = v;
    __syncthreads();
    for (int off = 1; off < 256; off <<= 1) {
        int add = (t >= off) ? sh[t - off] : 0;
        __syncthreads();
        sh[t] += add;
        __syncthreads();
    }
    if (i < NN) rowptr[i] = sh[t] - v;          // exclusive
    if (t == 255) bsum[blockIdx.x] = sh[255];
}

__global__ void scan2(int* __restrict__ bsum, int* __restrict__ rowptr, int nb2)
{
    __shared__ int sh[256];
    int t = threadIdx.x;
    int v = (t < nb2) ? bsum[t] : 0;
    sh[t] = v;
    __syncthreads();
    for (int off = 1; off < 256; off <<= 1) {
        int add = (t >= off) ? sh[t - off] : 0;
        __syncthreads();
        sh[t] += add;
        __syncthreads();
    }
    if (t < nb2) bsum[t] = sh[t] - v;            // exclusive
    if (t == 0) rowptr[NN] = EE;
}

__global__ void scan3(int* __restrict__ rowptr, const int* __restrict__ bsum,
                      int* __restrict__ cursor)
{
    int i = blockIdx.x * 256 + threadIdx.x;
    if (i < NN) {
        int r = rowptr[i] + bsum[blockIdx.x];
        rowptr[i] = r;
        cursor[i] = r;
    }
}

// ---------------------------------------------------------------------------
// Gather aggregation with in-block BN2 fold from raw y2 stats:
// agg[v] = a2 * (sum_{e: dst=v} y2[src_e]) + deg_v * c2.
// ONE WAVE per node: 4 edge-substreams x 16 chunk-lanes; 4 row-loads in
// flight per substream.
// ---------------------------------------------------------------------------
__global__ __launch_bounds__(256) void gather_agg(
    const int* __restrict__ rowptr, const int* __restrict__ csr_src,
    const float* __restrict__ y2,
    const float* __restrict__ isum, const float* __restrict__ isq,
    const float* __restrict__ g2, const float* __restrict__ b2,
    float* __restrict__ agg, float invN)
{
    __shared__ float a2s[64], c2s[64];
    int t = threadIdx.x;
    if (t < 64) {
        float m = isum[t] * invN;
        float vv = isq[t] * invN - m * m;
        float s = g2[t] * rsqrtf(vv + EPS);
        a2s[t] = s;
        c2s[t] = b2[t] - m * s;
    }
    __syncthreads();
    int g = t >> 6;              // node within block: 0..3 (one wave per node)
    int sub = (t >> 4) & 3;      // edge substream 0..3
    int l = t & 15;              // float4 chunk
    int v = blockIdx.x * 4 + g;
    if (v >= NN) return;
    int beg = rowptr[v], end = rowptr[v + 1];
    float ax0 = 0.f, ay0 = 0.f, az0 = 0.f, aw0 = 0.f;
    float ax1 = 0.f, ay1 = 0.f, az1 = 0.f, aw1 = 0.f;
    int k = beg + sub;
    for (; k + 12 < end; k += 16) {
        int s0 = csr_src[k], s1 = csr_src[k + 4];
        int s2 = csr_src[k + 8], s3 = csr_src[k + 12];
        float4 v0 = *(const float4*)&y2[(size_t)s0 * 64 + l * 4];
        float4 v1 = *(const float4*)&y2[(size_t)s1 * 64 + l * 4];
        float4 v2 = *(const float4*)&y2[(size_t)s2 * 64 + l * 4];
        float4 v3 = *(const float4*)&y2[(size_t)s3 * 64 + l * 4];
        ax0 += v0.x + v2.x; ay0 += v0.y + v2.y; az0 += v0.z + v2.z; aw0 += v0.w + v2.w;
        ax1 += v1.x + v3.x; ay1 += v1.y + v3.y; az1 += v1.z + v3.z; aw1 += v1.w + v3.w;
    }
    for (; k < end; k += 4) {
        int s = csr_src[k];
        float4 val = *(const float4*)&y2[(size_t)s * 64 + l * 4];
        ax0 += val.x; ay0 += val.y; az0 += val.z; aw0 += val.w;
    }
    float ax = ax0 + ax1, ay = ay0 + ay1, az = az0 + az1, aw = aw0 + aw1;
    ax += __shfl_down(ax, 32);
    ay += __shfl_down(ay, 32);
    az += __shfl_down(az, 32);
    aw += __shfl_down(aw, 32);
    ax += __shfl_down(ax, 16);
    ay += __shfl_down(ay, 16);
    az += __shfl_down(az, 16);
    aw += __shfl_down(aw, 16);
    if ((t & 63) < 16) {
        float dg = (float)(end - beg);
        float4 a4 = *(const float4*)&a2s[l * 4];
        float4 c4 = *(const float4*)&c2s[l * 4];
        float4 o;
        o.x = a4.x * ax + dg * c4.x;
        o.y = a4.y * ay + dg * c4.y;
        o.z = a4.z * az + dg * c4.z;
        o.w = a4.w * aw + dg * c4.w;
        *(float4*)&agg[(size_t)v * 64 + l * 4] = o;
    }
}

// ---------------------------------------------------------------------------
extern "C" void kernel_launch(void* const* d_in, const int* in_sizes, int n_in,
                              void* d_out, int out_size, void* d_ws, size_t ws_size,
                              hipStream_t stream)
{
    const float* x = (const float*)d_in[0];
    const int* ei = (const int*)d_in[1];
    const int* src = ei;          // row 0
    const int* dst = ei + EE;     // row 1
    const float* W1[3] = {(const float*)d_in[2], (const float*)d_in[9],  (const float*)d_in[16]};
    const float* W2[3] = {(const float*)d_in[3], (const float*)d_in[10], (const float*)d_in[17]};
    const float* Wp[3] = {(const float*)d_in[4], (const float*)d_in[11], (const float*)d_in[18]};
    const float* g1[3] = {(const float*)d_in[5], (const float*)d_in[12], (const float*)d_in[19]};
    const float* b1[3] = {(const float*)d_in[6], (const float*)d_in[13], (const float*)d_in[20]};
    const float* g2[3] = {(const float*)d_in[7], (const float*)d_in[14], (const float*)d_in[21]};
    const float* b2[3] = {(const float*)d_in[8], (const float*)d_in[15], (const float*)d_in[22]};
    const float* gbn[2] = {(const float*)d_in[23], (const float*)d_in[25]};
    const float* bbn[2] = {(const float*)d_in[24], (const float*)d_in[26]};
    const float* Wm1 = (const float*)d_in[27];
    const float* bm1 = (const float*)d_in[28];
    const float* Wm2 = (const float*)d_in[29];
    const float* bm2 = (const float*)d_in[30];

    // workspace layout (floats)
    float* wsf  = (float*)d_ws;
    float* hbuf = wsf;                          // N*256
    float* sbuf = hbuf + (size_t)NN * DD;       // N*256
    float* y1   = sbuf + (size_t)NN * DD;       // N*64
    float* y2   = y1 + (size_t)NN * 64;         // N*64
    float* agg  = y2 + (size_t)NN * 64;         // N*64
    float* sm   = agg + (size_t)NN * 64;        // small scratch region
    float* y1s  = sm;             // 384
    float* y2s  = sm + 384;       // 384
    float* hs   = sm + 768;       // 1024
    int* ibase   = (int*)(sm + 6080);
    int* deg     = ibase;                 // NN
    int* rowptr  = deg + NN;              // NN+1
    int* cursor  = rowptr + NN + 1;       // NN
    int* bsum    = cursor + NN;           // 256
    int* csr_src = bsum + 256;            // EE
    int  ioff    = ((NN * 3 + 1 + 256 + EE) + 7) & ~7;
    short* wm1h  = (short*)(ibase + ioff);     // 65536 shorts
    short* wm1l  = wm1h + 65536;               // 65536 shorts
    short* w1h   = wm1l + 65536;               // 3 * 16384 shorts
    short* w1l   = w1h + 3 * 16384;            // 3 * 16384 shorts
    short* wpb   = w1l + 3 * 16384;            // 1048576 shorts (dedicated Wpb)

    const dim3 blk(256);
    const float invN = 1.0f / NN;
    const int nb = (NN + 63) / 64;     // 469
    const int nbf = (NN + 127) / 128;  // 235 (fog BM=128, one round per CU)
    const int nb2 = (NN + 255) / 256;  // 118
    const int nbe = (EE + 255) / 256;  // 3750

    hipMemsetAsync(sm, 0, 1792 * sizeof(float), stream);   // all stats accumulators
    hipMemsetAsync(deg, 0, NN * sizeof(int), stream);
    conv_wm1<<<32, blk, 0, stream>>>(Wm1, wm1h, wm1l);
    conv_w64_3<<<20, blk, 0, stream>>>(W1[0], W1[1], W1[2],
                                       w1h, w1l,
                                       w1h + 16384, w1l + 16384,
                                       w1h + 32768, w1l + 32768);

    for (int l = 0; l < 3; ++l) {
        const float* xin = (l == 0) ? x : hbuf;
        int cin = (l == 0) ? IN_ : DD;
        float* sO = (l == 0) ? nullptr : sbuf;
        int smode = (l == 0) ? 0 : ((l == 1) ? 1 : 2);
        const float* pim = (l == 0) ? nullptr : hs + (l - 1) * 512;
        const float* piq = (l == 0) ? nullptr : hs + (l - 1) * 512 + 256;
        const float* pig = (l == 0) ? nullptr : gbn[l - 1];
        const float* pib = (l == 0) ? nullptr : bbn[l - 1];

        // y1 = leaky(xin' @ W1.T)  with fused prev-H BN+ReLU + JK-sum write.
        // Layer 0 additionally carries the CSR edge histogram (hidden).
        int gridY1 = (l == 0) ? nb + nbe : nb;
        gemm64_mfma<<<gridY1, blk, 0, stream>>>(xin, cin, w1h + l * 16384, w1l + l * 16384,
                                                nullptr, y1, NN,
                                                y1s + l * 128, y1s + l * 128 + 64,
                                                pim, piq, pig, pib, sO, smode, invN,
                                                (l == 0) ? dst : nullptr,
                                                (l == 0) ? deg : nullptr, nb);

        if (l == 0) {   // CSR scans (tiny) between hist and fill
            scan1<<<nb2, blk, 0, stream>>>(deg, rowptr, bsum);
            scan2<<<1, blk, 0, stream>>>(bsum, rowptr, nb2);
            scan3<<<nb2, blk, 0, stream>>>(rowptr, bsum, cursor);
        }

        // y2 = leaky(y1_bn @ W2f.T + b2f)  with in-block BN1+W2 fold
        // + fused Wp->bf16 conversion; layer 0 additionally carries fill_csr.
        int gridY2 = (l == 0) ? nb + 512 + nbe : nb + 512;
        gemm64_w2<<<gridY2, blk, 0, stream>>>(y1, W2[l],
                                              y1s + l * 128, y1s + l * 128 + 64,
                                              g1[l], b1[l], y2, NN,
                                              y2s + l * 128, y2s + l * 128 + 64, invN,
                                              Wp[l], wpb, nb,
                                              src, dst, cursor, csr_src);

        // agg with in-block BN2 fold from y2 stats
        gather_agg<<<(NN + 3) / 4, blk, 0, stream>>>(rowptr, csr_src, y2,
                                                     y2s + l * 128, y2s + l * 128 + 64,
                                                     g2[l], b2[l], agg, invN);

        bool st = (l < 2);
        fog_mfma<<<dim3(nbf), dim3(512), 0, stream>>>(y1,
                                                      y1s + l * 128, y1s + l * 128 + 64,
                                                      g1[l], b1[l],
                                                      agg, wpb, hbuf, NN,
                                                      st ? hs + l * 512 : nullptr,
                                                      st ? hs + l * 512 + 256 : nullptr,
                                                      st ? nullptr : sbuf, invN);
    }

    // fused MLP head + log-softmax
    head_lsm<<<nb, dim3(512), 0, stream>>>(sbuf, wm1h, wm1l, bm1, Wm2, bm2,
                                           (float*)d_out, NN);
}

// Round 22
// 560.946 us; speedup vs baseline: 1.1205x; 1.0289x over previous
//
#include <hip/hip_runtime.h>
#include <hip/hip_bf16.h>
#include <math.h>

#define NN 30000
#define EE 960000
#define IN_ 128
#define DD 256
#define CC 40
#define EPS 1e-5f

typedef short bf8 __attribute__((ext_vector_type(8)));    // 8 bf16 (4 VGPRs)
typedef float f32x4 __attribute__((ext_vector_type(4)));

__device__ inline short f2bf(float x) {
    unsigned u = __float_as_uint(x);
    unsigned r = (u + 0x7fffu + ((u >> 16) & 1u)) >> 16;   // RNE
    return (short)r;
}

__device__ inline float bf2f(unsigned short u) {
    return __uint_as_float(((unsigned)u) << 16);
}

__device__ inline unsigned pk2(float lo, float hi) {
    __hip_bfloat162 h = __float22bfloat162_rn(make_float2(lo, hi));
    return *reinterpret_cast<unsigned*>(&h);
}

// split 8 f32 into bf16 hi + bf16 lo(residual) fragments
__device__ inline void split8(float4 f0, float4 f1, bf8* h, bf8* l) {
    unsigned h0 = pk2(f0.x, f0.y), h1 = pk2(f0.z, f0.w);
    unsigned h2 = pk2(f1.x, f1.y), h3 = pk2(f1.z, f1.w);
    float e0 = f0.x - __uint_as_float(h0 << 16);
    float e1 = f0.y - __uint_as_float(h0 & 0xFFFF0000u);
    float e2 = f0.z - __uint_as_float(h1 << 16);
    float e3 = f0.w - __uint_as_float(h1 & 0xFFFF0000u);
    float e4 = f1.x - __uint_as_float(h2 << 16);
    float e5 = f1.y - __uint_as_float(h2 & 0xFFFF0000u);
    float e6 = f1.z - __uint_as_float(h3 << 16);
    float e7 = f1.w - __uint_as_float(h3 & 0xFFFF0000u);
    uint4 hu = make_uint4(h0, h1, h2, h3);
    uint4 lu = make_uint4(pk2(e0, e1), pk2(e2, e3), pk2(e4, e5), pk2(e6, e7));
    *h = *(bf8*)&hu;
    *l = *(bf8*)&lu;
}

// ---------------------------------------------------------------------------
// Small GEMM via bf16x3 split MFMA (y1 layers). Optional in-block BN fold of
// the INPUT from raw stats (K==256 mode) with JK-sum write. Per-col output
// sum/sumsq stats. Blocks >= nbG run hist_deg's edge histogram (layer-0).
// ---------------------------------------------------------------------------
__global__ __launch_bounds__(256) void gemm64_mfma(
    const float* __restrict__ A, int K,
    const short* __restrict__ Whi, const short* __restrict__ Wlo,
    const float* __restrict__ bias,
    float* __restrict__ Y, int Nrows,
    float* __restrict__ osum, float* __restrict__ osq,
    const float* __restrict__ isum, const float* __restrict__ isq,
    const float* __restrict__ ig, const float* __restrict__ ib,
    float* __restrict__ sOut, int smode, float invN,
    const int* __restrict__ hdst, int* __restrict__ hdeg, int nbG)
{
    if (blockIdx.x >= nbG) {
        // fused hist_deg (layer 0 only)
        int e = (blockIdx.x - nbG) * 256 + threadIdx.x;
        if (e < EE) atomicAdd(&hdeg[hdst[e]], 1);
        return;
    }

    __shared__ float redS[4][64], redQ[4][64];
    __shared__ float ah_s[256], ch_s[256];
    const int t = threadIdx.x;
    if (isum) {   // K==256 in this mode; 256 threads each fold one column
        float m = isum[t] * invN;
        float vv = isq[t] * invN - m * m;
        float s = ig[t] * rsqrtf(vv + EPS);
        ah_s[t] = s;
        ch_s[t] = ib[t] - m * s;
        __syncthreads();
    }
    const int lane = t & 63;
    const int w = t >> 6;
    const int l15 = lane & 15, l4 = (lane >> 4) & 3;
    const int row0 = blockIdx.x * 64 + w * 16;
    const bf8* whi = (const bf8*)Whi;
    const bf8* wlo = (const bf8*)Wlo;

    f32x4 acc[4] = {};
    const int nst = K >> 5;
    const int nA = row0 + l15;
    const bool valA = nA < Nrows;

#pragma unroll 2
    for (int ks = 0; ks < nst; ++ks) {
        int k0 = ks * 32 + l4 * 8;
        float4 f0, f1;
        if (valA) {
            const float* p = &A[(size_t)nA * K + k0];
            f0 = *(const float4*)p;
            f1 = *(const float4*)(p + 4);
        } else {
            f0 = make_float4(0.f, 0.f, 0.f, 0.f);
            f1 = f0;
        }
        if (isum) {
            float4 a4 = *(const float4*)&ah_s[k0], a5 = *(const float4*)&ah_s[k0 + 4];
            float4 c4 = *(const float4*)&ch_s[k0], c5 = *(const float4*)&ch_s[k0 + 4];
            f0.x = fmaxf(a4.x * f0.x + c4.x, 0.f);
            f0.y = fmaxf(a4.y * f0.y + c4.y, 0.f);
            f0.z = fmaxf(a4.z * f0.z + c4.z, 0.f);
            f0.w = fmaxf(a4.w * f0.w + c4.w, 0.f);
            f1.x = fmaxf(a5.x * f1.x + c5.x, 0.f);
            f1.y = fmaxf(a5.y * f1.y + c5.y, 0.f);
            f1.z = fmaxf(a5.z * f1.z + c5.z, 0.f);
            f1.w = fmaxf(a5.w * f1.w + c5.w, 0.f);
            if (valA) {
                float* sp = &sOut[(size_t)nA * K + k0];
                if (smode == 1) {
                    *(float4*)sp = f0;
                    *(float4*)(sp + 4) = f1;
                } else {
                    float4 s0 = *(const float4*)sp, s1 = *(const float4*)(sp + 4);
                    s0.x += f0.x; s0.y += f0.y; s0.z += f0.z; s0.w += f0.w;
                    s1.x += f1.x; s1.y += f1.y; s1.z += f1.z; s1.w += f1.w;
                    *(float4*)sp = s0;
                    *(float4*)(sp + 4) = s1;
                }
            }
        }
        bf8 ah, al;
        split8(f0, f1, &ah, &al);
        bf8 bh[4], bl[4];
#pragma unroll
        for (int nr = 0; nr < 4; ++nr) {
            int idx = (ks * 4 + nr) * 64 + lane;
            bh[nr] = whi[idx];
            bl[nr] = wlo[idx];
        }
#pragma unroll
        for (int nr = 0; nr < 4; ++nr) {
            acc[nr] = __builtin_amdgcn_mfma_f32_16x16x32_bf16(ah, bh[nr], acc[nr], 0, 0, 0);
            acc[nr] = __builtin_amdgcn_mfma_f32_16x16x32_bf16(ah, bl[nr], acc[nr], 0, 0, 0);
            acc[nr] = __builtin_amdgcn_mfma_f32_16x16x32_bf16(al, bh[nr], acc[nr], 0, 0, 0);
        }
    }

    float cs[4] = {}, cq[4] = {};
#pragma unroll
    for (int nr = 0; nr < 4; ++nr) {
#pragma unroll
        for (int r = 0; r < 4; ++r) {
            int n = row0 + l4 * 4 + r;
            float v = acc[nr][r];
            if (bias) v += bias[nr * 16 + l15];
            v = (v > 0.f) ? v : 0.01f * v;
            if (n < Nrows) {
                Y[(size_t)n * 64 + nr * 16 + l15] = v;
                cs[nr] += v;
                cq[nr] += v * v;
            }
        }
    }
#pragma unroll
    for (int nr = 0; nr < 4; ++nr) {
        float s1 = cs[nr], s2 = cq[nr];
        s1 += __shfl_down(s1, 32);
        s2 += __shfl_down(s2, 32);
        s1 += __shfl_down(s1, 16);
        s2 += __shfl_down(s2, 16);
        if (lane < 16) {
            redS[w][nr * 16 + l15] = s1;
            redQ[w][nr * 16 + l15] = s2;
        }
    }
    __syncthreads();
    if (t < 64) {
        float s1 = redS[0][t] + redS[1][t] + redS[2][t] + redS[3][t];
        float s2 = redQ[0][t] + redQ[1][t] + redQ[2][t] + redQ[3][t];
        atomicAdd(&osum[t], s1);
        atomicAdd(&osq[t], s2);
    }
}

// ---------------------------------------------------------------------------
// y2 GEMM with IN-BLOCK BN1 fold + W2 fold (blocks < nbG), fused Wp bf16
// conversion (blocks [nbG, nbG+512)), and fused fill_csr (blocks >= nbG+512,
// layer-0 only). y2 OUTPUT IS NOW bf16 (gather's sole-consumer byte-halving);
// BN2 stats still accumulated from exact f32 values.
// ---------------------------------------------------------------------------
__global__ __launch_bounds__(256) void gemm64_w2(
    const float* __restrict__ A,          // y1 [N][64]
    const float* __restrict__ W2,         // [64][64] f32
    const float* __restrict__ isum, const float* __restrict__ isq,   // y1 stats
    const float* __restrict__ g1v, const float* __restrict__ b1v,
    unsigned short* __restrict__ Yb, int Nrows,
    float* __restrict__ osum, float* __restrict__ osq, float invN,
    const float* __restrict__ Wp, short* __restrict__ Wpb, int nbG,
    const int* __restrict__ fsrc, const int* __restrict__ fdst,
    int* __restrict__ fcursor, int* __restrict__ fcsr)
{
    if (blockIdx.x >= nbG + 512) {
        // fused fill_csr (layer 0 only)
        int e = (blockIdx.x - nbG - 512) * 256 + threadIdx.x;
        if (e < EE) {
            int p = atomicAdd(&fcursor[fdst[e]], 1);
            fcsr[p] = fsrc[e];
        }
        return;
    }
    if (blockIdx.x >= nbG) {
        // conv_wp: convert Wp (f32 [256][4096]) to bf16 pre-tiled fragments
        int tid = (blockIdx.x - nbG) * 256 + threadIdx.x;   // 131072 threads
        int l = tid & 63;
        int r = tid >> 6;
        int jo = r & 1;
        int q = r >> 1;
        int cb = q & 15;
        int i = q >> 4;
        int col = cb * 16 + (l & 15);
        int k = i * 64 + jo * 32 + ((l >> 4) & 3) * 8;
        const float* srcp = Wp + (size_t)col * 4096 + k;
        bf8 v;
#pragma unroll
        for (int e = 0; e < 8; ++e) v[e] = f2bf(srcp[e]);
        ((bf8*)Wpb)[tid] = v;
        return;
    }

    __shared__ float redS[4][64], redQ[4][64];
    __shared__ float as_[64], cs_[64], b2s[64];
    __shared__ __align__(16) short w2hs[4096], w2ls[4096];
    const int t = threadIdx.x;

    // fold BN1 from raw stats (identical expressions to fold_bn1_w2)
    if (t < 64) {
        float m = isum[t] * invN;
        float vv = isq[t] * invN - m * m;
        float s = g1v[t] * rsqrtf(vv + EPS);
        as_[t] = s;
        cs_[t] = b1v[t] - m * s;
    }
    __syncthreads();
    if (t < 64) {
        float bb = 0.f;
        for (int i = 0; i < 64; ++i) bb += W2[t * 64 + i] * cs_[i];
        b2s[t] = bb;
    }
    // build W2f bf16 hi/lo fragments (512 slots, 2 per thread)
    for (int slot = t; slot < 512; slot += 256) {
        int rep = slot >> 6, l = slot & 63;
        int cb = rep & 3, ks = rep >> 2;
        int col = cb * 16 + (l & 15);
        int k = ks * 32 + ((l >> 4) & 3) * 8;
        bf8 h, lo;
#pragma unroll
        for (int e = 0; e < 8; ++e) {
            float v = W2[col * 64 + k + e] * as_[k + e];
            short hb = f2bf(v);
            float hf = __uint_as_float(((unsigned)(unsigned short)hb) << 16);
            h[e] = hb;
            lo[e] = f2bf(v - hf);
        }
        ((bf8*)w2hs)[slot] = h;
        ((bf8*)w2ls)[slot] = lo;
    }
    __syncthreads();

    const int lane = t & 63;
    const int w = t >> 6;
    const int l15 = lane & 15, l4 = (lane >> 4) & 3;
    const int row0 = blockIdx.x * 64 + w * 16;
    const bf8* whi = (const bf8*)w2hs;
    const bf8* wlo = (const bf8*)w2ls;

    f32x4 acc[4] = {};
    const int nA = row0 + l15;
    const bool valA = nA < Nrows;

#pragma unroll
    for (int ks = 0; ks < 2; ++ks) {
        int k0 = ks * 32 + l4 * 8;
        float4 f0, f1;
        if (valA) {
            const float* p = &A[(size_t)nA * 64 + k0];
            f0 = *(const float4*)p;
            f1 = *(const float4*)(p + 4);
        } else {
            f0 = make_float4(0.f, 0.f, 0.f, 0.f);
            f1 = f0;
        }
        bf8 ah, al;
        split8(f0, f1, &ah, &al);
        bf8 bh[4], bl[4];
#pragma unroll
        for (int nr = 0; nr < 4; ++nr) {
            int idx = (ks * 4 + nr) * 64 + lane;
            bh[nr] = whi[idx];
            bl[nr] = wlo[idx];
        }
#pragma unroll
        for (int nr = 0; nr < 4; ++nr) {
            acc[nr] = __builtin_amdgcn_mfma_f32_16x16x32_bf16(ah, bh[nr], acc[nr], 0, 0, 0);
            acc[nr] = __builtin_amdgcn_mfma_f32_16x16x32_bf16(ah, bl[nr], acc[nr], 0, 0, 0);
            acc[nr] = __builtin_amdgcn_mfma_f32_16x16x32_bf16(al, bh[nr], acc[nr], 0, 0, 0);
        }
    }

    float cs[4] = {}, cq[4] = {};
#pragma unroll
    for (int nr = 0; nr < 4; ++nr) {
#pragma unroll
        for (int r = 0; r < 4; ++r) {
            int n = row0 + l4 * 4 + r;
            float v = acc[nr][r] + b2s[nr * 16 + l15];
            v = (v > 0.f) ? v : 0.01f * v;
            if (n < Nrows) {
                Yb[(size_t)n * 64 + nr * 16 + l15] = (unsigned short)f2bf(v);
                cs[nr] += v;
                cq[nr] += v * v;
            }
        }
    }
#pragma unroll
    for (int nr = 0; nr < 4; ++nr) {
        float s1 = cs[nr], s2 = cq[nr];
        s1 += __shfl_down(s1, 32);
        s2 += __shfl_down(s2, 32);
        s1 += __shfl_down(s1, 16);
        s2 += __shfl_down(s2, 16);
        if (lane < 16) {
            redS[w][nr * 16 + l15] = s1;
            redQ[w][nr * 16 + l15] = s2;
        }
    }
    __syncthreads();
    if (t < 64) {
        float s1 = redS[0][t] + redS[1][t] + redS[2][t] + redS[3][t];
        float s2 = redQ[0][t] + redQ[1][t] + redQ[2][t] + redQ[3][t];
        atomicAdd(&osum[t], s1);
        atomicAdd(&osq[t], s2);
    }
}

// ---------------------------------------------------------------------------
// Convert the three W1 weights ([64][K] f32) to bf16 hi/lo tiled frags, 1 launch.
// ---------------------------------------------------------------------------
__global__ void conv_w64_3(const float* __restrict__ W0, const float* __restrict__ Wa,
                           const float* __restrict__ Wb,
                           short* __restrict__ O0h, short* __restrict__ O0l,
                           short* __restrict__ O1h, short* __restrict__ O1l,
                           short* __restrict__ O2h, short* __restrict__ O2l)
{
    int tid = blockIdx.x * 256 + threadIdx.x;   // 1024 + 2048 + 2048 = 5120 frags
    const float* W; short* oh; short* ol; int K, f;
    if (tid < 1024)      { W = W0; oh = O0h; ol = O0l; K = 128; f = tid; }
    else if (tid < 3072) { W = Wa; oh = O1h; ol = O1l; K = 256; f = tid - 1024; }
    else if (tid < 5120) { W = Wb; oh = O2h; ol = O2l; K = 256; f = tid - 3072; }
    else return;
    int l = f & 63;
    int r = f >> 6;
    int cb = r & 3, ks = r >> 2;
    int col = cb * 16 + (l & 15);
    int k = ks * 32 + ((l >> 4) & 3) * 8;
    const float* src = W + (size_t)col * K + k;
    bf8 h, lo;
#pragma unroll
    for (int e = 0; e < 8; ++e) {
        float v = src[e];
        short hb = f2bf(v);
        float hf = __uint_as_float(((unsigned)(unsigned short)hb) << 16);
        h[e] = hb;
        lo[e] = f2bf(v - hf);
    }
    ((bf8*)oh)[f] = h;
    ((bf8*)ol)[f] = lo;
}

// ---------------------------------------------------------------------------
// Convert Wm1 (f32 [256][256]) to bf16 hi/lo pre-tiled fragments (16 cb).
// ---------------------------------------------------------------------------
__global__ void conv_wm1(const float* __restrict__ W,
                         short* __restrict__ Whi, short* __restrict__ Wlo)
{
    int tid = blockIdx.x * 256 + threadIdx.x;   // 8192 threads
    int l = tid & 63;
    int f = tid >> 6;
    int cb = f & 15;
    int ks = f >> 4;
    int col = cb * 16 + (l & 15);
    int k = ks * 32 + ((l >> 4) & 3) * 8;
    const float* src = W + (size_t)col * 256 + k;
    bf8 h, lo;
#pragma unroll
    for (int e = 0; e < 8; ++e) {
        float v = src[e];
        short hb = f2bf(v);
        float hf = __uint_as_float(((unsigned)(unsigned short)hb) << 16);
        h[e] = hb;
        lo[e] = f2bf(v - hf);
    }
    ((bf8*)Whi)[tid] = h;
    ((bf8*)Wlo)[tid] = lo;
}

// ---------------------------------------------------------------------------
// MFMA big GEMM v9 (BM=128, one round per CU, lgkmcnt-only barrier) with
// IN-BLOCK BN1 fold prologue (a1/c1 from y1 stats; identical FP expressions).
// ---------------------------------------------------------------------------
#define FOG_BARRIER() asm volatile("s_waitcnt lgkmcnt(0)\n\ts_barrier" ::: "memory")

#define FOG_STEP(I, BUF, BU, BP)                                              \
  {                                                                           \
    bf8 af[4][2];                                                             \
    _Pragma("unroll")                                                         \
    for (int m = 0; m < 4; ++m) {                                             \
      _Pragma("unroll")                                                       \
      for (int jo = 0; jo < 2; ++jo) {                                        \
        int c = jo * 4 + l4;                                                  \
        int n = (mrb + m) * 16 + l15;                                         \
        af[m][jo] = *(const bf8*)&At[BUF][c][n ^ (c & 7)][0];                 \
      }                                                                       \
    }                                                                         \
    int inext = ((I) < 63) ? (I) + 1 : 63;                                    \
    _Pragma("unroll")                                                         \
    for (int nr = 0; nr < 4; ++nr) {                                          \
      _Pragma("unroll")                                                       \
      for (int jo = 0; jo < 2; ++jo)                                          \
        BP[nr][jo] = wp8[((inext * 16 + cbb + nr) * 2 + jo) * 64 + lane];     \
    }                                                                         \
    _Pragma("unroll")                                                         \
    for (int m = 0; m < 4; ++m) {                                             \
      _Pragma("unroll")                                                       \
      for (int nr = 0; nr < 4; ++nr) {                                        \
        acc[m][nr] = __builtin_amdgcn_mfma_f32_16x16x32_bf16(af[m][0], BU[nr][0], acc[m][nr], 0, 0, 0); \
        acc[m][nr] = __builtin_amdgcn_mfma_f32_16x16x32_bf16(af[m][1], BU[nr][1], acc[m][nr], 0, 0, 0); \
      }                                                                       \
    }                                                                         \
    if ((I) < 63) {                                                           \
      float xv = xd_s[nl][(I) + 1];                                           \
      uint4 q0, q1;                                                           \
      q0.x = pk2(xv * agr[0],  xv * agr[1]);                                  \
      q0.y = pk2(xv * agr[2],  xv * agr[3]);                                  \
      q0.z = pk2(xv * agr[4],  xv * agr[5]);                                  \
      q0.w = pk2(xv * agr[6],  xv * agr[7]);                                  \
      q1.x = pk2(xv * agr[8],  xv * agr[9]);                                  \
      q1.y = pk2(xv * agr[10], xv * agr[11]);                                 \
      q1.z = pk2(xv * agr[12], xv * agr[13]);                                 \
      q1.w = pk2(xv * agr[14], xv * agr[15]);                                 \
      *(uint4*)&At[(BUF) ^ 1][cA][nl ^ (cA & 7)][0] = q0;                     \
      *(uint4*)&At[(BUF) ^ 1][cB][nl ^ (cB & 7)][0] = q1;                     \
    }                                                                         \
    FOG_BARRIER();                                                            \
  }

__global__ __launch_bounds__(512, 2) void fog_mfma(
    const float* __restrict__ y1,
    const float* __restrict__ isum, const float* __restrict__ isq,   // y1 stats
    const float* __restrict__ g1v, const float* __restrict__ b1v,
    const float* __restrict__ agg, const short* __restrict__ Wpb,
    float* __restrict__ H, int Nrows,
    float* __restrict__ ssum, float* __restrict__ ssq,
    float* __restrict__ sjk, float invN)
{
    __shared__ float xd_s[128][68];
    __shared__ __align__(16) short At[2][8][128][8];  // [buf][chunk][node^chunk][8 bf16]
    __shared__ float a1s[64], c1s[64];
    const int t = threadIdx.x;          // 0..511
    const int lane = t & 63;
    const int w = t >> 6;               // wave 0..7
    const int nbase = blockIdx.x * 128;
    const int nl = t >> 2;              // staging node 0..127
    const int cA = (t & 3) * 2;         // staging j-chunks cA, cB
    const int cB = cA + 1;
    const int l15 = lane & 15;
    const int l4 = (lane >> 4) & 3;
    const int mrb = (w & 1) * 4;        // row 16-block base: 0 or 4
    const int cbb = (w >> 1) * 4;       // col 16-block base: 0,4,8,12

    // in-block BN1 fold (identical expressions to the old fold kernel)
    if (t < 64) {
        float m = isum[t] * invN;
        float vv = isq[t] * invN - m * m;
        float s = g1v[t] * rsqrtf(vv + EPS);
        a1s[t] = s;
        c1s[t] = b1v[t] - m * s;
    }
    __syncthreads();

    // stage xd (BN1-folded y1) into LDS; agg 16-value chunk into regs
    float agr[16];
    {
        int n = nbase + nl;
        bool valid = n < Nrows;
        const float* yr = y1 + (size_t)n * 64 + cA * 8;
        const float* ar = agg + (size_t)n * 64 + cA * 8;
#pragma unroll
        for (int u = 0; u < 16; u += 4) {
            float4 yv = valid ? *(const float4*)(yr + u) : make_float4(0.f, 0.f, 0.f, 0.f);
            float4 av = valid ? *(const float4*)(ar + u) : make_float4(0.f, 0.f, 0.f, 0.f);
            int j0 = cA * 8 + u;
            xd_s[nl][j0 + 0] = a1s[j0 + 0] * yv.x + c1s[j0 + 0];
            xd_s[nl][j0 + 1] = a1s[j0 + 1] * yv.y + c1s[j0 + 1];
            xd_s[nl][j0 + 2] = a1s[j0 + 2] * yv.z + c1s[j0 + 2];
            xd_s[nl][j0 + 3] = a1s[j0 + 3] * yv.w + c1s[j0 + 3];
            agr[u + 0] = av.x; agr[u + 1] = av.y; agr[u + 2] = av.z; agr[u + 3] = av.w;
        }
    }
    __syncthreads();

    const bf8* wp8 = (const bf8*)Wpb;
    // gen A(0) -> buf0 ; load B(0) -> bA
    {
        float xv = xd_s[nl][0];
        uint4 q0, q1;
        q0.x = pk2(xv * agr[0],  xv * agr[1]);
        q0.y = pk2(xv * agr[2],  xv * agr[3]);
        q0.z = pk2(xv * agr[4],  xv * agr[5]);
        q0.w = pk2(xv * agr[6],  xv * agr[7]);
        q1.x = pk2(xv * agr[8],  xv * agr[9]);
        q1.y = pk2(xv * agr[10], xv * agr[11]);
        q1.z = pk2(xv * agr[12], xv * agr[13]);
        q1.w = pk2(xv * agr[14], xv * agr[15]);
        *(uint4*)&At[0][cA][nl ^ (cA & 7)][0] = q0;
        *(uint4*)&At[0][cB][nl ^ (cB & 7)][0] = q1;
    }
    bf8 bA[4][2], bB[4][2];
#pragma unroll
    for (int nr = 0; nr < 4; ++nr)
#pragma unroll
        for (int jo = 0; jo < 2; ++jo)
            bA[nr][jo] = wp8[((cbb + nr) * 2 + jo) * 64 + lane];
    __syncthreads();

    f32x4 acc[4][4] = {};
    for (int i = 0; i < 64; i += 2) {
        FOG_STEP(i,     0, bA, bB);
        FOG_STEP(i + 1, 1, bB, bA);
    }

    if (ssum) {
        float cs[4] = {}, cq[4] = {};
#pragma unroll
        for (int m = 0; m < 4; ++m) {
#pragma unroll
            for (int r = 0; r < 4; ++r) {
                int n = nbase + (mrb + m) * 16 + l4 * 4 + r;
                if (n < Nrows) {
#pragma unroll
                    for (int nr = 0; nr < 4; ++nr) {
                        float v = acc[m][nr][r];
                        H[(size_t)n * 256 + (cbb + nr) * 16 + l15] = v;
                        cs[nr] += v;
                        cq[nr] += v * v;
                    }
                }
            }
        }
#pragma unroll
        for (int nr = 0; nr < 4; ++nr) {
            float s1 = cs[nr], s2 = cq[nr];
            s1 += __shfl_down(s1, 32);
            s2 += __shfl_down(s2, 32);
            s1 += __shfl_down(s1, 16);
            s2 += __shfl_down(s2, 16);
            if (l4 == 0 && lane < 16) {
                atomicAdd(&ssum[(cbb + nr) * 16 + l15], s1);
                atomicAdd(&ssq[(cbb + nr) * 16 + l15], s2);
            }
        }
    } else {
        // last layer: s += x3 fused (each (n,col) owned by exactly one thread)
#pragma unroll
        for (int m = 0; m < 4; ++m) {
#pragma unroll
            for (int r = 0; r < 4; ++r) {
                int n = nbase + (mrb + m) * 16 + l4 * 4 + r;
                if (n < Nrows) {
#pragma unroll
                    for (int nr = 0; nr < 4; ++nr) {
                        size_t idx = (size_t)n * 256 + (cbb + nr) * 16 + l15;
                        sjk[idx] += acc[m][nr][r];
                    }
                }
            }
        }
    }
}

// ---------------------------------------------------------------------------
// Fused MLP head: hid = relu(s @ Wm1.T + bm1) via bf16x3 MFMA (staged in LDS),
// then logits = hid @ Wm2.T + bm2 and row log_softmax -> out. One kernel.
// ---------------------------------------------------------------------------
__global__ __launch_bounds__(512) void head_lsm(
    const float* __restrict__ A,
    const short* __restrict__ Whi, const short* __restrict__ Wlo,
    const float* __restrict__ bias,
    const float* __restrict__ Wm2, const float* __restrict__ bm2,
    float* __restrict__ out, int Nrows)
{
    __shared__ float hid_s[64][257];
    __shared__ float Wl[40][257];
    __shared__ float bl[40];
    const int t = threadIdx.x;
    const int lane = t & 63;
    const int w = t >> 6;
    const int nbase = blockIdx.x * 64;
    const int l15 = lane & 15, l4 = (lane >> 4) & 3;
    const int mrb = (w & 1) * 32;
    const int cbb = (w >> 1) * 4;
    const bf8* whi = (const bf8*)Whi;
    const bf8* wlo = (const bf8*)Wlo;

    for (int e = t; e < 40 * 256; e += 512) Wl[e >> 8][e & 255] = Wm2[e];
    if (t < 40) bl[t] = bm2[t];

    f32x4 acc[2][4] = {};
#pragma unroll
    for (int ks = 0; ks < 8; ++ks) {
        bf8 ah[2], al[2];
#pragma unroll
        for (int m = 0; m < 2; ++m) {
            int n = nbase + mrb + m * 16 + l15;
            float4 f0, f1;
            if (n < Nrows) {
                const float* p = &A[(size_t)n * 256 + ks * 32 + l4 * 8];
                f0 = *(const float4*)p;
                f1 = *(const float4*)(p + 4);
            } else {
                f0 = make_float4(0.f, 0.f, 0.f, 0.f);
                f1 = f0;
            }
            split8(f0, f1, &ah[m], &al[m]);
        }
        bf8 bh[4], blw[4];
#pragma unroll
        for (int nr = 0; nr < 4; ++nr) {
            int idx = (ks * 16 + cbb + nr) * 64 + lane;
            bh[nr] = whi[idx];
            blw[nr] = wlo[idx];
        }
#pragma unroll
        for (int m = 0; m < 2; ++m)
#pragma unroll
            for (int nr = 0; nr < 4; ++nr) {
                acc[m][nr] = __builtin_amdgcn_mfma_f32_16x16x32_bf16(ah[m], bh[nr], acc[m][nr], 0, 0, 0);
                acc[m][nr] = __builtin_amdgcn_mfma_f32_16x16x32_bf16(ah[m], blw[nr], acc[m][nr], 0, 0, 0);
                acc[m][nr] = __builtin_amdgcn_mfma_f32_16x16x32_bf16(al[m], bh[nr], acc[m][nr], 0, 0, 0);
            }
    }

#pragma unroll
    for (int m = 0; m < 2; ++m) {
#pragma unroll
        for (int r = 0; r < 4; ++r) {
            int rl = mrb + m * 16 + l4 * 4 + r;   // local row 0..63
#pragma unroll
            for (int nr = 0; nr < 4; ++nr) {
                int col = (cbb + nr) * 16 + l15;
                float v = acc[m][nr][r] + bias[col];
                hid_s[rl][col] = fmaxf(v, 0.f);
            }
        }
    }
    __syncthreads();

    // log-softmax: 8 threads per node, 5 classes each
    int nl2 = t >> 3;
    int sub = t & 7;
    int node = nbase + nl2;
    if (node >= Nrows) return;

    float accl[5];
#pragma unroll
    for (int r = 0; r < 5; ++r) accl[r] = bl[sub * 5 + r];
    for (int k = 0; k < 256; k += 4) {
        float4 h4 = *(const float4*)&hid_s[nl2][k];
        float hv[4] = {h4.x, h4.y, h4.z, h4.w};
#pragma unroll
        for (int kk = 0; kk < 4; ++kk)
#pragma unroll
            for (int r = 0; r < 5; ++r)
                accl[r] += hv[kk] * Wl[sub * 5 + r][k + kk];
    }
    float mx = accl[0];
#pragma unroll
    for (int r = 1; r < 5; ++r) mx = fmaxf(mx, accl[r]);
    for (int off = 1; off < 8; off <<= 1) mx = fmaxf(mx, __shfl_xor(mx, off, 8));
    float se = 0.f;
#pragma unroll
    for (int r = 0; r < 5; ++r) se += expf(accl[r] - mx);
    for (int off = 1; off < 8; off <<= 1) se += __shfl_xor(se, off, 8);
    float lse = logf(se);
#pragma unroll
    for (int r = 0; r < 5; ++r)
        out[(size_t)node * 40 + sub * 5 + r] = accl[r] - mx - lse;
}

// ---------------------------------------------------------------------------
// CSR scans (hist and fill are fused into the layer-0 GEMM launches).
// ---------------------------------------------------------------------------
__global__ void scan1(const int* __restrict__ deg, int* __restrict__ rowptr,
                      int* __restrict__ bsum)
{
    __shared__ int sh[256];
    int t = threadIdx.x;
    int i = blockIdx.x * 256 + t;
    int v = (i < NN) ? deg[i] : 0;
    sh[t] = v;
    __syncthreads();
    for (int off = 1; off < 256; off <<= 1) {
        int add = (t >= off) ? sh[t - off] : 0;
        __syncthreads();
        sh[t] += add;
        __syncthreads();
    }
    if (i < NN) rowptr[i] = sh[t] - v;          // exclusive
    if (t == 255) bsum[blockIdx.x] = sh[255];
}

__global__ void scan2(int* __restrict__ bsum, int* __restrict__ rowptr, int nb2)
{
    __shared__ int sh[256];
    int t = threadIdx.x;
    int v = (t < nb2) ? bsum[t] : 0;
    sh[t] = v;
    __syncthreads();
    for (int off = 1; off < 256; off <<= 1) {
        int add = (t >= off) ? sh[t - off] : 0;
        __syncthreads();
        sh[t] += add;
        __syncthreads();
    }
    if (t < nb2) bsum[t] = sh[t] - v;            // exclusive
    if (t == 0) rowptr[NN] = EE;
}

__global__ void scan3(int* __restrict__ rowptr, const int* __restrict__ bsum,
                      int* __restrict__ cursor)
{
    int i = blockIdx.x * 256 + threadIdx.x;
    if (i < NN) {
        int r = rowptr[i] + bsum[blockIdx.x];
        rowptr[i] = r;
        cursor[i] = r;
    }
}

// ---------------------------------------------------------------------------
// Gather aggregation with in-block BN2 fold; y2 is bf16 (half the bytes):
// agg[v] = a2 * (sum_{e: dst=v} y2[src_e]) + deg_v * c2.
// ONE WAVE per node: 4 edge-substreams x 16 chunk-lanes; 4 row-loads in
// flight per substream.
// ---------------------------------------------------------------------------
__global__ __launch_bounds__(256) void gather_agg(
    const int* __restrict__ rowptr, const int* __restrict__ csr_src,
    const unsigned short* __restrict__ y2b,
    const float* __restrict__ isum, const float* __restrict__ isq,
    const float* __restrict__ g2, const float* __restrict__ b2,
    float* __restrict__ agg, float invN)
{
    __shared__ float a2s[64], c2s[64];
    int t = threadIdx.x;
    if (t < 64) {
        float m = isum[t] * invN;
        float vv = isq[t] * invN - m * m;
        float s = g2[t] * rsqrtf(vv + EPS);
        a2s[t] = s;
        c2s[t] = b2[t] - m * s;
    }
    __syncthreads();
    int g = t >> 6;              // node within block: 0..3 (one wave per node)
    int sub = (t >> 4) & 3;      // edge substream 0..3
    int l = t & 15;              // 4-col chunk
    int v = blockIdx.x * 4 + g;
    if (v >= NN) return;
    int beg = rowptr[v], end = rowptr[v + 1];
    float ax0 = 0.f, ay0 = 0.f, az0 = 0.f, aw0 = 0.f;
    float ax1 = 0.f, ay1 = 0.f, az1 = 0.f, aw1 = 0.f;
    int k = beg + sub;
    for (; k + 12 < end; k += 16) {
        int s0 = csr_src[k], s1 = csr_src[k + 4];
        int s2 = csr_src[k + 8], s3 = csr_src[k + 12];
        ushort4 r0 = *(const ushort4*)&y2b[(size_t)s0 * 64 + l * 4];
        ushort4 r1 = *(const ushort4*)&y2b[(size_t)s1 * 64 + l * 4];
        ushort4 r2 = *(const ushort4*)&y2b[(size_t)s2 * 64 + l * 4];
        ushort4 r3 = *(const ushort4*)&y2b[(size_t)s3 * 64 + l * 4];
        ax0 += bf2f(r0.x) + bf2f(r2.x); ay0 += bf2f(r0.y) + bf2f(r2.y);
        az0 += bf2f(r0.z) + bf2f(r2.z); aw0 += bf2f(r0.w) + bf2f(r2.w);
        ax1 += bf2f(r1.x) + bf2f(r3.x); ay1 += bf2f(r1.y) + bf2f(r3.y);
        az1 += bf2f(r1.z) + bf2f(r3.z); aw1 += bf2f(r1.w) + bf2f(r3.w);
    }
    for (; k < end; k += 4) {
        int s = csr_src[k];
        ushort4 rv = *(const ushort4*)&y2b[(size_t)s * 64 + l * 4];
        ax0 += bf2f(rv.x); ay0 += bf2f(rv.y); az0 += bf2f(rv.z); aw0 += bf2f(rv.w);
    }
    float ax = ax0 + ax1, ay = ay0 + ay1, az = az0 + az1, aw = aw0 + aw1;
    ax += __shfl_down(ax, 32);
    ay += __shfl_down(ay, 32);
    az += __shfl_down(az, 32);
    aw += __shfl_down(aw, 32);
    ax += __shfl_down(ax, 16);
    ay += __shfl_down(ay, 16);
    az += __shfl_down(az, 16);
    aw += __shfl_down(aw, 16);
    if ((t & 63) < 16) {
        float dg = (float)(end - beg);
        float4 a4 = *(const float4*)&a2s[l * 4];
        float4 c4 = *(const float4*)&c2s[l * 4];
        float4 o;
        o.x = a4.x * ax + dg * c4.x;
        o.y = a4.y * ay + dg * c4.y;
        o.z = a4.z * az + dg * c4.z;
        o.w = a4.w * aw + dg * c4.w;
        *(float4*)&agg[(size_t)v * 64 + l * 4] = o;
    }
}

// ---------------------------------------------------------------------------
extern "C" void kernel_launch(void* const* d_in, const int* in_sizes, int n_in,
                              void* d_out, int out_size, void* d_ws, size_t ws_size,
                              hipStream_t stream)
{
    const float* x = (const float*)d_in[0];
    const int* ei = (const int*)d_in[1];
    const int* src = ei;          // row 0
    const int* dst = ei + EE;     // row 1
    const float* W1[3] = {(const float*)d_in[2], (const float*)d_in[9],  (const float*)d_in[16]};
    const float* W2[3] = {(const float*)d_in[3], (const float*)d_in[10], (const float*)d_in[17]};
    const float* Wp[3] = {(const float*)d_in[4], (const float*)d_in[11], (const float*)d_in[18]};
    const float* g1[3] = {(const float*)d_in[5], (const float*)d_in[12], (const float*)d_in[19]};
    const float* b1[3] = {(const float*)d_in[6], (const float*)d_in[13], (const float*)d_in[20]};
    const float* g2[3] = {(const float*)d_in[7], (const float*)d_in[14], (const float*)d_in[21]};
    const float* b2[3] = {(const float*)d_in[8], (const float*)d_in[15], (const float*)d_in[22]};
    const float* gbn[2] = {(const float*)d_in[23], (const float*)d_in[25]};
    const float* bbn[2] = {(const float*)d_in[24], (const float*)d_in[26]};
    const float* Wm1 = (const float*)d_in[27];
    const float* bm1 = (const float*)d_in[28];
    const float* Wm2 = (const float*)d_in[29];
    const float* bm2 = (const float*)d_in[30];

    // workspace layout (floats)
    float* wsf  = (float*)d_ws;
    float* hbuf = wsf;                          // N*256
    float* sbuf = hbuf + (size_t)NN * DD;       // N*256
    float* y1   = sbuf + (size_t)NN * DD;       // N*64
    float* y2   = y1 + (size_t)NN * 64;         // N*64 region (bf16 uses half)
    float* agg  = y2 + (size_t)NN * 64;         // N*64
    float* sm   = agg + (size_t)NN * 64;        // small scratch region
    float* y1s  = sm;             // 384
    float* y2s  = sm + 384;       // 384
    float* hs   = sm + 768;       // 1024
    int* ibase   = (int*)(sm + 6080);
    int* deg     = ibase;                 // NN
    int* rowptr  = deg + NN;              // NN+1
    int* cursor  = rowptr + NN + 1;       // NN
    int* bsum    = cursor + NN;           // 256
    int* csr_src = bsum + 256;            // EE
    int  ioff    = ((NN * 3 + 1 + 256 + EE) + 7) & ~7;
    short* wm1h  = (short*)(ibase + ioff);     // 65536 shorts
    short* wm1l  = wm1h + 65536;               // 65536 shorts
    short* w1h   = wm1l + 65536;               // 3 * 16384 shorts
    short* w1l   = w1h + 3 * 16384;            // 3 * 16384 shorts
    short* wpb   = w1l + 3 * 16384;            // 1048576 shorts (dedicated Wpb)
    unsigned short* y2b = (unsigned short*)y2; // bf16 y2 [N][64]

    const dim3 blk(256);
    const float invN = 1.0f / NN;
    const int nb = (NN + 63) / 64;     // 469
    const int nbf = (NN + 127) / 128;  // 235 (fog BM=128, one round per CU)
    const int nb2 = (NN + 255) / 256;  // 118
    const int nbe = (EE + 255) / 256;  // 3750

    hipMemsetAsync(sm, 0, 1792 * sizeof(float), stream);   // all stats accumulators
    hipMemsetAsync(deg, 0, NN * sizeof(int), stream);
    conv_wm1<<<32, blk, 0, stream>>>(Wm1, wm1h, wm1l);
    conv_w64_3<<<20, blk, 0, stream>>>(W1[0], W1[1], W1[2],
                                       w1h, w1l,
                                       w1h + 16384, w1l + 16384,
                                       w1h + 32768, w1l + 32768);

    for (int l = 0; l < 3; ++l) {
        const float* xin = (l == 0) ? x : hbuf;
        int cin = (l == 0) ? IN_ : DD;
        float* sO = (l == 0) ? nullptr : sbuf;
        int smode = (l == 0) ? 0 : ((l == 1) ? 1 : 2);
        const float* pim = (l == 0) ? nullptr : hs + (l - 1) * 512;
        const float* piq = (l == 0) ? nullptr : hs + (l - 1) * 512 + 256;
        const float* pig = (l == 0) ? nullptr : gbn[l - 1];
        const float* pib = (l == 0) ? nullptr : bbn[l - 1];

        // y1 = leaky(xin' @ W1.T)  with fused prev-H BN+ReLU + JK-sum write.
        // Layer 0 additionally carries the CSR edge histogram (hidden).
        int gridY1 = (l == 0) ? nb + nbe : nb;
        gemm64_mfma<<<gridY1, blk, 0, stream>>>(xin, cin, w1h + l * 16384, w1l + l * 16384,
                                                nullptr, y1, NN,
                                                y1s + l * 128, y1s + l * 128 + 64,
                                                pim, piq, pig, pib, sO, smode, invN,
                                                (l == 0) ? dst : nullptr,
                                                (l == 0) ? deg : nullptr, nb);

        if (l == 0) {   // CSR scans (tiny) between hist and fill
            scan1<<<nb2, blk, 0, stream>>>(deg, rowptr, bsum);
            scan2<<<1, blk, 0, stream>>>(bsum, rowptr, nb2);
            scan3<<<nb2, blk, 0, stream>>>(rowptr, bsum, cursor);
        }

        // y2 (bf16) = leaky(y1_bn @ W2f.T + b2f)  with in-block BN1+W2 fold
        // + fused Wp->bf16 conversion; layer 0 additionally carries fill_csr.
        int gridY2 = (l == 0) ? nb + 512 + nbe : nb + 512;
        gemm64_w2<<<gridY2, blk, 0, stream>>>(y1, W2[l],
                                              y1s + l * 128, y1s + l * 128 + 64,
                                              g1[l], b1[l], y2b, NN,
                                              y2s + l * 128, y2s + l * 128 + 64, invN,
                                              Wp[l], wpb, nb,
                                              src, dst, cursor, csr_src);

        // agg with in-block BN2 fold from y2 stats (bf16 y2 reads)
        gather_agg<<<(NN + 3) / 4, blk, 0, stream>>>(rowptr, csr_src, y2b,
                                                     y2s + l * 128, y2s + l * 128 + 64,
                                                     g2[l], b2[l], agg, invN);

        bool st = (l < 2);
        fog_mfma<<<dim3(nbf), dim3(512), 0, stream>>>(y1,
                                                      y1s + l * 128, y1s + l * 128 + 64,
                                                      g1[l], b1[l],
                                                      agg, wpb, hbuf, NN,
                                                      st ? hs + l * 512 : nullptr,
                                                      st ? hs + l * 512 + 256 : nullptr,
                                                      st ? nullptr : sbuf, invN);
    }

    // fused MLP head + log-softmax
    head_lsm<<<nb, dim3(512), 0, stream>>>(sbuf, wm1h, wm1l, bm1, Wm2, bm2,
                                           (float*)d_out, NN);
}